// Round 14
// baseline (1062.827 us; speedup 1.0000x reference)
//
#include <hip/hip_runtime.h>
#include <math.h>

#define BB 4
#define LL 2048
#define DD 512
#define NH 8
#define DINNER 2048
#define NLAYERS 4
#define MM (BB * LL)  // 8192

typedef __attribute__((ext_vector_type(8))) __bf16 bf16x8;
typedef __attribute__((ext_vector_type(4))) float f32x4;

__device__ __forceinline__ unsigned short f2b(float f) {
  union { __bf16 h; unsigned short u; } v;
  v.h = (__bf16)f;  // native RNE convert
  return v.u;
}
__device__ __forceinline__ float b2f(unsigned short h) {
  union { unsigned u; float f; } v; v.u = ((unsigned)h) << 16; return v.f;
}
__device__ __forceinline__ unsigned pk2(float lo, float hi) {
  return (unsigned)f2b(lo) | ((unsigned)f2b(hi) << 16);
}
__device__ __forceinline__ float exp2f_fast(float x) {
  float r; asm("v_exp_f32 %0, %1" : "=v"(r) : "v"(x)); return r;
}

__device__ __forceinline__ void gload16(const void* g, void* l) {
  __builtin_amdgcn_global_load_lds(
      (const __attribute__((address_space(1))) void*)g,
      (__attribute__((address_space(3))) void*)l, 16, 0, 0);
}

// ---- init: temporal enc + embedding gather; emits xa = emb+tem directly ----
__global__ __launch_bounds__(512) void init_kernel(
    const int* __restrict__ etype, const float* __restrict__ etime,
    const float* __restrict__ npm, const float* __restrict__ emb,
    float* __restrict__ tem, float* __restrict__ xa,
    unsigned short* __restrict__ xab) {
  int row = blockIdx.x;
  int d = threadIdx.x;
  float t = etime[row];
  float mask = npm[row];
  int dd = d & ~1;
  float pv = expf(9.210340371976184f * ((float)dd * (1.0f / (float)DD)));
  float r = t / pv;
  float val = (d & 1) ? cosf(r) : sinf(r);
  float tv = val * mask;
  tem[(size_t)row * DD + d] = tv;
  int ty = etype[row];
  float a = emb[(size_t)ty * DD + d] + tv;
  xa[(size_t)row * DD + d] = a;
  xab[(size_t)row * DD + d] = f2b(a);
}

// ---------------- weight transpose+convert: fp32 [K][N] -> bf16 [N][K] ----
__global__ __launch_bounds__(256) void wtrans_kernel(
    const float* __restrict__ in, unsigned short* __restrict__ out,
    int K, int N, long in_ls, long out_ls) {
  __shared__ float t[32][33];
  int l = blockIdx.z;
  int n0 = blockIdx.x * 32, k0 = blockIdx.y * 32;
  int tx = threadIdx.x & 31, ty = threadIdx.x >> 5;
  const float* ip = in + (size_t)l * in_ls;
  unsigned short* op = out + (size_t)l * out_ls;
#pragma unroll
  for (int r = ty; r < 32; r += 8)
    t[r][tx] = ip[(size_t)(k0 + r) * N + n0 + tx];
  __syncthreads();
#pragma unroll
  for (int r = ty; r < 32; r += 8)
    op[(size_t)(n0 + r) * K + k0 + tx] = f2b(t[tx][r]);
}

// ---- MFMA GEMM, 2-phase pipelined, XCD-chunked 1D grid (T1 swizzle) ----
// C[M,N] = A(bf16 [M,K]) @ WT(bf16 [N,K])^T.  1D grid, nwg % 8 == 0.
// NS>1: split-K — grid = NS * (M/BM)*(N/128); split is the SLOWEST work dim;
// each split writes a partial (no bias/res/gelu) to Cv + split*M*ldc.
template <int BM, bool BIAS, bool RES, bool GELU_, bool OBF16, int NS = 1>
__global__ __launch_bounds__(256) void gemm_kernel(
    const unsigned short* __restrict__ A, const unsigned short* __restrict__ WT,
    const float* __restrict__ bias, const float* __restrict__ res, int ldres,
    void* __restrict__ Cv, int ldc, int M, int N, int K) {
  __shared__ unsigned short As[2][BM * 32];
  __shared__ unsigned short Bs[2][128 * 32];
  constexpr int NT = (BM == 128) ? 4 : 2;
  int tid = threadIdx.x;
  int w = tid >> 6, l = tid & 63;
  int li = l & 15, g = l >> 4;
  // XCD-chunked bijective remap (nwg divisible by 8)
  int nwg = gridDim.x;
  int bid = blockIdx.x;
  int wg = (bid & 7) * (nwg >> 3) + (bid >> 3);
  int gx = N >> 7;  // N/128 col-tiles
  int split = 0;
  if (NS > 1) {
    int items = (M / BM) * gx;
    split = wg / items;
    wg -= split * items;
  }
  int row0 = (wg / gx) * BM, col0 = (wg % gx) * 128;
  int kbeg = (NS > 1) ? split * (K / NS) : 0;
  size_t splitoff = (size_t)split * M * ldc;
  int wm = (BM == 128) ? (w & 1) * 64 : 0;
  int wnb = (BM == 128) ? (w >> 1) * 64 : w * 32;
  f32x4 acc[4][NT];
#pragma unroll
  for (int i = 0; i < 4; i++)
#pragma unroll
    for (int j = 0; j < NT; j++) acc[i][j] = (f32x4){0.f, 0.f, 0.f, 0.f};

  int lr = l >> 2;
  int lc = (l & 3) ^ (lr & 3);

  auto stage = [&](int bb, int kb) {
    int k0 = kbeg + kb * 32;
    if (BM == 128) {
#pragma unroll
      for (int i = 0; i < 2; i++) {
        int ai = w * 2 + i;
        gload16(A + (size_t)(row0 + ai * 16 + lr) * K + k0 + lc * 8,
                &As[bb][ai * 512]);
        gload16(WT + (size_t)(col0 + ai * 16 + lr) * K + k0 + lc * 8,
                &Bs[bb][ai * 512]);
      }
    } else {
      gload16(A + (size_t)(row0 + w * 16 + lr) * K + k0 + lc * 8,
              &As[bb][w * 512]);
#pragma unroll
      for (int i = 0; i < 2; i++) {
        int bi = w * 2 + i;
        gload16(WT + (size_t)(col0 + bi * 16 + lr) * K + k0 + lc * 8,
                &Bs[bb][bi * 512]);
      }
    }
  };

  int nk = (K / NS) >> 5;
  stage(0, 0);
  __syncthreads();
  int buf = 0;
  for (int kb = 0; kb < nk; kb++) {
    if (kb + 1 < nk) stage(buf ^ 1, kb + 1);
    bf16x8 af[4], bf_[NT];
#pragma unroll
    for (int mt = 0; mt < 4; mt++) {
      int r = wm + mt * 16 + li;
      af[mt] = *(const bf16x8*)&As[buf][r * 32 + ((g ^ (r & 3)) * 8)];
    }
#pragma unroll
    for (int nt = 0; nt < NT; nt++) {
      int r = wnb + nt * 16 + li;
      bf_[nt] = *(const bf16x8*)&Bs[buf][r * 32 + ((g ^ (r & 3)) * 8)];
    }
#pragma unroll
    for (int mt = 0; mt < 4; mt++)
#pragma unroll
      for (int nt = 0; nt < NT; nt++)
        acc[mt][nt] = __builtin_amdgcn_mfma_f32_16x16x32_bf16(
            af[mt], bf_[nt], acc[mt][nt], 0, 0, 0);
    __syncthreads();
    buf ^= 1;
  }
#pragma unroll
  for (int mt = 0; mt < 4; mt++) {
#pragma unroll
    for (int nt = 0; nt < NT; nt++) {
#pragma unroll
      for (int r = 0; r < 4; r++) {
        int row = row0 + wm + mt * 16 + g * 4 + r;
        int col = col0 + wnb + nt * 16 + li;
        float v = acc[mt][nt][r];
        if (BIAS) v += bias[col];
        if (RES) v += res[(size_t)row * ldres + col];
        if (GELU_) v = 0.5f * v * (1.0f + erff(v * 0.70710678118654752f));
        if (OBF16)
          ((unsigned short*)Cv)[splitoff + (size_t)row * ldc + col] = f2b(v);
        else
          ((float*)Cv)[splitoff + (size_t)row * ldc + col] = v;
      }
    }
  }
}

// ---------------- transpose v slice of qkv -> vT [bh*64+d][L] ----------
__global__ __launch_bounds__(256) void vtrans_kernel(
    const unsigned short* __restrict__ qkv, unsigned short* __restrict__ vT) {
  __shared__ unsigned short t[64][65];
  int bh = blockIdx.y;
  int b = bh >> 3, h = bh & 7;
  int l0 = blockIdx.x * 64;
  int tid = threadIdx.x;
  int c = tid & 63, p = tid >> 6;
#pragma unroll
  for (int r = p; r < 64; r += 4)
    t[r][c] = qkv[(size_t)(b * LL + l0 + r) * 1536 + 1024 + h * 64 + c];
  __syncthreads();
#pragma unroll
  for (int r = p; r < 64; r += 4)
    vT[((size_t)bh * 64 + r) * LL + l0 + c] = t[c][r];
}

// ---------------- meanV over L per (b,h,d), from vT ----------------
__global__ __launch_bounds__(256) void meanv_kernel(
    const unsigned short* __restrict__ vT, float* __restrict__ meanV) {
  __shared__ float red[256];
  int bh = blockIdx.x;
  int tid = threadIdx.x;
  int d = tid >> 2, p = tid & 3;
  const unsigned short* vp = vT + ((size_t)bh * 64 + d) * LL;
  float s = 0.f;
  for (int i = p * 512; i < p * 512 + 512; i++) s += b2f(vp[i]);
  red[tid] = s;
  __syncthreads();
  if (p == 0)
    meanV[bh * 64 + d] =
        (red[tid] + red[tid + 1] + red[tid + 2] + red[tid + 3]) *
        (1.0f / (float)LL);
}

// ---- MFMA flash attention, 2-way KEY-SPLIT (r10 proven structure) ----
__global__ __launch_bounds__(256) void attn_kernel(
    const unsigned short* __restrict__ qkv, const unsigned short* __restrict__ vT,
    const int* __restrict__ etype, unsigned short* __restrict__ opart,
    float* __restrict__ ml) {
  __shared__ unsigned short Ks[2][64 * 64];  // [buf][key*64+d], swizzled 8KB
  __shared__ unsigned short Ps[64][72];
  int hwbid = blockIdx.x;
  int work = (hwbid & 7) * 256 + (hwbid >> 3);  // XCD-chunked (bijective)
  int bh = work >> 6;
  int rem = work & 63;
  int qt = 31 - (rem >> 1);  // LPT: big q-tiles first
  int half = rem & 1;
  int h = bh & 7, b = bh >> 3;
  int q0 = qt * 64;
  int nt = qt + 1;
  int ha = (nt + 1) >> 1;  // half A gets ceil(nt/2), always nonempty
  int j0 = half ? ha : 0;
  int j1 = half ? nt : ha;
  int pidx = (bh * 32 + qt) * 2 + half;
  int tid = threadIdx.x, w = tid >> 6, l = tid & 63;
  int g = l >> 4, li = l & 15;
  const float SC = 0.125f * 1.44269504f;  // scale * log2(e)

  f32x4 o[4];
#pragma unroll
  for (int n = 0; n < 4; n++) o[n] = (f32x4){0.f, 0.f, 0.f, 0.f};
  float mreg[4], lreg[4];
#pragma unroll
  for (int r = 0; r < 4; r++) { mreg[r] = -3.0e38f; lreg[r] = 0.f; }

  if (j0 < j1) {
    const unsigned short* qrp =
        qkv + (size_t)(b * LL + q0 + w * 16 + li) * 1536 + h * 64;
    bf16x8 aq0 = *(const bf16x8*)&qrp[g * 8];
    bf16x8 aq1 = *(const bf16x8*)&qrp[32 + g * 8];

    // prologue: stage tile j0 into buf 0
#pragma unroll
    for (int e = 0; e < 2; e++) {
      int idx = e * 256 + tid;
      int r = idx >> 3;
      int src = (l & 7) ^ (r & 7);
      gload16(
          qkv + (size_t)(b * LL + j0 * 64 + r) * 1536 + 512 + h * 64 + src * 8,
          &Ks[0][(e * 256 + w * 64) * 8]);
    }
    __syncthreads();

    int cur = 0;
    for (int j = j0; j < j1; j++) {
      int k0 = j << 6;
      if (j + 1 < j1) {
#pragma unroll
        for (int e = 0; e < 2; e++) {
          int idx = e * 256 + tid;
          int r = idx >> 3;
          int src = (l & 7) ^ (r & 7);
          gload16(qkv + (size_t)(b * LL + k0 + 64 + r) * 1536 + 512 + h * 64 +
                      src * 8,
                  &Ks[cur ^ 1][(e * 256 + w * 64) * 8]);
        }
      }
      // V frags + pad bias, issued early (L2-resident)
      bf16x8 bv0[4], bv1[4];
      float pb[4];
#pragma unroll
      for (int n = 0; n < 4; n++) {
        const unsigned short* vp =
            vT + ((size_t)(bh * 64 + n * 16 + li)) * LL + k0;
        bv0[n] = *(const bf16x8*)&vp[g * 8];
        bv1[n] = *(const bf16x8*)&vp[32 + g * 8];
        pb[n] = (etype[b * LL + k0 + n * 16 + li] == 0) ? -1.0e9f : 0.f;
      }
      // S = Q K^T from swizzled LDS
      f32x4 s[4];
#pragma unroll
      for (int n = 0; n < 4; n++) {
        int rK = n * 16 + li;
        const unsigned short* kb = &Ks[cur][rK * 64];
        bf16x8 bk0 = *(const bf16x8*)&kb[(g ^ (rK & 7)) * 8];
        bf16x8 bk1 = *(const bf16x8*)&kb[((g + 4) ^ (rK & 7)) * 8];
        f32x4 a = (f32x4){0.f, 0.f, 0.f, 0.f};
        __builtin_amdgcn_s_setprio(1);
        a = __builtin_amdgcn_mfma_f32_16x16x32_bf16(aq0, bk0, a, 0, 0, 0);
        a = __builtin_amdgcn_mfma_f32_16x16x32_bf16(aq1, bk1, a, 0, 0, 0);
        __builtin_amdgcn_s_setprio(0);
        s[n] = a;
      }
      // scale + mask: fast path off-diagonal (pad bias only)
      if (j == qt) {
#pragma unroll
        for (int n = 0; n < 4; n++) {
          int key = k0 + n * 16 + li;
#pragma unroll
          for (int r = 0; r < 4; r++) {
            int qrow = q0 + w * 16 + g * 4 + r;
            float sv = fmaf(s[n][r], SC, pb[n]);
            if (key > qrow) sv = -1.0e9f;
            s[n][r] = sv;
          }
        }
      } else {
#pragma unroll
        for (int n = 0; n < 4; n++)
#pragma unroll
          for (int r = 0; r < 4; r++) s[n][r] = fmaf(s[n][r], SC, pb[n]);
      }
      // wave-parallel online softmax (reduce across 16 li lanes), exp2 domain
      float pm[4], corr[4], psum[4];
#pragma unroll
      for (int r = 0; r < 4; r++)
        pm[r] = fmaxf(fmaxf(s[0][r], s[1][r]), fmaxf(s[2][r], s[3][r]));
#pragma unroll
      for (int msk = 1; msk <= 8; msk <<= 1)
#pragma unroll
        for (int r = 0; r < 4; r++)
          pm[r] = fmaxf(pm[r], __shfl_xor(pm[r], msk, 64));
#pragma unroll
      for (int r = 0; r < 4; r++) {
        float mnew = fmaxf(mreg[r], pm[r]);
        corr[r] = exp2f_fast(mreg[r] - mnew);
        mreg[r] = mnew;
        float ps = 0.f;
#pragma unroll
        for (int n = 0; n < 4; n++) {
          float p = exp2f_fast(s[n][r] - mnew);
          s[n][r] = p;
          ps += p;
        }
        psum[r] = ps;
      }
#pragma unroll
      for (int msk = 1; msk <= 8; msk <<= 1)
#pragma unroll
        for (int r = 0; r < 4; r++) psum[r] += __shfl_xor(psum[r], msk, 64);
#pragma unroll
      for (int r = 0; r < 4; r++) lreg[r] = lreg[r] * corr[r] + psum[r];
      // P -> LDS (own-wave rows only; same-wave ordering via lgkmcnt)
#pragma unroll
      for (int n = 0; n < 4; n++)
#pragma unroll
        for (int r = 0; r < 4; r++)
          Ps[w * 16 + g * 4 + r][n * 16 + li] = f2b(s[n][r]);
      // rescale O
#pragma unroll
      for (int n = 0; n < 4; n++)
#pragma unroll
        for (int r = 0; r < 4; r++) o[n][r] *= corr[r];
      // PV: A = P rows (LDS), B = V frags (regs)
      bf16x8 ap0 = *(const bf16x8*)&Ps[w * 16 + li][g * 8];
      bf16x8 ap1 = *(const bf16x8*)&Ps[w * 16 + li][32 + g * 8];
      __builtin_amdgcn_s_setprio(1);
#pragma unroll
      for (int n = 0; n < 4; n++) {
        o[n] = __builtin_amdgcn_mfma_f32_16x16x32_bf16(ap0, bv0[n], o[n], 0, 0, 0);
        o[n] = __builtin_amdgcn_mfma_f32_16x16x32_bf16(ap1, bv1[n], o[n], 0, 0, 0);
      }
      __builtin_amdgcn_s_setprio(0);
      __syncthreads();  // drains prefetch (vmcnt) + Ks/Ps traffic
      cur ^= 1;
    }
  }
  // epilogue: l-normalized partial O (bf16) + per-row (m,l)
#pragma unroll
  for (int r = 0; r < 4; r++) {
    int qrl = w * 16 + g * 4 + r;
    float inv = (lreg[r] > 0.f) ? 1.0f / lreg[r] : 0.f;
#pragma unroll
    for (int n = 0; n < 4; n++)
      opart[((size_t)pidx * 64 + qrl) * 64 + n * 16 + li] = f2b(o[n][r] * inv);
    if (li == 0) {
      ml[(size_t)pidx * 128 + qrl] = mreg[r];
      ml[(size_t)pidx * 128 + 64 + qrl] = lreg[r];
    }
  }
}

// ---------------- merge the two key-split halves (static, no arrays) ------
__global__ __launch_bounds__(256) void amerge_kernel(
    const unsigned short* __restrict__ opart, const float* __restrict__ ml,
    const float* __restrict__ meanV, unsigned short* __restrict__ ao) {
  int blk = blockIdx.x;  // bh*32 + qt  (1024 blocks)
  int bh = blk >> 5, qt = blk & 31;
  int b = bh >> 3, h = bh & 7;
  int tid = threadIdx.x;
  int d = tid & 63;
  int pA = blk * 2, pB = blk * 2 + 1;
  for (int rr = tid >> 6; rr < 64; rr += 4) {
    float mA = ml[(size_t)pA * 128 + rr], lA = ml[(size_t)pA * 128 + 64 + rr];
    float mB = ml[(size_t)pB * 128 + rr], lB = ml[(size_t)pB * 128 + 64 + rr];
    float m = fmaxf(mA, mB);
    float v;
    if (m <= -1.0e8f) {
      v = meanV[bh * 64 + d];  // fully-masked row: uniform softmax = meanV
    } else {
      float acc = 0.f, wsum = 0.f;
      if (lA > 0.f) {
        float wA = exp2f_fast(mA - m) * lA;
        acc += b2f(opart[((size_t)pA * 64 + rr) * 64 + d]) * wA;
        wsum += wA;
      }
      if (lB > 0.f) {
        float wB = exp2f_fast(mB - m) * lB;
        acc += b2f(opart[((size_t)pB * 64 + rr) * 64 + d]) * wB;
        wsum += wB;
      }
      v = acc / wsum;
    }
    int qr = qt * 64 + rr;
    ao[(size_t)(b * LL + qr) * DD + h * 64 + d] = f2b(v);
  }
}

// ---- LayerNorm (+npm), bf16 input (packed loads); plain LN1 variant ----
__global__ __launch_bounds__(256) void ln_kernel(
    const unsigned short* __restrict__ in, const float* __restrict__ g,
    const float* __restrict__ bta, const float* __restrict__ npm,
    float* __restrict__ out, unsigned short* __restrict__ out_bf) {
  __shared__ float red[4];
  int row = blockIdx.x;
  int tid = threadIdx.x;
  unsigned u = ((const unsigned*)(in + (size_t)row * DD))[tid];
  float v0 = b2f((unsigned short)u), v1 = b2f((unsigned short)(u >> 16));
  int e0 = tid * 2, e1 = tid * 2 + 1;
  float s = v0 + v1;
#pragma unroll
  for (int o = 32; o > 0; o >>= 1) s += __shfl_down(s, o, 64);
  if ((tid & 63) == 0) red[tid >> 6] = s;
  __syncthreads();
  float mean = (red[0] + red[1] + red[2] + red[3]) * (1.0f / (float)DD);
  float d0 = v0 - mean, d1 = v1 - mean;
  float sq = d0 * d0 + d1 * d1;
#pragma unroll
  for (int o = 32; o > 0; o >>= 1) sq += __shfl_down(sq, o, 64);
  __syncthreads();
  if ((tid & 63) == 0) red[tid >> 6] = sq;
  __syncthreads();
  float var = (red[0] + red[1] + red[2] + red[3]) * (1.0f / (float)DD);
  float rstd = rsqrtf(var + 1e-6f);
  float m = npm[row];
  float o0 = (d0 * rstd * g[e0] + bta[e0]) * m;
  float o1 = (d1 * rstd * g[e1] + bta[e1]) * m;
  ((float2*)(out + (size_t)row * DD))[tid] = make_float2(o0, o1);
  ((unsigned*)(out_bf + (size_t)row * DD))[tid] = pk2(o0, o1);
}

// ---- LN2 fused: sum 4 bf16 K-split partials + bias + residual, LN, +tem ----
__global__ __launch_bounds__(256) void ln2f_kernel(
    const unsigned short* __restrict__ part,  // 4 partials, stride MM*DD
    const float* __restrict__ bias, const float* __restrict__ resx,
    const float* __restrict__ g, const float* __restrict__ bta,
    const float* __restrict__ npm, const float* __restrict__ tem,
    float* __restrict__ out, float* __restrict__ out2,
    unsigned short* __restrict__ out_bf) {
  __shared__ float red[4];
  int row = blockIdx.x;
  int tid = threadIdx.x;
  int e0 = tid * 2, e1 = tid * 2 + 1;
  const size_t ro = (size_t)row * DD;
  unsigned u0 = ((const unsigned*)(part + 0 * (size_t)MM * DD + ro))[tid];
  unsigned u1 = ((const unsigned*)(part + 1 * (size_t)MM * DD + ro))[tid];
  unsigned u2 = ((const unsigned*)(part + 2 * (size_t)MM * DD + ro))[tid];
  unsigned u3 = ((const unsigned*)(part + 3 * (size_t)MM * DD + ro))[tid];
  float2 rv = ((const float2*)(resx + ro))[tid];
  float v0 = b2f((unsigned short)u0) + b2f((unsigned short)u1) +
             b2f((unsigned short)u2) + b2f((unsigned short)u3) + bias[e0] +
             rv.x;
  float v1 = b2f((unsigned short)(u0 >> 16)) + b2f((unsigned short)(u1 >> 16)) +
             b2f((unsigned short)(u2 >> 16)) + b2f((unsigned short)(u3 >> 16)) +
             bias[e1] + rv.y;
  float s = v0 + v1;
#pragma unroll
  for (int o = 32; o > 0; o >>= 1) s += __shfl_down(s, o, 64);
  if ((tid & 63) == 0) red[tid >> 6] = s;
  __syncthreads();
  float mean = (red[0] + red[1] + red[2] + red[3]) * (1.0f / (float)DD);
  float d0 = v0 - mean, d1 = v1 - mean;
  float sq = d0 * d0 + d1 * d1;
#pragma unroll
  for (int o = 32; o > 0; o >>= 1) sq += __shfl_down(sq, o, 64);
  __syncthreads();
  if ((tid & 63) == 0) red[tid >> 6] = sq;
  __syncthreads();
  float var = (red[0] + red[1] + red[2] + red[3]) * (1.0f / (float)DD);
  float rstd = rsqrtf(var + 1e-6f);
  float m = npm[row];
  float o0 = (d0 * rstd * g[e0] + bta[e0]) * m;
  float o1 = (d1 * rstd * g[e1] + bta[e1]) * m;
  ((float2*)(out + ro))[tid] = make_float2(o0, o1);
  float2 tv = ((const float2*)(tem + ro))[tid];
  float a0 = o0 + tv.x, a1 = o1 + tv.y;
  ((float2*)(out2 + ro))[tid] = make_float2(a0, a1);
  ((unsigned*)(out_bf + ro))[tid] = pk2(a0, a1);
}

extern "C" void kernel_launch(void* const* d_in, const int* in_sizes, int n_in,
                              void* d_out, int out_size, void* d_ws,
                              size_t ws_size, hipStream_t stream) {
  const int* etype = (const int*)d_in[0];
  const float* etime = (const float*)d_in[1];
  const float* npm = (const float*)d_in[2];
  const float* emb = (const float*)d_in[3];
  const float* Wq = (const float*)d_in[4];
  const float* Wk = (const float*)d_in[5];
  const float* Wv = (const float*)d_in[6];
  const float* fc_w = (const float*)d_in[7];
  const float* fc_b = (const float*)d_in[8];
  const float* ln1_g = (const float*)d_in[9];
  const float* ln1_b = (const float*)d_in[10];
  const float* W1 = (const float*)d_in[11];
  const float* b1 = (const float*)d_in[12];
  const float* W2 = (const float*)d_in[13];
  const float* b2 = (const float*)d_in[14];
  const float* ln2_g = (const float*)d_in[15];
  const float* ln2_b = (const float*)d_in[16];

  float* x = (float*)d_out;
  char* ws = (char*)d_ws;
  const size_t SZF = (size_t)MM * DD * sizeof(float);
  const size_t SZB = (size_t)MM * DD * sizeof(short);
  float* tem = (float*)ws; ws += SZF;
  float* xa  = (float*)ws; ws += SZF;
  unsigned short* xab = (unsigned short*)ws; ws += SZB;
  unsigned short* xbf = (unsigned short*)ws; ws += SZB;
  unsigned short* qkv = (unsigned short*)ws; ws += (size_t)MM * 1536 * 2;
  unsigned short* vT  = (unsigned short*)ws; ws += (size_t)BB * NH * 64 * LL * 2;
  unsigned short* ao  = (unsigned short*)ws; ws += SZB;
  unsigned short* hb  = (unsigned short*)ws; ws += (size_t)MM * DINNER * 2;
  unsigned short* ybb = (unsigned short*)ws; ws += SZB;       // fc bf16 out
  unsigned short* pbuf = (unsigned short*)ws; ws += 4 * SZB;  // FFN2 partials
  unsigned short* qkvT = (unsigned short*)ws; ws += (size_t)NLAYERS * 1536 * 512 * 2;
  unsigned short* fcT  = (unsigned short*)ws; ws += (size_t)NLAYERS * 512 * 512 * 2;
  unsigned short* W1T  = (unsigned short*)ws; ws += (size_t)NLAYERS * 2048 * 512 * 2;
  unsigned short* W2T  = (unsigned short*)ws; ws += (size_t)NLAYERS * 512 * 2048 * 2;
  float* meanV = (float*)ws; ws += BB * NH * 64 * sizeof(float);
  unsigned short* opart = (unsigned short*)ws; ws += (size_t)2048 * 64 * 64 * 2;
  float* ml = (float*)ws; ws += (size_t)2048 * 128 * sizeof(float);

  init_kernel<<<MM, 512, 0, stream>>>(etype, etime, npm, emb, tem, xa, xab);

  wtrans_kernel<<<dim3(16, 16, NLAYERS), 256, 0, stream>>>(
      Wq, qkvT + 0 * 512 * 512, 512, 512, 512L * 512, 1536L * 512);
  wtrans_kernel<<<dim3(16, 16, NLAYERS), 256, 0, stream>>>(
      Wk, qkvT + 1 * 512 * 512, 512, 512, 512L * 512, 1536L * 512);
  wtrans_kernel<<<dim3(16, 16, NLAYERS), 256, 0, stream>>>(
      Wv, qkvT + 2 * 512 * 512, 512, 512, 512L * 512, 1536L * 512);
  wtrans_kernel<<<dim3(16, 16, NLAYERS), 256, 0, stream>>>(
      fc_w, fcT, 512, 512, 512L * 512, 512L * 512);
  wtrans_kernel<<<dim3(64, 16, NLAYERS), 256, 0, stream>>>(
      W1, W1T, 512, 2048, 512L * 2048, 2048L * 512);
  wtrans_kernel<<<dim3(16, 64, NLAYERS), 256, 0, stream>>>(
      W2, W2T, 2048, 512, 2048L * 512, 512L * 2048);

  for (int l = 0; l < NLAYERS; l++) {
    // QKV (grid 768)
    gemm_kernel<128, false, false, false, true><<<64 * 12, 256, 0, stream>>>(
        xab, qkvT + (size_t)l * 1536 * 512, nullptr, nullptr, 0, qkv, 1536,
        MM, 1536, 512);

    vtrans_kernel<<<dim3(32, 32), 256, 0, stream>>>(qkv, vT);
    meanv_kernel<<<BB * NH, 256, 0, stream>>>(vT, meanV);
    attn_kernel<<<2048, 256, 0, stream>>>(qkv, vT, etype, opart, ml);
    amerge_kernel<<<1024, 256, 0, stream>>>(opart, ml, meanV, ao);

    // fc: +bias +residual(xa fp32) -> bf16 ybb   (grid 512)
    gemm_kernel<64, true, true, false, true><<<128 * 4, 256, 0, stream>>>(
        ao, fcT + (size_t)l * 512 * 512, fc_b + (size_t)l * 512, xa, 512, ybb,
        512, MM, 512, 512);
    ln_kernel<<<MM, 256, 0, stream>>>(ybb, ln1_g + (size_t)l * 512,
                                      ln1_b + (size_t)l * 512, npm, x, xbf);

    // FFN1 (grid 1024)
    gemm_kernel<128, true, false, true, true><<<64 * 16, 256, 0, stream>>>(
        xbf, W1T + (size_t)l * 2048 * 512, b1 + (size_t)l * 2048, nullptr, 0,
        hb, 2048, MM, 2048, 512);
    // FFN2: 4-way split-K, bf16 partials (grid 2048)
    gemm_kernel<64, false, false, false, true, 4><<<2048, 256, 0, stream>>>(
        hb, W2T + (size_t)l * 512 * 2048, nullptr, nullptr, 0, pbuf, 512, MM,
        512, 2048);
    // LN2 fused: sum partials + b2 + residual(x) -> LN -> x, xa, xab
    ln2f_kernel<<<MM, 256, 0, stream>>>(
        pbuf, b2 + (size_t)l * 512, x, ln2_g + (size_t)l * 512,
        ln2_b + (size_t)l * 512, npm, tem, x, xa, xab);
  }
}

// Round 15
// 1032.339 us; speedup vs baseline: 1.0295x; 1.0295x over previous
//
#include <hip/hip_runtime.h>
#include <math.h>

#define BB 4
#define LL 2048
#define DD 512
#define NH 8
#define DINNER 2048
#define NLAYERS 4
#define MM (BB * LL)  // 8192

typedef __attribute__((ext_vector_type(8))) __bf16 bf16x8;
typedef __attribute__((ext_vector_type(4))) float f32x4;

__device__ __forceinline__ unsigned short f2b(float f) {
  union { __bf16 h; unsigned short u; } v;
  v.h = (__bf16)f;  // native RNE convert
  return v.u;
}
__device__ __forceinline__ float b2f(unsigned short h) {
  union { unsigned u; float f; } v; v.u = ((unsigned)h) << 16; return v.f;
}
__device__ __forceinline__ unsigned pk2(float lo, float hi) {
  return (unsigned)f2b(lo) | ((unsigned)f2b(hi) << 16);
}
__device__ __forceinline__ float exp2f_fast(float x) {
  float r; asm("v_exp_f32 %0, %1" : "=v"(r) : "v"(x)); return r;
}

__device__ __forceinline__ void gload16(const void* g, void* l) {
  __builtin_amdgcn_global_load_lds(
      (const __attribute__((address_space(1))) void*)g,
      (__attribute__((address_space(3))) void*)l, 16, 0, 0);
}

// ---- init: temporal enc + embedding gather; emits xa = emb+tem directly ----
__global__ __launch_bounds__(512) void init_kernel(
    const int* __restrict__ etype, const float* __restrict__ etime,
    const float* __restrict__ npm, const float* __restrict__ emb,
    float* __restrict__ tem, float* __restrict__ xa,
    unsigned short* __restrict__ xab) {
  int row = blockIdx.x;
  int d = threadIdx.x;
  float t = etime[row];
  float mask = npm[row];
  int dd = d & ~1;
  float pv = expf(9.210340371976184f * ((float)dd * (1.0f / (float)DD)));
  float r = t / pv;
  float val = (d & 1) ? cosf(r) : sinf(r);
  float tv = val * mask;
  tem[(size_t)row * DD + d] = tv;
  int ty = etype[row];
  float a = emb[(size_t)ty * DD + d] + tv;
  xa[(size_t)row * DD + d] = a;
  xab[(size_t)row * DD + d] = f2b(a);
}

// ---------------- weight transpose+convert: fp32 [K][N] -> bf16 [N][K] ----
__global__ __launch_bounds__(256) void wtrans_kernel(
    const float* __restrict__ in, unsigned short* __restrict__ out,
    int K, int N, long in_ls, long out_ls) {
  __shared__ float t[32][33];
  int l = blockIdx.z;
  int n0 = blockIdx.x * 32, k0 = blockIdx.y * 32;
  int tx = threadIdx.x & 31, ty = threadIdx.x >> 5;
  const float* ip = in + (size_t)l * in_ls;
  unsigned short* op = out + (size_t)l * out_ls;
#pragma unroll
  for (int r = ty; r < 32; r += 8)
    t[r][tx] = ip[(size_t)(k0 + r) * N + n0 + tx];
  __syncthreads();
#pragma unroll
  for (int r = ty; r < 32; r += 8)
    op[(size_t)(n0 + r) * K + k0 + tx] = f2b(t[tx][r]);
}

// ---- MFMA GEMM, 2-phase pipelined, XCD-chunked 1D grid (T1 swizzle) ----
// C[M,N] = A(bf16 [M,K]) @ WT(bf16 [N,K])^T.  1D grid = (M/BM)*(N/BN),
// nwg % 8 == 0. Tile variants: 128x128 (4 waves: 64x64 quadrants),
// 64x128 (4 waves: 64x32 col-strips), 64x64 (4 waves: 32x32 quadrants —
// doubles grid for narrow-N latency-bound shapes).
template <int BM, int BN, bool BIAS, bool RES, bool GELU_, bool OBF16>
__global__ __launch_bounds__(256) void gemm_kernel(
    const unsigned short* __restrict__ A, const unsigned short* __restrict__ WT,
    const float* __restrict__ bias, const float* __restrict__ res, int ldres,
    void* __restrict__ Cv, int ldc, int M, int N, int K) {
  __shared__ unsigned short As[2][BM * 32];
  __shared__ unsigned short Bs[2][BN * 32];
  constexpr int MT = (BM == 128) ? 4 : ((BN == 64) ? 2 : 4);
  constexpr int NT = (BM == 128 && BN == 128) ? 4 : 2;
  int tid = threadIdx.x;
  int w = tid >> 6, l = tid & 63;
  int li = l & 15, g = l >> 4;
  // XCD-chunked bijective remap (nwg divisible by 8)
  int nwg = gridDim.x;
  int bid = blockIdx.x;
  int wg = (bid & 7) * (nwg >> 3) + (bid >> 3);
  int gx = N / BN;
  int row0 = (wg / gx) * BM, col0 = (wg % gx) * BN;
  int wm = (BM == 128) ? (w & 1) * 64 : ((BN == 64) ? (w >> 1) * 32 : 0);
  int wnb = (BM == 128) ? (w >> 1) * 64 : ((BN == 64) ? (w & 1) * 32 : w * 32);
  f32x4 acc[MT][NT];
#pragma unroll
  for (int i = 0; i < MT; i++)
#pragma unroll
    for (int j = 0; j < NT; j++) acc[i][j] = (f32x4){0.f, 0.f, 0.f, 0.f};

  int lr = l >> 2;
  int lc = (l & 3) ^ (lr & 3);

  auto stage = [&](int bb, int kb) {
    int k0 = kb * 32;
    if (BM == 128) {
#pragma unroll
      for (int i = 0; i < 2; i++) {
        int ai = w * 2 + i;
        gload16(A + (size_t)(row0 + ai * 16 + lr) * K + k0 + lc * 8,
                &As[bb][ai * 512]);
      }
    } else {
      gload16(A + (size_t)(row0 + w * 16 + lr) * K + k0 + lc * 8,
              &As[bb][w * 512]);
    }
    if (BN == 128) {
#pragma unroll
      for (int i = 0; i < 2; i++) {
        int bi = w * 2 + i;
        gload16(WT + (size_t)(col0 + bi * 16 + lr) * K + k0 + lc * 8,
                &Bs[bb][bi * 512]);
      }
    } else {
      gload16(WT + (size_t)(col0 + w * 16 + lr) * K + k0 + lc * 8,
              &Bs[bb][w * 512]);
    }
  };

  int nk = K >> 5;
  stage(0, 0);
  __syncthreads();
  int buf = 0;
  for (int kb = 0; kb < nk; kb++) {
    if (kb + 1 < nk) stage(buf ^ 1, kb + 1);
    bf16x8 af[MT], bf_[NT];
#pragma unroll
    for (int mt = 0; mt < MT; mt++) {
      int r = wm + mt * 16 + li;
      af[mt] = *(const bf16x8*)&As[buf][r * 32 + ((g ^ (r & 3)) * 8)];
    }
#pragma unroll
    for (int nt = 0; nt < NT; nt++) {
      int r = wnb + nt * 16 + li;
      bf_[nt] = *(const bf16x8*)&Bs[buf][r * 32 + ((g ^ (r & 3)) * 8)];
    }
#pragma unroll
    for (int mt = 0; mt < MT; mt++)
#pragma unroll
      for (int nt = 0; nt < NT; nt++)
        acc[mt][nt] = __builtin_amdgcn_mfma_f32_16x16x32_bf16(
            af[mt], bf_[nt], acc[mt][nt], 0, 0, 0);
    __syncthreads();
    buf ^= 1;
  }
#pragma unroll
  for (int mt = 0; mt < MT; mt++) {
#pragma unroll
    for (int nt = 0; nt < NT; nt++) {
#pragma unroll
      for (int r = 0; r < 4; r++) {
        int row = row0 + wm + mt * 16 + g * 4 + r;
        int col = col0 + wnb + nt * 16 + li;
        float v = acc[mt][nt][r];
        if (BIAS) v += bias[col];
        if (RES) v += res[(size_t)row * ldres + col];
        if (GELU_) v = 0.5f * v * (1.0f + erff(v * 0.70710678118654752f));
        if (OBF16)
          ((unsigned short*)Cv)[(size_t)row * ldc + col] = f2b(v);
        else
          ((float*)Cv)[(size_t)row * ldc + col] = v;
      }
    }
  }
}

// ---------------- transpose v slice of qkv -> vT [bh*64+d][L] ----------
__global__ __launch_bounds__(256) void vtrans_kernel(
    const unsigned short* __restrict__ qkv, unsigned short* __restrict__ vT) {
  __shared__ unsigned short t[64][65];
  int bh = blockIdx.y;
  int b = bh >> 3, h = bh & 7;
  int l0 = blockIdx.x * 64;
  int tid = threadIdx.x;
  int c = tid & 63, p = tid >> 6;
#pragma unroll
  for (int r = p; r < 64; r += 4)
    t[r][c] = qkv[(size_t)(b * LL + l0 + r) * 1536 + 1024 + h * 64 + c];
  __syncthreads();
#pragma unroll
  for (int r = p; r < 64; r += 4)
    vT[((size_t)bh * 64 + r) * LL + l0 + c] = t[c][r];
}

// ---------------- meanV over L per (b,h,d), from vT ----------------
__global__ __launch_bounds__(256) void meanv_kernel(
    const unsigned short* __restrict__ vT, float* __restrict__ meanV) {
  __shared__ float red[256];
  int bh = blockIdx.x;
  int tid = threadIdx.x;
  int d = tid >> 2, p = tid & 3;
  const unsigned short* vp = vT + ((size_t)bh * 64 + d) * LL;
  float s = 0.f;
  for (int i = p * 512; i < p * 512 + 512; i++) s += b2f(vp[i]);
  red[tid] = s;
  __syncthreads();
  if (p == 0)
    meanV[bh * 64 + d] =
        (red[tid] + red[tid + 1] + red[tid + 2] + red[tid + 3]) *
        (1.0f / (float)LL);
}

// ---- MFMA flash attention, 2-way KEY-SPLIT (r10 proven structure) ----
__global__ __launch_bounds__(256) void attn_kernel(
    const unsigned short* __restrict__ qkv, const unsigned short* __restrict__ vT,
    const int* __restrict__ etype, unsigned short* __restrict__ opart,
    float* __restrict__ ml) {
  __shared__ unsigned short Ks[2][64 * 64];  // [buf][key*64+d], swizzled 8KB
  __shared__ unsigned short Ps[64][72];
  int hwbid = blockIdx.x;
  int work = (hwbid & 7) * 256 + (hwbid >> 3);  // XCD-chunked (bijective)
  int bh = work >> 6;
  int rem = work & 63;
  int qt = 31 - (rem >> 1);  // LPT: big q-tiles first
  int half = rem & 1;
  int h = bh & 7, b = bh >> 3;
  int q0 = qt * 64;
  int nt = qt + 1;
  int ha = (nt + 1) >> 1;  // half A gets ceil(nt/2), always nonempty
  int j0 = half ? ha : 0;
  int j1 = half ? nt : ha;
  int pidx = (bh * 32 + qt) * 2 + half;
  int tid = threadIdx.x, w = tid >> 6, l = tid & 63;
  int g = l >> 4, li = l & 15;
  const float SC = 0.125f * 1.44269504f;  // scale * log2(e)

  f32x4 o[4];
#pragma unroll
  for (int n = 0; n < 4; n++) o[n] = (f32x4){0.f, 0.f, 0.f, 0.f};
  float mreg[4], lreg[4];
#pragma unroll
  for (int r = 0; r < 4; r++) { mreg[r] = -3.0e38f; lreg[r] = 0.f; }

  if (j0 < j1) {
    const unsigned short* qrp =
        qkv + (size_t)(b * LL + q0 + w * 16 + li) * 1536 + h * 64;
    bf16x8 aq0 = *(const bf16x8*)&qrp[g * 8];
    bf16x8 aq1 = *(const bf16x8*)&qrp[32 + g * 8];

    // prologue: stage tile j0 into buf 0
#pragma unroll
    for (int e = 0; e < 2; e++) {
      int idx = e * 256 + tid;
      int r = idx >> 3;
      int src = (l & 7) ^ (r & 7);
      gload16(
          qkv + (size_t)(b * LL + j0 * 64 + r) * 1536 + 512 + h * 64 + src * 8,
          &Ks[0][(e * 256 + w * 64) * 8]);
    }
    __syncthreads();

    int cur = 0;
    for (int j = j0; j < j1; j++) {
      int k0 = j << 6;
      if (j + 1 < j1) {
#pragma unroll
        for (int e = 0; e < 2; e++) {
          int idx = e * 256 + tid;
          int r = idx >> 3;
          int src = (l & 7) ^ (r & 7);
          gload16(qkv + (size_t)(b * LL + k0 + 64 + r) * 1536 + 512 + h * 64 +
                      src * 8,
                  &Ks[cur ^ 1][(e * 256 + w * 64) * 8]);
        }
      }
      // V frags + pad bias, issued early (L2-resident)
      bf16x8 bv0[4], bv1[4];
      float pb[4];
#pragma unroll
      for (int n = 0; n < 4; n++) {
        const unsigned short* vp =
            vT + ((size_t)(bh * 64 + n * 16 + li)) * LL + k0;
        bv0[n] = *(const bf16x8*)&vp[g * 8];
        bv1[n] = *(const bf16x8*)&vp[32 + g * 8];
        pb[n] = (etype[b * LL + k0 + n * 16 + li] == 0) ? -1.0e9f : 0.f;
      }
      // S = Q K^T from swizzled LDS
      f32x4 s[4];
#pragma unroll
      for (int n = 0; n < 4; n++) {
        int rK = n * 16 + li;
        const unsigned short* kb = &Ks[cur][rK * 64];
        bf16x8 bk0 = *(const bf16x8*)&kb[(g ^ (rK & 7)) * 8];
        bf16x8 bk1 = *(const bf16x8*)&kb[((g + 4) ^ (rK & 7)) * 8];
        f32x4 a = (f32x4){0.f, 0.f, 0.f, 0.f};
        __builtin_amdgcn_s_setprio(1);
        a = __builtin_amdgcn_mfma_f32_16x16x32_bf16(aq0, bk0, a, 0, 0, 0);
        a = __builtin_amdgcn_mfma_f32_16x16x32_bf16(aq1, bk1, a, 0, 0, 0);
        __builtin_amdgcn_s_setprio(0);
        s[n] = a;
      }
      // scale + mask: fast path off-diagonal (pad bias only)
      if (j == qt) {
#pragma unroll
        for (int n = 0; n < 4; n++) {
          int key = k0 + n * 16 + li;
#pragma unroll
          for (int r = 0; r < 4; r++) {
            int qrow = q0 + w * 16 + g * 4 + r;
            float sv = fmaf(s[n][r], SC, pb[n]);
            if (key > qrow) sv = -1.0e9f;
            s[n][r] = sv;
          }
        }
      } else {
#pragma unroll
        for (int n = 0; n < 4; n++)
#pragma unroll
          for (int r = 0; r < 4; r++) s[n][r] = fmaf(s[n][r], SC, pb[n]);
      }
      // wave-parallel online softmax (reduce across 16 li lanes), exp2 domain
      float pm[4], corr[4], psum[4];
#pragma unroll
      for (int r = 0; r < 4; r++)
        pm[r] = fmaxf(fmaxf(s[0][r], s[1][r]), fmaxf(s[2][r], s[3][r]));
#pragma unroll
      for (int msk = 1; msk <= 8; msk <<= 1)
#pragma unroll
        for (int r = 0; r < 4; r++)
          pm[r] = fmaxf(pm[r], __shfl_xor(pm[r], msk, 64));
#pragma unroll
      for (int r = 0; r < 4; r++) {
        float mnew = fmaxf(mreg[r], pm[r]);
        corr[r] = exp2f_fast(mreg[r] - mnew);
        mreg[r] = mnew;
        float ps = 0.f;
#pragma unroll
        for (int n = 0; n < 4; n++) {
          float p = exp2f_fast(s[n][r] - mnew);
          s[n][r] = p;
          ps += p;
        }
        psum[r] = ps;
      }
#pragma unroll
      for (int msk = 1; msk <= 8; msk <<= 1)
#pragma unroll
        for (int r = 0; r < 4; r++) psum[r] += __shfl_xor(psum[r], msk, 64);
#pragma unroll
      for (int r = 0; r < 4; r++) lreg[r] = lreg[r] * corr[r] + psum[r];
      // P -> LDS (own-wave rows only; same-wave ordering via lgkmcnt)
#pragma unroll
      for (int n = 0; n < 4; n++)
#pragma unroll
        for (int r = 0; r < 4; r++)
          Ps[w * 16 + g * 4 + r][n * 16 + li] = f2b(s[n][r]);
      // rescale O
#pragma unroll
      for (int n = 0; n < 4; n++)
#pragma unroll
        for (int r = 0; r < 4; r++) o[n][r] *= corr[r];
      // PV: A = P rows (LDS), B = V frags (regs)
      bf16x8 ap0 = *(const bf16x8*)&Ps[w * 16 + li][g * 8];
      bf16x8 ap1 = *(const bf16x8*)&Ps[w * 16 + li][32 + g * 8];
      __builtin_amdgcn_s_setprio(1);
#pragma unroll
      for (int n = 0; n < 4; n++) {
        o[n] = __builtin_amdgcn_mfma_f32_16x16x32_bf16(ap0, bv0[n], o[n], 0, 0, 0);
        o[n] = __builtin_amdgcn_mfma_f32_16x16x32_bf16(ap1, bv1[n], o[n], 0, 0, 0);
      }
      __builtin_amdgcn_s_setprio(0);
      __syncthreads();  // drains prefetch (vmcnt) + Ks/Ps traffic
      cur ^= 1;
    }
  }
  // epilogue: l-normalized partial O (bf16) + per-row (m,l)
#pragma unroll
  for (int r = 0; r < 4; r++) {
    int qrl = w * 16 + g * 4 + r;
    float inv = (lreg[r] > 0.f) ? 1.0f / lreg[r] : 0.f;
#pragma unroll
    for (int n = 0; n < 4; n++)
      opart[((size_t)pidx * 64 + qrl) * 64 + n * 16 + li] = f2b(o[n][r] * inv);
    if (li == 0) {
      ml[(size_t)pidx * 128 + qrl] = mreg[r];
      ml[(size_t)pidx * 128 + 64 + qrl] = lreg[r];
    }
  }
}

// ---------------- merge the two key-split halves (static, no arrays) ------
__global__ __launch_bounds__(256) void amerge_kernel(
    const unsigned short* __restrict__ opart, const float* __restrict__ ml,
    const float* __restrict__ meanV, unsigned short* __restrict__ ao) {
  int blk = blockIdx.x;  // bh*32 + qt  (1024 blocks)
  int bh = blk >> 5, qt = blk & 31;
  int b = bh >> 3, h = bh & 7;
  int tid = threadIdx.x;
  int d = tid & 63;
  int pA = blk * 2, pB = blk * 2 + 1;
  for (int rr = tid >> 6; rr < 64; rr += 4) {
    float mA = ml[(size_t)pA * 128 + rr], lA = ml[(size_t)pA * 128 + 64 + rr];
    float mB = ml[(size_t)pB * 128 + rr], lB = ml[(size_t)pB * 128 + 64 + rr];
    float m = fmaxf(mA, mB);
    float v;
    if (m <= -1.0e8f) {
      v = meanV[bh * 64 + d];  // fully-masked row: uniform softmax = meanV
    } else {
      float acc = 0.f, wsum = 0.f;
      if (lA > 0.f) {
        float wA = exp2f_fast(mA - m) * lA;
        acc += b2f(opart[((size_t)pA * 64 + rr) * 64 + d]) * wA;
        wsum += wA;
      }
      if (lB > 0.f) {
        float wB = exp2f_fast(mB - m) * lB;
        acc += b2f(opart[((size_t)pB * 64 + rr) * 64 + d]) * wB;
        wsum += wB;
      }
      v = acc / wsum;
    }
    int qr = qt * 64 + rr;
    ao[(size_t)(b * LL + qr) * DD + h * 64 + d] = f2b(v);
  }
}

// ---- LayerNorm (+npm), bf16 input (packed loads); ADDTEM emits xa=x+tem ----
template <bool ADDTEM>
__global__ __launch_bounds__(256) void ln_kernel(
    const unsigned short* __restrict__ in, const float* __restrict__ g,
    const float* __restrict__ bta, const float* __restrict__ npm,
    const float* __restrict__ tem, float* __restrict__ out,
    float* __restrict__ out2, unsigned short* __restrict__ out_bf) {
  __shared__ float red[4];
  int row = blockIdx.x;
  int tid = threadIdx.x;
  unsigned u = ((const unsigned*)(in + (size_t)row * DD))[tid];
  float v0 = b2f((unsigned short)u), v1 = b2f((unsigned short)(u >> 16));
  int e0 = tid * 2, e1 = tid * 2 + 1;
  float s = v0 + v1;
#pragma unroll
  for (int o = 32; o > 0; o >>= 1) s += __shfl_down(s, o, 64);
  if ((tid & 63) == 0) red[tid >> 6] = s;
  __syncthreads();
  float mean = (red[0] + red[1] + red[2] + red[3]) * (1.0f / (float)DD);
  float d0 = v0 - mean, d1 = v1 - mean;
  float sq = d0 * d0 + d1 * d1;
#pragma unroll
  for (int o = 32; o > 0; o >>= 1) sq += __shfl_down(sq, o, 64);
  __syncthreads();
  if ((tid & 63) == 0) red[tid >> 6] = sq;
  __syncthreads();
  float var = (red[0] + red[1] + red[2] + red[3]) * (1.0f / (float)DD);
  float rstd = rsqrtf(var + 1e-6f);
  float m = npm[row];
  float o0 = (d0 * rstd * g[e0] + bta[e0]) * m;
  float o1 = (d1 * rstd * g[e1] + bta[e1]) * m;
  ((float2*)(out + (size_t)row * DD))[tid] = make_float2(o0, o1);
  if (ADDTEM) {
    float2 tv = ((const float2*)(tem + (size_t)row * DD))[tid];
    float a0 = o0 + tv.x, a1 = o1 + tv.y;
    ((float2*)(out2 + (size_t)row * DD))[tid] = make_float2(a0, a1);
    ((unsigned*)(out_bf + (size_t)row * DD))[tid] = pk2(a0, a1);
  } else {
    ((unsigned*)(out_bf + (size_t)row * DD))[tid] = pk2(o0, o1);
  }
}

extern "C" void kernel_launch(void* const* d_in, const int* in_sizes, int n_in,
                              void* d_out, int out_size, void* d_ws,
                              size_t ws_size, hipStream_t stream) {
  const int* etype = (const int*)d_in[0];
  const float* etime = (const float*)d_in[1];
  const float* npm = (const float*)d_in[2];
  const float* emb = (const float*)d_in[3];
  const float* Wq = (const float*)d_in[4];
  const float* Wk = (const float*)d_in[5];
  const float* Wv = (const float*)d_in[6];
  const float* fc_w = (const float*)d_in[7];
  const float* fc_b = (const float*)d_in[8];
  const float* ln1_g = (const float*)d_in[9];
  const float* ln1_b = (const float*)d_in[10];
  const float* W1 = (const float*)d_in[11];
  const float* b1 = (const float*)d_in[12];
  const float* W2 = (const float*)d_in[13];
  const float* b2 = (const float*)d_in[14];
  const float* ln2_g = (const float*)d_in[15];
  const float* ln2_b = (const float*)d_in[16];

  float* x = (float*)d_out;
  char* ws = (char*)d_ws;
  const size_t SZF = (size_t)MM * DD * sizeof(float);
  const size_t SZB = (size_t)MM * DD * sizeof(short);
  float* tem = (float*)ws; ws += SZF;
  float* xa  = (float*)ws; ws += SZF;
  unsigned short* xab = (unsigned short*)ws; ws += SZB;
  unsigned short* xbf = (unsigned short*)ws; ws += SZB;
  unsigned short* qkv = (unsigned short*)ws; ws += (size_t)MM * 1536 * 2;
  unsigned short* vT  = (unsigned short*)ws; ws += (size_t)BB * NH * 64 * LL * 2;
  unsigned short* ao  = (unsigned short*)ws; ws += SZB;
  unsigned short* hb  = (unsigned short*)ws; ws += (size_t)MM * DINNER * 2;
  unsigned short* ybb = (unsigned short*)ws; ws += SZB;  // bf16 LN input
  unsigned short* qkvT = (unsigned short*)ws; ws += (size_t)NLAYERS * 1536 * 512 * 2;
  unsigned short* fcT  = (unsigned short*)ws; ws += (size_t)NLAYERS * 512 * 512 * 2;
  unsigned short* W1T  = (unsigned short*)ws; ws += (size_t)NLAYERS * 2048 * 512 * 2;
  unsigned short* W2T  = (unsigned short*)ws; ws += (size_t)NLAYERS * 512 * 2048 * 2;
  float* meanV = (float*)ws; ws += BB * NH * 64 * sizeof(float);
  unsigned short* opart = (unsigned short*)ws; ws += (size_t)2048 * 64 * 64 * 2;
  float* ml = (float*)ws; ws += (size_t)2048 * 128 * sizeof(float);

  init_kernel<<<MM, 512, 0, stream>>>(etype, etime, npm, emb, tem, xa, xab);

  wtrans_kernel<<<dim3(16, 16, NLAYERS), 256, 0, stream>>>(
      Wq, qkvT + 0 * 512 * 512, 512, 512, 512L * 512, 1536L * 512);
  wtrans_kernel<<<dim3(16, 16, NLAYERS), 256, 0, stream>>>(
      Wk, qkvT + 1 * 512 * 512, 512, 512, 512L * 512, 1536L * 512);
  wtrans_kernel<<<dim3(16, 16, NLAYERS), 256, 0, stream>>>(
      Wv, qkvT + 2 * 512 * 512, 512, 512, 512L * 512, 1536L * 512);
  wtrans_kernel<<<dim3(16, 16, NLAYERS), 256, 0, stream>>>(
      fc_w, fcT, 512, 512, 512L * 512, 512L * 512);
  wtrans_kernel<<<dim3(64, 16, NLAYERS), 256, 0, stream>>>(
      W1, W1T, 512, 2048, 512L * 2048, 2048L * 512);
  wtrans_kernel<<<dim3(16, 64, NLAYERS), 256, 0, stream>>>(
      W2, W2T, 2048, 512, 2048L * 512, 512L * 2048);

  for (int l = 0; l < NLAYERS; l++) {
    // QKV (grid 768, 128x128 tiles)
    gemm_kernel<128, 128, false, false, false, true><<<64 * 12, 256, 0, stream>>>(
        xab, qkvT + (size_t)l * 1536 * 512, nullptr, nullptr, 0, qkv, 1536,
        MM, 1536, 512);

    vtrans_kernel<<<dim3(32, 32), 256, 0, stream>>>(qkv, vT);
    meanv_kernel<<<BB * NH, 256, 0, stream>>>(vT, meanV);
    attn_kernel<<<2048, 256, 0, stream>>>(qkv, vT, etype, opart, ml);
    amerge_kernel<<<1024, 256, 0, stream>>>(opart, ml, meanV, ao);

    // fc: +bias +residual(xa fp32) -> bf16 ybb   (grid 1024, 64x64 tiles)
    gemm_kernel<64, 64, true, true, false, true><<<128 * 8, 256, 0, stream>>>(
        ao, fcT + (size_t)l * 512 * 512, fc_b + (size_t)l * 512, xa, 512, ybb,
        512, MM, 512, 512);
    ln_kernel<false><<<MM, 256, 0, stream>>>(
        ybb, ln1_g + (size_t)l * 512, ln1_b + (size_t)l * 512, npm, nullptr, x,
        nullptr, xbf);

    // FFN1 (grid 1024, 128x128 tiles)
    gemm_kernel<128, 128, true, false, true, true><<<64 * 16, 256, 0, stream>>>(
        xbf, W1T + (size_t)l * 2048 * 512, b1 + (size_t)l * 2048, nullptr, 0,
        hb, 2048, MM, 2048, 512);
    // FFN2: +bias +residual(x fp32) -> bf16 ybb  (grid 1024, 64x64 tiles)
    gemm_kernel<64, 64, true, true, false, true><<<128 * 8, 256, 0, stream>>>(
        hb, W2T + (size_t)l * 512 * 2048, b2 + (size_t)l * 512, x, 512, ybb,
        512, MM, 512, 2048);
    ln_kernel<true><<<MM, 256, 0, stream>>>(
        ybb, ln2_g + (size_t)l * 512, ln2_b + (size_t)l * 512, npm, tem, x, xa,
        xab);
  }
}

// Round 16
// 968.713 us; speedup vs baseline: 1.0972x; 1.0657x over previous
//
#include <hip/hip_runtime.h>
#include <math.h>

#define BB 4
#define LL 2048
#define DD 512
#define NH 8
#define DINNER 2048
#define NLAYERS 4
#define MM (BB * LL)  // 8192

typedef __attribute__((ext_vector_type(8))) __bf16 bf16x8;
typedef __attribute__((ext_vector_type(4))) float f32x4;
typedef __attribute__((ext_vector_type(4))) unsigned short us4;

__device__ __forceinline__ unsigned short f2b(float f) {
  union { __bf16 h; unsigned short u; } v;
  v.h = (__bf16)f;  // native RNE convert
  return v.u;
}
__device__ __forceinline__ float b2f(unsigned short h) {
  union { unsigned u; float f; } v; v.u = ((unsigned)h) << 16; return v.f;
}
__device__ __forceinline__ unsigned pk2(float lo, float hi) {
  return (unsigned)f2b(lo) | ((unsigned)f2b(hi) << 16);
}
__device__ __forceinline__ float exp2f_fast(float x) {
  float r; asm("v_exp_f32 %0, %1" : "=v"(r) : "v"(x)); return r;
}

__device__ __forceinline__ void gload16(const void* g, void* l) {
  __builtin_amdgcn_global_load_lds(
      (const __attribute__((address_space(1))) void*)g,
      (__attribute__((address_space(3))) void*)l, 16, 0, 0);
}

// ---- init: temporal enc + embedding gather; emits xa = emb+tem directly ----
__global__ __launch_bounds__(512) void init_kernel(
    const int* __restrict__ etype, const float* __restrict__ etime,
    const float* __restrict__ npm, const float* __restrict__ emb,
    float* __restrict__ tem, float* __restrict__ xa,
    unsigned short* __restrict__ xab) {
  int row = blockIdx.x;
  int d = threadIdx.x;
  float t = etime[row];
  float mask = npm[row];
  int dd = d & ~1;
  float pv = expf(9.210340371976184f * ((float)dd * (1.0f / (float)DD)));
  float r = t / pv;
  float val = (d & 1) ? cosf(r) : sinf(r);
  float tv = val * mask;
  tem[(size_t)row * DD + d] = tv;
  int ty = etype[row];
  float a = emb[(size_t)ty * DD + d] + tv;
  xa[(size_t)row * DD + d] = a;
  xab[(size_t)row * DD + d] = f2b(a);
}

// ---------------- weight transpose+convert: fp32 [K][N] -> bf16 [N][K] ----
__global__ __launch_bounds__(256) void wtrans_kernel(
    const float* __restrict__ in, unsigned short* __restrict__ out,
    int K, int N, long in_ls, long out_ls) {
  __shared__ float t[32][33];
  int l = blockIdx.z;
  int n0 = blockIdx.x * 32, k0 = blockIdx.y * 32;
  int tx = threadIdx.x & 31, ty = threadIdx.x >> 5;
  const float* ip = in + (size_t)l * in_ls;
  unsigned short* op = out + (size_t)l * out_ls;
#pragma unroll
  for (int r = ty; r < 32; r += 8)
    t[r][tx] = ip[(size_t)(k0 + r) * N + n0 + tx];
  __syncthreads();
#pragma unroll
  for (int r = ty; r < 32; r += 8)
    op[(size_t)(n0 + r) * K + k0 + tx] = f2b(t[tx][r]);
}

// ---- MFMA GEMM, 2-phase pipelined, XCD-chunked 1D grid (T1 swizzle) ----
// C[M,N] = A(bf16 [M,K]) @ WT(bf16 [N,K])^T.  1D grid = (M/BM)*(N/BN),
// nwg % 8 == 0. Tile variants: 128x128, 64x128, 64x64.
template <int BM, int BN, bool BIAS, bool RES, bool GELU_, bool OBF16>
__global__ __launch_bounds__(256) void gemm_kernel(
    const unsigned short* __restrict__ A, const unsigned short* __restrict__ WT,
    const float* __restrict__ bias, const float* __restrict__ res, int ldres,
    void* __restrict__ Cv, int ldc, int M, int N, int K) {
  __shared__ unsigned short As[2][BM * 32];
  __shared__ unsigned short Bs[2][BN * 32];
  constexpr int MT = (BM == 128) ? 4 : ((BN == 64) ? 2 : 4);
  constexpr int NT = (BM == 128 && BN == 128) ? 4 : 2;
  int tid = threadIdx.x;
  int w = tid >> 6, l = tid & 63;
  int li = l & 15, g = l >> 4;
  // XCD-chunked bijective remap (nwg divisible by 8)
  int nwg = gridDim.x;
  int bid = blockIdx.x;
  int wg = (bid & 7) * (nwg >> 3) + (bid >> 3);
  int gx = N / BN;
  int row0 = (wg / gx) * BM, col0 = (wg % gx) * BN;
  int wm = (BM == 128) ? (w & 1) * 64 : ((BN == 64) ? (w >> 1) * 32 : 0);
  int wnb = (BM == 128) ? (w >> 1) * 64 : ((BN == 64) ? (w & 1) * 32 : w * 32);
  f32x4 acc[MT][NT];
#pragma unroll
  for (int i = 0; i < MT; i++)
#pragma unroll
    for (int j = 0; j < NT; j++) acc[i][j] = (f32x4){0.f, 0.f, 0.f, 0.f};

  int lr = l >> 2;
  int lc = (l & 3) ^ (lr & 3);

  auto stage = [&](int bb, int kb) {
    int k0 = kb * 32;
    if (BM == 128) {
#pragma unroll
      for (int i = 0; i < 2; i++) {
        int ai = w * 2 + i;
        gload16(A + (size_t)(row0 + ai * 16 + lr) * K + k0 + lc * 8,
                &As[bb][ai * 512]);
      }
    } else {
      gload16(A + (size_t)(row0 + w * 16 + lr) * K + k0 + lc * 8,
              &As[bb][w * 512]);
    }
    if (BN == 128) {
#pragma unroll
      for (int i = 0; i < 2; i++) {
        int bi = w * 2 + i;
        gload16(WT + (size_t)(col0 + bi * 16 + lr) * K + k0 + lc * 8,
                &Bs[bb][bi * 512]);
      }
    } else {
      gload16(WT + (size_t)(col0 + w * 16 + lr) * K + k0 + lc * 8,
              &Bs[bb][w * 512]);
    }
  };

  int nk = K >> 5;
  stage(0, 0);
  __syncthreads();
  int buf = 0;
  for (int kb = 0; kb < nk; kb++) {
    if (kb + 1 < nk) stage(buf ^ 1, kb + 1);
    bf16x8 af[MT], bf_[NT];
#pragma unroll
    for (int mt = 0; mt < MT; mt++) {
      int r = wm + mt * 16 + li;
      af[mt] = *(const bf16x8*)&As[buf][r * 32 + ((g ^ (r & 3)) * 8)];
    }
#pragma unroll
    for (int nt = 0; nt < NT; nt++) {
      int r = wnb + nt * 16 + li;
      bf_[nt] = *(const bf16x8*)&Bs[buf][r * 32 + ((g ^ (r & 3)) * 8)];
    }
#pragma unroll
    for (int mt = 0; mt < MT; mt++)
#pragma unroll
      for (int nt = 0; nt < NT; nt++)
        acc[mt][nt] = __builtin_amdgcn_mfma_f32_16x16x32_bf16(
            af[mt], bf_[nt], acc[mt][nt], 0, 0, 0);
    __syncthreads();
    buf ^= 1;
  }
#pragma unroll
  for (int mt = 0; mt < MT; mt++) {
#pragma unroll
    for (int nt = 0; nt < NT; nt++) {
#pragma unroll
      for (int r = 0; r < 4; r++) {
        int row = row0 + wm + mt * 16 + g * 4 + r;
        int col = col0 + wnb + nt * 16 + li;
        float v = acc[mt][nt][r];
        if (BIAS) v += bias[col];
        if (RES) v += res[(size_t)row * ldres + col];
        if (GELU_) v = 0.5f * v * (1.0f + erff(v * 0.70710678118654752f));
        if (OBF16)
          ((unsigned short*)Cv)[(size_t)row * ldc + col] = f2b(v);
        else
          ((float*)Cv)[(size_t)row * ldc + col] = v;
      }
    }
  }
}

// ---------------- transpose v slice of qkv -> vT [bh*64+d][L] ----------
__global__ __launch_bounds__(256) void vtrans_kernel(
    const unsigned short* __restrict__ qkv, unsigned short* __restrict__ vT) {
  __shared__ unsigned short t[64][65];
  int bh = blockIdx.y;
  int b = bh >> 3, h = bh & 7;
  int l0 = blockIdx.x * 64;
  int tid = threadIdx.x;
  int c = tid & 63, p = tid >> 6;
#pragma unroll
  for (int r = p; r < 64; r += 4)
    t[r][c] = qkv[(size_t)(b * LL + l0 + r) * 1536 + 1024 + h * 64 + c];
  __syncthreads();
#pragma unroll
  for (int r = p; r < 64; r += 4)
    vT[((size_t)bh * 64 + r) * LL + l0 + c] = t[c][r];
}

// ---- meanV partial sums: grid 256 = 32 bh x 8 L-chunks, vectorized ----
__global__ __launch_bounds__(256) void meanv_kernel(
    const unsigned short* __restrict__ vT, float* __restrict__ meanVpart) {
  __shared__ float red[4][64];
  int chunk = blockIdx.x & 7;
  int bh = blockIdx.x >> 3;
  int tid = threadIdx.x;
  int d = tid & 63, p = tid >> 6;
  const unsigned short* vp =
      vT + ((size_t)bh * 64 + d) * LL + chunk * 256 + p * 64;
  float s = 0.f;
#pragma unroll
  for (int i = 0; i < 16; i++) {
    us4 v = *(const us4*)&vp[i * 4];
    s += b2f(v[0]) + b2f(v[1]) + b2f(v[2]) + b2f(v[3]);
  }
  red[p][d] = s;
  __syncthreads();
  if (p == 0)
    meanVpart[(size_t)blockIdx.x * 64 + d] =
        red[0][d] + red[1][d] + red[2][d] + red[3][d];
}

// ---- MFMA flash attention, 2-way KEY-SPLIT (r10 proven structure) ----
__global__ __launch_bounds__(256) void attn_kernel(
    const unsigned short* __restrict__ qkv, const unsigned short* __restrict__ vT,
    const int* __restrict__ etype, unsigned short* __restrict__ opart,
    float* __restrict__ ml) {
  __shared__ unsigned short Ks[2][64 * 64];  // [buf][key*64+d], swizzled 8KB
  __shared__ unsigned short Ps[64][72];
  int hwbid = blockIdx.x;
  int work = (hwbid & 7) * 256 + (hwbid >> 3);  // XCD-chunked (bijective)
  int bh = work >> 6;
  int rem = work & 63;
  int qt = 31 - (rem >> 1);  // LPT: big q-tiles first
  int half = rem & 1;
  int h = bh & 7, b = bh >> 3;
  int q0 = qt * 64;
  int nt = qt + 1;
  int ha = (nt + 1) >> 1;  // half A gets ceil(nt/2), always nonempty
  int j0 = half ? ha : 0;
  int j1 = half ? nt : ha;
  int pidx = (bh * 32 + qt) * 2 + half;
  int tid = threadIdx.x, w = tid >> 6, l = tid & 63;
  int g = l >> 4, li = l & 15;
  const float SC = 0.125f * 1.44269504f;  // scale * log2(e)

  f32x4 o[4];
#pragma unroll
  for (int n = 0; n < 4; n++) o[n] = (f32x4){0.f, 0.f, 0.f, 0.f};
  float mreg[4], lreg[4];
#pragma unroll
  for (int r = 0; r < 4; r++) { mreg[r] = -3.0e38f; lreg[r] = 0.f; }

  if (j0 < j1) {
    const unsigned short* qrp =
        qkv + (size_t)(b * LL + q0 + w * 16 + li) * 1536 + h * 64;
    bf16x8 aq0 = *(const bf16x8*)&qrp[g * 8];
    bf16x8 aq1 = *(const bf16x8*)&qrp[32 + g * 8];

    // prologue: stage tile j0 into buf 0
#pragma unroll
    for (int e = 0; e < 2; e++) {
      int idx = e * 256 + tid;
      int r = idx >> 3;
      int src = (l & 7) ^ (r & 7);
      gload16(
          qkv + (size_t)(b * LL + j0 * 64 + r) * 1536 + 512 + h * 64 + src * 8,
          &Ks[0][(e * 256 + w * 64) * 8]);
    }
    __syncthreads();

    int cur = 0;
    for (int j = j0; j < j1; j++) {
      int k0 = j << 6;
      if (j + 1 < j1) {
#pragma unroll
        for (int e = 0; e < 2; e++) {
          int idx = e * 256 + tid;
          int r = idx >> 3;
          int src = (l & 7) ^ (r & 7);
          gload16(qkv + (size_t)(b * LL + k0 + 64 + r) * 1536 + 512 + h * 64 +
                      src * 8,
                  &Ks[cur ^ 1][(e * 256 + w * 64) * 8]);
        }
      }
      // V frags + pad bias, issued early (L2-resident)
      bf16x8 bv0[4], bv1[4];
      float pb[4];
#pragma unroll
      for (int n = 0; n < 4; n++) {
        const unsigned short* vp =
            vT + ((size_t)(bh * 64 + n * 16 + li)) * LL + k0;
        bv0[n] = *(const bf16x8*)&vp[g * 8];
        bv1[n] = *(const bf16x8*)&vp[32 + g * 8];
        pb[n] = (etype[b * LL + k0 + n * 16 + li] == 0) ? -1.0e9f : 0.f;
      }
      // S = Q K^T from swizzled LDS
      f32x4 s[4];
#pragma unroll
      for (int n = 0; n < 4; n++) {
        int rK = n * 16 + li;
        const unsigned short* kb = &Ks[cur][rK * 64];
        bf16x8 bk0 = *(const bf16x8*)&kb[(g ^ (rK & 7)) * 8];
        bf16x8 bk1 = *(const bf16x8*)&kb[((g + 4) ^ (rK & 7)) * 8];
        f32x4 a = (f32x4){0.f, 0.f, 0.f, 0.f};
        __builtin_amdgcn_s_setprio(1);
        a = __builtin_amdgcn_mfma_f32_16x16x32_bf16(aq0, bk0, a, 0, 0, 0);
        a = __builtin_amdgcn_mfma_f32_16x16x32_bf16(aq1, bk1, a, 0, 0, 0);
        __builtin_amdgcn_s_setprio(0);
        s[n] = a;
      }
      // scale + mask: fast path off-diagonal (pad bias only)
      if (j == qt) {
#pragma unroll
        for (int n = 0; n < 4; n++) {
          int key = k0 + n * 16 + li;
#pragma unroll
          for (int r = 0; r < 4; r++) {
            int qrow = q0 + w * 16 + g * 4 + r;
            float sv = fmaf(s[n][r], SC, pb[n]);
            if (key > qrow) sv = -1.0e9f;
            s[n][r] = sv;
          }
        }
      } else {
#pragma unroll
        for (int n = 0; n < 4; n++)
#pragma unroll
          for (int r = 0; r < 4; r++) s[n][r] = fmaf(s[n][r], SC, pb[n]);
      }
      // wave-parallel online softmax (reduce across 16 li lanes), exp2 domain
      float pm[4], corr[4], psum[4];
#pragma unroll
      for (int r = 0; r < 4; r++)
        pm[r] = fmaxf(fmaxf(s[0][r], s[1][r]), fmaxf(s[2][r], s[3][r]));
#pragma unroll
      for (int msk = 1; msk <= 8; msk <<= 1)
#pragma unroll
        for (int r = 0; r < 4; r++)
          pm[r] = fmaxf(pm[r], __shfl_xor(pm[r], msk, 64));
#pragma unroll
      for (int r = 0; r < 4; r++) {
        float mnew = fmaxf(mreg[r], pm[r]);
        corr[r] = exp2f_fast(mreg[r] - mnew);
        mreg[r] = mnew;
        float ps = 0.f;
#pragma unroll
        for (int n = 0; n < 4; n++) {
          float p = exp2f_fast(s[n][r] - mnew);
          s[n][r] = p;
          ps += p;
        }
        psum[r] = ps;
      }
#pragma unroll
      for (int msk = 1; msk <= 8; msk <<= 1)
#pragma unroll
        for (int r = 0; r < 4; r++) psum[r] += __shfl_xor(psum[r], msk, 64);
#pragma unroll
      for (int r = 0; r < 4; r++) lreg[r] = lreg[r] * corr[r] + psum[r];
      // P -> LDS (own-wave rows only; same-wave ordering via lgkmcnt)
#pragma unroll
      for (int n = 0; n < 4; n++)
#pragma unroll
        for (int r = 0; r < 4; r++)
          Ps[w * 16 + g * 4 + r][n * 16 + li] = f2b(s[n][r]);
      // rescale O
#pragma unroll
      for (int n = 0; n < 4; n++)
#pragma unroll
        for (int r = 0; r < 4; r++) o[n][r] *= corr[r];
      // PV: A = P rows (LDS), B = V frags (regs)
      bf16x8 ap0 = *(const bf16x8*)&Ps[w * 16 + li][g * 8];
      bf16x8 ap1 = *(const bf16x8*)&Ps[w * 16 + li][32 + g * 8];
      __builtin_amdgcn_s_setprio(1);
#pragma unroll
      for (int n = 0; n < 4; n++) {
        o[n] = __builtin_amdgcn_mfma_f32_16x16x32_bf16(ap0, bv0[n], o[n], 0, 0, 0);
        o[n] = __builtin_amdgcn_mfma_f32_16x16x32_bf16(ap1, bv1[n], o[n], 0, 0, 0);
      }
      __builtin_amdgcn_s_setprio(0);
      __syncthreads();  // drains prefetch (vmcnt) + Ks/Ps traffic
      cur ^= 1;
    }
  }
  // epilogue: l-normalized partial O (bf16) + per-row (m,l)
#pragma unroll
  for (int r = 0; r < 4; r++) {
    int qrl = w * 16 + g * 4 + r;
    float inv = (lreg[r] > 0.f) ? 1.0f / lreg[r] : 0.f;
#pragma unroll
    for (int n = 0; n < 4; n++)
      opart[((size_t)pidx * 64 + qrl) * 64 + n * 16 + li] = f2b(o[n][r] * inv);
    if (li == 0) {
      ml[(size_t)pidx * 128 + qrl] = mreg[r];
      ml[(size_t)pidx * 128 + 64 + qrl] = lreg[r];
    }
  }
}

// ---- merge the two key-split halves (packed 2-wide, static) ----
__global__ __launch_bounds__(256) void amerge_kernel(
    const unsigned short* __restrict__ opart, const float* __restrict__ ml,
    const float* __restrict__ meanVpart, unsigned short* __restrict__ ao) {
  int blk = blockIdx.x;  // bh*32 + qt  (1024 blocks)
  int bh = blk >> 5, qt = blk & 31;
  int b = bh >> 3, h = bh & 7;
  int tid = threadIdx.x;
  int d2 = (tid & 31) * 2;
  int pA = blk * 2, pB = blk * 2 + 1;
  for (int rr = tid >> 5; rr < 64; rr += 8) {
    float mA = ml[(size_t)pA * 128 + rr], lA = ml[(size_t)pA * 128 + 64 + rr];
    float mB = ml[(size_t)pB * 128 + rr], lB = ml[(size_t)pB * 128 + 64 + rr];
    float m = fmaxf(mA, mB);
    float v0, v1;
    if (m <= -1.0e8f) {
      // fully-masked row: uniform softmax over all keys = meanV
      float s0 = 0.f, s1 = 0.f;
#pragma unroll
      for (int cc = 0; cc < 8; cc++) {
        s0 += meanVpart[((size_t)bh * 8 + cc) * 64 + d2];
        s1 += meanVpart[((size_t)bh * 8 + cc) * 64 + d2 + 1];
      }
      v0 = s0 * (1.0f / (float)LL);
      v1 = s1 * (1.0f / (float)LL);
    } else {
      float a0 = 0.f, a1 = 0.f, wsum = 0.f;
      if (lA > 0.f) {
        float wA = exp2f_fast(mA - m) * lA;
        unsigned ua = *(const unsigned*)&opart[((size_t)pA * 64 + rr) * 64 + d2];
        a0 += b2f((unsigned short)ua) * wA;
        a1 += b2f((unsigned short)(ua >> 16)) * wA;
        wsum += wA;
      }
      if (lB > 0.f) {
        float wB = exp2f_fast(mB - m) * lB;
        unsigned ub = *(const unsigned*)&opart[((size_t)pB * 64 + rr) * 64 + d2];
        a0 += b2f((unsigned short)ub) * wB;
        a1 += b2f((unsigned short)(ub >> 16)) * wB;
        wsum += wB;
      }
      float inv = 1.0f / wsum;
      v0 = a0 * inv;
      v1 = a1 * inv;
    }
    int qr = qt * 64 + rr;
    *(unsigned*)&ao[(size_t)(b * LL + qr) * DD + h * 64 + d2] = pk2(v0, v1);
  }
}

// ---- LayerNorm (+npm), bf16 input (packed loads); ADDTEM emits xa=x+tem ----
template <bool ADDTEM>
__global__ __launch_bounds__(256) void ln_kernel(
    const unsigned short* __restrict__ in, const float* __restrict__ g,
    const float* __restrict__ bta, const float* __restrict__ npm,
    const float* __restrict__ tem, float* __restrict__ out,
    float* __restrict__ out2, unsigned short* __restrict__ out_bf) {
  __shared__ float red[4];
  int row = blockIdx.x;
  int tid = threadIdx.x;
  unsigned u = ((const unsigned*)(in + (size_t)row * DD))[tid];
  float v0 = b2f((unsigned short)u), v1 = b2f((unsigned short)(u >> 16));
  int e0 = tid * 2, e1 = tid * 2 + 1;
  float s = v0 + v1;
#pragma unroll
  for (int o = 32; o > 0; o >>= 1) s += __shfl_down(s, o, 64);
  if ((tid & 63) == 0) red[tid >> 6] = s;
  __syncthreads();
  float mean = (red[0] + red[1] + red[2] + red[3]) * (1.0f / (float)DD);
  float d0 = v0 - mean, d1 = v1 - mean;
  float sq = d0 * d0 + d1 * d1;
#pragma unroll
  for (int o = 32; o > 0; o >>= 1) sq += __shfl_down(sq, o, 64);
  __syncthreads();
  if ((tid & 63) == 0) red[tid >> 6] = sq;
  __syncthreads();
  float var = (red[0] + red[1] + red[2] + red[3]) * (1.0f / (float)DD);
  float rstd = rsqrtf(var + 1e-6f);
  float m = npm[row];
  float o0 = (d0 * rstd * g[e0] + bta[e0]) * m;
  float o1 = (d1 * rstd * g[e1] + bta[e1]) * m;
  ((float2*)(out + (size_t)row * DD))[tid] = make_float2(o0, o1);
  if (ADDTEM) {
    float2 tv = ((const float2*)(tem + (size_t)row * DD))[tid];
    float a0 = o0 + tv.x, a1 = o1 + tv.y;
    ((float2*)(out2 + (size_t)row * DD))[tid] = make_float2(a0, a1);
    ((unsigned*)(out_bf + (size_t)row * DD))[tid] = pk2(a0, a1);
  } else {
    ((unsigned*)(out_bf + (size_t)row * DD))[tid] = pk2(o0, o1);
  }
}

extern "C" void kernel_launch(void* const* d_in, const int* in_sizes, int n_in,
                              void* d_out, int out_size, void* d_ws,
                              size_t ws_size, hipStream_t stream) {
  const int* etype = (const int*)d_in[0];
  const float* etime = (const float*)d_in[1];
  const float* npm = (const float*)d_in[2];
  const float* emb = (const float*)d_in[3];
  const float* Wq = (const float*)d_in[4];
  const float* Wk = (const float*)d_in[5];
  const float* Wv = (const float*)d_in[6];
  const float* fc_w = (const float*)d_in[7];
  const float* fc_b = (const float*)d_in[8];
  const float* ln1_g = (const float*)d_in[9];
  const float* ln1_b = (const float*)d_in[10];
  const float* W1 = (const float*)d_in[11];
  const float* b1 = (const float*)d_in[12];
  const float* W2 = (const float*)d_in[13];
  const float* b2 = (const float*)d_in[14];
  const float* ln2_g = (const float*)d_in[15];
  const float* ln2_b = (const float*)d_in[16];

  float* x = (float*)d_out;
  char* ws = (char*)d_ws;
  const size_t SZF = (size_t)MM * DD * sizeof(float);
  const size_t SZB = (size_t)MM * DD * sizeof(short);
  float* tem = (float*)ws; ws += SZF;
  float* xa  = (float*)ws; ws += SZF;
  unsigned short* xab = (unsigned short*)ws; ws += SZB;
  unsigned short* xbf = (unsigned short*)ws; ws += SZB;
  unsigned short* qkv = (unsigned short*)ws; ws += (size_t)MM * 1536 * 2;
  unsigned short* vT  = (unsigned short*)ws; ws += (size_t)BB * NH * 64 * LL * 2;
  unsigned short* ao  = (unsigned short*)ws; ws += SZB;
  unsigned short* hb  = (unsigned short*)ws; ws += (size_t)MM * DINNER * 2;
  unsigned short* ybb = (unsigned short*)ws; ws += SZB;  // bf16 LN input
  unsigned short* qkvT = (unsigned short*)ws; ws += (size_t)NLAYERS * 1536 * 512 * 2;
  unsigned short* fcT  = (unsigned short*)ws; ws += (size_t)NLAYERS * 512 * 512 * 2;
  unsigned short* W1T  = (unsigned short*)ws; ws += (size_t)NLAYERS * 2048 * 512 * 2;
  unsigned short* W2T  = (unsigned short*)ws; ws += (size_t)NLAYERS * 512 * 2048 * 2;
  float* meanVpart = (float*)ws; ws += (size_t)32 * 8 * 64 * sizeof(float);
  unsigned short* opart = (unsigned short*)ws; ws += (size_t)2048 * 64 * 64 * 2;
  float* ml = (float*)ws; ws += (size_t)2048 * 128 * sizeof(float);

  init_kernel<<<MM, 512, 0, stream>>>(etype, etime, npm, emb, tem, xa, xab);

  wtrans_kernel<<<dim3(16, 16, NLAYERS), 256, 0, stream>>>(
      Wq, qkvT + 0 * 512 * 512, 512, 512, 512L * 512, 1536L * 512);
  wtrans_kernel<<<dim3(16, 16, NLAYERS), 256, 0, stream>>>(
      Wk, qkvT + 1 * 512 * 512, 512, 512, 512L * 512, 1536L * 512);
  wtrans_kernel<<<dim3(16, 16, NLAYERS), 256, 0, stream>>>(
      Wv, qkvT + 2 * 512 * 512, 512, 512, 512L * 512, 1536L * 512);
  wtrans_kernel<<<dim3(16, 16, NLAYERS), 256, 0, stream>>>(
      fc_w, fcT, 512, 512, 512L * 512, 512L * 512);
  wtrans_kernel<<<dim3(64, 16, NLAYERS), 256, 0, stream>>>(
      W1, W1T, 512, 2048, 512L * 2048, 2048L * 512);
  wtrans_kernel<<<dim3(16, 64, NLAYERS), 256, 0, stream>>>(
      W2, W2T, 2048, 512, 2048L * 512, 512L * 2048);

  for (int l = 0; l < NLAYERS; l++) {
    // QKV (grid 768, 128x128 tiles)
    gemm_kernel<128, 128, false, false, false, true><<<64 * 12, 256, 0, stream>>>(
        xab, qkvT + (size_t)l * 1536 * 512, nullptr, nullptr, 0, qkv, 1536,
        MM, 1536, 512);

    vtrans_kernel<<<dim3(32, 32), 256, 0, stream>>>(qkv, vT);
    meanv_kernel<<<32 * 8, 256, 0, stream>>>(vT, meanVpart);
    attn_kernel<<<2048, 256, 0, stream>>>(qkv, vT, etype, opart, ml);
    amerge_kernel<<<1024, 256, 0, stream>>>(opart, ml, meanVpart, ao);

    // fc: +bias +residual(xa fp32) -> bf16 ybb   (grid 1024, 64x64 tiles)
    gemm_kernel<64, 64, true, true, false, true><<<128 * 8, 256, 0, stream>>>(
        ao, fcT + (size_t)l * 512 * 512, fc_b + (size_t)l * 512, xa, 512, ybb,
        512, MM, 512, 512);
    ln_kernel<false><<<MM, 256, 0, stream>>>(
        ybb, ln1_g + (size_t)l * 512, ln1_b + (size_t)l * 512, npm, nullptr, x,
        nullptr, xbf);

    // FFN1 (grid 1024, 128x128 tiles)
    gemm_kernel<128, 128, true, false, true, true><<<64 * 16, 256, 0, stream>>>(
        xbf, W1T + (size_t)l * 2048 * 512, b1 + (size_t)l * 2048, nullptr, 0,
        hb, 2048, MM, 2048, 512);
    // FFN2: +bias +residual(x fp32) -> bf16 ybb  (grid 1024, 64x64 tiles)
    gemm_kernel<64, 64, true, true, false, true><<<128 * 8, 256, 0, stream>>>(
        hb, W2T + (size_t)l * 512 * 2048, b2 + (size_t)l * 512, x, 512, ybb,
        512, MM, 512, 2048);
    if (l + 1 < NLAYERS) {
      ln_kernel<true><<<MM, 256, 0, stream>>>(
          ybb, ln2_g + (size_t)l * 512, ln2_b + (size_t)l * 512, npm, tem, x,
          xa, xab);
    } else {
      // final layer: no next-layer inputs needed
      ln_kernel<false><<<MM, 256, 0, stream>>>(
          ybb, ln2_g + (size_t)l * 512, ln2_b + (size_t)l * 512, npm, nullptr,
          x, nullptr, xbf);
    }
  }
}

// Round 17
// 956.982 us; speedup vs baseline: 1.1106x; 1.0123x over previous
//
#include <hip/hip_runtime.h>
#include <math.h>

#define BB 4
#define LL 2048
#define DD 512
#define NH 8
#define DINNER 2048
#define NLAYERS 4
#define MM (BB * LL)  // 8192

typedef __attribute__((ext_vector_type(8))) __bf16 bf16x8;
typedef __attribute__((ext_vector_type(4))) float f32x4;
typedef __attribute__((ext_vector_type(4))) unsigned short us4;

__device__ __forceinline__ unsigned short f2b(float f) {
  union { __bf16 h; unsigned short u; } v;
  v.h = (__bf16)f;  // native RNE convert
  return v.u;
}
__device__ __forceinline__ float b2f(unsigned short h) {
  union { unsigned u; float f; } v; v.u = ((unsigned)h) << 16; return v.f;
}
__device__ __forceinline__ unsigned pk2(float lo, float hi) {
  return (unsigned)f2b(lo) | ((unsigned)f2b(hi) << 16);
}
__device__ __forceinline__ float exp2f_fast(float x) {
  float r; asm("v_exp_f32 %0, %1" : "=v"(r) : "v"(x)); return r;
}

__device__ __forceinline__ void gload16(const void* g, void* l) {
  __builtin_amdgcn_global_load_lds(
      (const __attribute__((address_space(1))) void*)g,
      (__attribute__((address_space(3))) void*)l, 16, 0, 0);
}

// ---- init: temporal enc + embedding gather; emits xa = emb+tem directly ----
__global__ __launch_bounds__(512) void init_kernel(
    const int* __restrict__ etype, const float* __restrict__ etime,
    const float* __restrict__ npm, const float* __restrict__ emb,
    float* __restrict__ tem, float* __restrict__ xa,
    unsigned short* __restrict__ xab) {
  int row = blockIdx.x;
  int d = threadIdx.x;
  float t = etime[row];
  float mask = npm[row];
  int dd = d & ~1;
  float pv = expf(9.210340371976184f * ((float)dd * (1.0f / (float)DD)));
  float r = t / pv;
  float val = (d & 1) ? cosf(r) : sinf(r);
  float tv = val * mask;
  tem[(size_t)row * DD + d] = tv;
  int ty = etype[row];
  float a = emb[(size_t)ty * DD + d] + tv;
  xa[(size_t)row * DD + d] = a;
  xab[(size_t)row * DD + d] = f2b(a);
}

// ---------------- weight transpose+convert: fp32 [K][N] -> bf16 [N][K] ----
__global__ __launch_bounds__(256) void wtrans_kernel(
    const float* __restrict__ in, unsigned short* __restrict__ out,
    int K, int N, long in_ls, long out_ls) {
  __shared__ float t[32][33];
  int l = blockIdx.z;
  int n0 = blockIdx.x * 32, k0 = blockIdx.y * 32;
  int tx = threadIdx.x & 31, ty = threadIdx.x >> 5;
  const float* ip = in + (size_t)l * in_ls;
  unsigned short* op = out + (size_t)l * out_ls;
#pragma unroll
  for (int r = ty; r < 32; r += 8)
    t[r][tx] = ip[(size_t)(k0 + r) * N + n0 + tx];
  __syncthreads();
#pragma unroll
  for (int r = ty; r < 32; r += 8)
    op[(size_t)(n0 + r) * K + k0 + tx] = f2b(t[tx][r]);
}

// ---- MFMA GEMM, 2-phase pipelined, XCD-chunked 1D grid (T1 swizzle) ----
// C[M,N] = A(bf16 [M,K]) @ WT(bf16 [N,K])^T.  1D grid = (M/BM)*(N/BN),
// nwg % 8 == 0. Tile variants: 128x128, 64x128, 64x64.
// RESB16: residual read as bf16 (packed) instead of fp32.
template <int BM, int BN, bool BIAS, bool RES, bool GELU_, bool OBF16,
          bool RESB16>
__global__ __launch_bounds__(256) void gemm_kernel(
    const unsigned short* __restrict__ A, const unsigned short* __restrict__ WT,
    const float* __restrict__ bias, const void* __restrict__ resv, int ldres,
    void* __restrict__ Cv, int ldc, int M, int N, int K) {
  __shared__ unsigned short As[2][BM * 32];
  __shared__ unsigned short Bs[2][BN * 32];
  constexpr int MT = (BM == 128) ? 4 : ((BN == 64) ? 2 : 4);
  constexpr int NT = (BM == 128 && BN == 128) ? 4 : 2;
  int tid = threadIdx.x;
  int w = tid >> 6, l = tid & 63;
  int li = l & 15, g = l >> 4;
  // XCD-chunked bijective remap (nwg divisible by 8)
  int nwg = gridDim.x;
  int bid = blockIdx.x;
  int wg = (bid & 7) * (nwg >> 3) + (bid >> 3);
  int gx = N / BN;
  int row0 = (wg / gx) * BM, col0 = (wg % gx) * BN;
  int wm = (BM == 128) ? (w & 1) * 64 : ((BN == 64) ? (w >> 1) * 32 : 0);
  int wnb = (BM == 128) ? (w >> 1) * 64 : ((BN == 64) ? (w & 1) * 32 : w * 32);
  f32x4 acc[MT][NT];
#pragma unroll
  for (int i = 0; i < MT; i++)
#pragma unroll
    for (int j = 0; j < NT; j++) acc[i][j] = (f32x4){0.f, 0.f, 0.f, 0.f};

  int lr = l >> 2;
  int lc = (l & 3) ^ (lr & 3);

  auto stage = [&](int bb, int kb) {
    int k0 = kb * 32;
    if (BM == 128) {
#pragma unroll
      for (int i = 0; i < 2; i++) {
        int ai = w * 2 + i;
        gload16(A + (size_t)(row0 + ai * 16 + lr) * K + k0 + lc * 8,
                &As[bb][ai * 512]);
      }
    } else {
      gload16(A + (size_t)(row0 + w * 16 + lr) * K + k0 + lc * 8,
              &As[bb][w * 512]);
    }
    if (BN == 128) {
#pragma unroll
      for (int i = 0; i < 2; i++) {
        int bi = w * 2 + i;
        gload16(WT + (size_t)(col0 + bi * 16 + lr) * K + k0 + lc * 8,
                &Bs[bb][bi * 512]);
      }
    } else {
      gload16(WT + (size_t)(col0 + w * 16 + lr) * K + k0 + lc * 8,
              &Bs[bb][w * 512]);
    }
  };

  int nk = K >> 5;
  stage(0, 0);
  __syncthreads();
  int buf = 0;
  for (int kb = 0; kb < nk; kb++) {
    if (kb + 1 < nk) stage(buf ^ 1, kb + 1);
    bf16x8 af[MT], bf_[NT];
#pragma unroll
    for (int mt = 0; mt < MT; mt++) {
      int r = wm + mt * 16 + li;
      af[mt] = *(const bf16x8*)&As[buf][r * 32 + ((g ^ (r & 3)) * 8)];
    }
#pragma unroll
    for (int nt = 0; nt < NT; nt++) {
      int r = wnb + nt * 16 + li;
      bf_[nt] = *(const bf16x8*)&Bs[buf][r * 32 + ((g ^ (r & 3)) * 8)];
    }
#pragma unroll
    for (int mt = 0; mt < MT; mt++)
#pragma unroll
      for (int nt = 0; nt < NT; nt++)
        acc[mt][nt] = __builtin_amdgcn_mfma_f32_16x16x32_bf16(
            af[mt], bf_[nt], acc[mt][nt], 0, 0, 0);
    __syncthreads();
    buf ^= 1;
  }
#pragma unroll
  for (int mt = 0; mt < MT; mt++) {
#pragma unroll
    for (int nt = 0; nt < NT; nt++) {
#pragma unroll
      for (int r = 0; r < 4; r++) {
        int row = row0 + wm + mt * 16 + g * 4 + r;
        int col = col0 + wnb + nt * 16 + li;
        float v = acc[mt][nt][r];
        if (BIAS) v += bias[col];
        if (RES) {
          if (RESB16)
            v += b2f(((const unsigned short*)resv)[(size_t)row * ldres + col]);
          else
            v += ((const float*)resv)[(size_t)row * ldres + col];
        }
        if (GELU_) v = 0.5f * v * (1.0f + erff(v * 0.70710678118654752f));
        if (OBF16)
          ((unsigned short*)Cv)[(size_t)row * ldc + col] = f2b(v);
        else
          ((float*)Cv)[(size_t)row * ldc + col] = v;
      }
    }
  }
}

// ---- transpose v slice of qkv -> vT [bh*64+d][L], vectorized global ----
__global__ __launch_bounds__(256) void vtrans_kernel(
    const unsigned short* __restrict__ qkv, unsigned short* __restrict__ vT) {
  __shared__ unsigned short t[64][65];
  int bh = blockIdx.y;
  int b = bh >> 3, h = bh & 7;
  int l0 = blockIdx.x * 64;
  int tid = threadIdx.x;
  int rr = tid >> 4, c4 = (tid & 15) * 4;
#pragma unroll
  for (int pass = 0; pass < 4; pass++) {
    int r = pass * 16 + rr;
    us4 v = *(const us4*)&qkv[(size_t)(b * LL + l0 + r) * 1536 + 1024 +
                              h * 64 + c4];
    t[r][c4] = v[0];
    t[r][c4 + 1] = v[1];
    t[r][c4 + 2] = v[2];
    t[r][c4 + 3] = v[3];
  }
  __syncthreads();
#pragma unroll
  for (int pass = 0; pass < 4; pass++) {
    int r = pass * 16 + rr;  // vT row (d)
    us4 v = {t[c4][r], t[c4 + 1][r], t[c4 + 2][r], t[c4 + 3][r]};
    *(us4*)&vT[((size_t)bh * 64 + r) * LL + l0 + c4] = v;
  }
}

// ---- meanV partial sums: grid 256 = 32 bh x 8 L-chunks, vectorized ----
__global__ __launch_bounds__(256) void meanv_kernel(
    const unsigned short* __restrict__ vT, float* __restrict__ meanVpart) {
  __shared__ float red[4][64];
  int chunk = blockIdx.x & 7;
  int bh = blockIdx.x >> 3;
  int tid = threadIdx.x;
  int d = tid & 63, p = tid >> 6;
  const unsigned short* vp =
      vT + ((size_t)bh * 64 + d) * LL + chunk * 256 + p * 64;
  float s = 0.f;
#pragma unroll
  for (int i = 0; i < 16; i++) {
    us4 v = *(const us4*)&vp[i * 4];
    s += b2f(v[0]) + b2f(v[1]) + b2f(v[2]) + b2f(v[3]);
  }
  red[p][d] = s;
  __syncthreads();
  if (p == 0)
    meanVpart[(size_t)blockIdx.x * 64 + d] =
        red[0][d] + red[1][d] + red[2][d] + red[3][d];
}

// ---- MFMA flash attention, 2-way KEY-SPLIT (r10 proven structure) ----
__global__ __launch_bounds__(256) void attn_kernel(
    const unsigned short* __restrict__ qkv, const unsigned short* __restrict__ vT,
    const int* __restrict__ etype, unsigned short* __restrict__ opart,
    float* __restrict__ ml) {
  __shared__ unsigned short Ks[2][64 * 64];  // [buf][key*64+d], swizzled 8KB
  __shared__ unsigned short Ps[64][72];
  int hwbid = blockIdx.x;
  int work = (hwbid & 7) * 256 + (hwbid >> 3);  // XCD-chunked (bijective)
  int bh = work >> 6;
  int rem = work & 63;
  int qt = 31 - (rem >> 1);  // LPT: big q-tiles first
  int half = rem & 1;
  int h = bh & 7, b = bh >> 3;
  int q0 = qt * 64;
  int nt = qt + 1;
  int ha = (nt + 1) >> 1;  // half A gets ceil(nt/2), always nonempty
  int j0 = half ? ha : 0;
  int j1 = half ? nt : ha;
  int pidx = (bh * 32 + qt) * 2 + half;
  int tid = threadIdx.x, w = tid >> 6, l = tid & 63;
  int g = l >> 4, li = l & 15;
  const float SC = 0.125f * 1.44269504f;  // scale * log2(e)

  f32x4 o[4];
#pragma unroll
  for (int n = 0; n < 4; n++) o[n] = (f32x4){0.f, 0.f, 0.f, 0.f};
  float mreg[4], lreg[4];
#pragma unroll
  for (int r = 0; r < 4; r++) { mreg[r] = -3.0e38f; lreg[r] = 0.f; }

  if (j0 < j1) {
    const unsigned short* qrp =
        qkv + (size_t)(b * LL + q0 + w * 16 + li) * 1536 + h * 64;
    bf16x8 aq0 = *(const bf16x8*)&qrp[g * 8];
    bf16x8 aq1 = *(const bf16x8*)&qrp[32 + g * 8];

    // prologue: stage tile j0 into buf 0
#pragma unroll
    for (int e = 0; e < 2; e++) {
      int idx = e * 256 + tid;
      int r = idx >> 3;
      int src = (l & 7) ^ (r & 7);
      gload16(
          qkv + (size_t)(b * LL + j0 * 64 + r) * 1536 + 512 + h * 64 + src * 8,
          &Ks[0][(e * 256 + w * 64) * 8]);
    }
    __syncthreads();

    int cur = 0;
    for (int j = j0; j < j1; j++) {
      int k0 = j << 6;
      if (j + 1 < j1) {
#pragma unroll
        for (int e = 0; e < 2; e++) {
          int idx = e * 256 + tid;
          int r = idx >> 3;
          int src = (l & 7) ^ (r & 7);
          gload16(qkv + (size_t)(b * LL + k0 + 64 + r) * 1536 + 512 + h * 64 +
                      src * 8,
                  &Ks[cur ^ 1][(e * 256 + w * 64) * 8]);
        }
      }
      // V frags + pad bias, issued early (L2-resident)
      bf16x8 bv0[4], bv1[4];
      float pb[4];
#pragma unroll
      for (int n = 0; n < 4; n++) {
        const unsigned short* vp =
            vT + ((size_t)(bh * 64 + n * 16 + li)) * LL + k0;
        bv0[n] = *(const bf16x8*)&vp[g * 8];
        bv1[n] = *(const bf16x8*)&vp[32 + g * 8];
        pb[n] = (etype[b * LL + k0 + n * 16 + li] == 0) ? -1.0e9f : 0.f;
      }
      // S = Q K^T from swizzled LDS
      f32x4 s[4];
#pragma unroll
      for (int n = 0; n < 4; n++) {
        int rK = n * 16 + li;
        const unsigned short* kb = &Ks[cur][rK * 64];
        bf16x8 bk0 = *(const bf16x8*)&kb[(g ^ (rK & 7)) * 8];
        bf16x8 bk1 = *(const bf16x8*)&kb[((g + 4) ^ (rK & 7)) * 8];
        f32x4 a = (f32x4){0.f, 0.f, 0.f, 0.f};
        __builtin_amdgcn_s_setprio(1);
        a = __builtin_amdgcn_mfma_f32_16x16x32_bf16(aq0, bk0, a, 0, 0, 0);
        a = __builtin_amdgcn_mfma_f32_16x16x32_bf16(aq1, bk1, a, 0, 0, 0);
        __builtin_amdgcn_s_setprio(0);
        s[n] = a;
      }
      // scale + mask: fast path off-diagonal (pad bias only)
      if (j == qt) {
#pragma unroll
        for (int n = 0; n < 4; n++) {
          int key = k0 + n * 16 + li;
#pragma unroll
          for (int r = 0; r < 4; r++) {
            int qrow = q0 + w * 16 + g * 4 + r;
            float sv = fmaf(s[n][r], SC, pb[n]);
            if (key > qrow) sv = -1.0e9f;
            s[n][r] = sv;
          }
        }
      } else {
#pragma unroll
        for (int n = 0; n < 4; n++)
#pragma unroll
          for (int r = 0; r < 4; r++) s[n][r] = fmaf(s[n][r], SC, pb[n]);
      }
      // wave-parallel online softmax (reduce across 16 li lanes), exp2 domain
      float pm[4], corr[4], psum[4];
#pragma unroll
      for (int r = 0; r < 4; r++)
        pm[r] = fmaxf(fmaxf(s[0][r], s[1][r]), fmaxf(s[2][r], s[3][r]));
#pragma unroll
      for (int msk = 1; msk <= 8; msk <<= 1)
#pragma unroll
        for (int r = 0; r < 4; r++)
          pm[r] = fmaxf(pm[r], __shfl_xor(pm[r], msk, 64));
#pragma unroll
      for (int r = 0; r < 4; r++) {
        float mnew = fmaxf(mreg[r], pm[r]);
        corr[r] = exp2f_fast(mreg[r] - mnew);
        mreg[r] = mnew;
        float ps = 0.f;
#pragma unroll
        for (int n = 0; n < 4; n++) {
          float p = exp2f_fast(s[n][r] - mnew);
          s[n][r] = p;
          ps += p;
        }
        psum[r] = ps;
      }
#pragma unroll
      for (int msk = 1; msk <= 8; msk <<= 1)
#pragma unroll
        for (int r = 0; r < 4; r++) psum[r] += __shfl_xor(psum[r], msk, 64);
#pragma unroll
      for (int r = 0; r < 4; r++) lreg[r] = lreg[r] * corr[r] + psum[r];
      // P -> LDS (own-wave rows only; same-wave ordering via lgkmcnt)
#pragma unroll
      for (int n = 0; n < 4; n++)
#pragma unroll
        for (int r = 0; r < 4; r++)
          Ps[w * 16 + g * 4 + r][n * 16 + li] = f2b(s[n][r]);
      // rescale O
#pragma unroll
      for (int n = 0; n < 4; n++)
#pragma unroll
        for (int r = 0; r < 4; r++) o[n][r] *= corr[r];
      // PV: A = P rows (LDS), B = V frags (regs)
      bf16x8 ap0 = *(const bf16x8*)&Ps[w * 16 + li][g * 8];
      bf16x8 ap1 = *(const bf16x8*)&Ps[w * 16 + li][32 + g * 8];
      __builtin_amdgcn_s_setprio(1);
#pragma unroll
      for (int n = 0; n < 4; n++) {
        o[n] = __builtin_amdgcn_mfma_f32_16x16x32_bf16(ap0, bv0[n], o[n], 0, 0, 0);
        o[n] = __builtin_amdgcn_mfma_f32_16x16x32_bf16(ap1, bv1[n], o[n], 0, 0, 0);
      }
      __builtin_amdgcn_s_setprio(0);
      __syncthreads();  // drains prefetch (vmcnt) + Ks/Ps traffic
      cur ^= 1;
    }
  }
  // epilogue: l-normalized partial O (bf16) + per-row (m,l)
#pragma unroll
  for (int r = 0; r < 4; r++) {
    int qrl = w * 16 + g * 4 + r;
    float inv = (lreg[r] > 0.f) ? 1.0f / lreg[r] : 0.f;
#pragma unroll
    for (int n = 0; n < 4; n++)
      opart[((size_t)pidx * 64 + qrl) * 64 + n * 16 + li] = f2b(o[n][r] * inv);
    if (li == 0) {
      ml[(size_t)pidx * 128 + qrl] = mreg[r];
      ml[(size_t)pidx * 128 + 64 + qrl] = lreg[r];
    }
  }
}

// ---- merge the two key-split halves (packed 2-wide, static) ----
__global__ __launch_bounds__(256) void amerge_kernel(
    const unsigned short* __restrict__ opart, const float* __restrict__ ml,
    const float* __restrict__ meanVpart, unsigned short* __restrict__ ao) {
  int blk = blockIdx.x;  // bh*32 + qt  (1024 blocks)
  int bh = blk >> 5, qt = blk & 31;
  int b = bh >> 3, h = bh & 7;
  int tid = threadIdx.x;
  int d2 = (tid & 31) * 2;
  int pA = blk * 2, pB = blk * 2 + 1;
  for (int rr = tid >> 5; rr < 64; rr += 8) {
    float mA = ml[(size_t)pA * 128 + rr], lA = ml[(size_t)pA * 128 + 64 + rr];
    float mB = ml[(size_t)pB * 128 + rr], lB = ml[(size_t)pB * 128 + 64 + rr];
    float m = fmaxf(mA, mB);
    float v0, v1;
    if (m <= -1.0e8f) {
      float s0 = 0.f, s1 = 0.f;
#pragma unroll
      for (int cc = 0; cc < 8; cc++) {
        s0 += meanVpart[((size_t)bh * 8 + cc) * 64 + d2];
        s1 += meanVpart[((size_t)bh * 8 + cc) * 64 + d2 + 1];
      }
      v0 = s0 * (1.0f / (float)LL);
      v1 = s1 * (1.0f / (float)LL);
    } else {
      float a0 = 0.f, a1 = 0.f, wsum = 0.f;
      if (lA > 0.f) {
        float wA = exp2f_fast(mA - m) * lA;
        unsigned ua = *(const unsigned*)&opart[((size_t)pA * 64 + rr) * 64 + d2];
        a0 += b2f((unsigned short)ua) * wA;
        a1 += b2f((unsigned short)(ua >> 16)) * wA;
        wsum += wA;
      }
      if (lB > 0.f) {
        float wB = exp2f_fast(mB - m) * lB;
        unsigned ub = *(const unsigned*)&opart[((size_t)pB * 64 + rr) * 64 + d2];
        a0 += b2f((unsigned short)ub) * wB;
        a1 += b2f((unsigned short)(ub >> 16)) * wB;
        wsum += wB;
      }
      float inv = 1.0f / wsum;
      v0 = a0 * inv;
      v1 = a1 * inv;
    }
    int qr = qt * 64 + rr;
    *(unsigned*)&ao[(size_t)(b * LL + qr) * DD + h * 64 + d2] = pk2(v0, v1);
  }
}

// ---- LayerNorm (+npm), bf16 input. WF32: write fp32 out; WBF: write bf16;
// ADDTEM: also emit xa=x+tem (fp32) + xab (bf16). ----
template <bool ADDTEM, bool WF32, bool WBF>
__global__ __launch_bounds__(256) void ln_kernel(
    const unsigned short* __restrict__ in, const float* __restrict__ g,
    const float* __restrict__ bta, const float* __restrict__ npm,
    const float* __restrict__ tem, float* __restrict__ out,
    float* __restrict__ out2, unsigned short* __restrict__ out_bf) {
  __shared__ float red[4];
  int row = blockIdx.x;
  int tid = threadIdx.x;
  unsigned u = ((const unsigned*)(in + (size_t)row * DD))[tid];
  float v0 = b2f((unsigned short)u), v1 = b2f((unsigned short)(u >> 16));
  int e0 = tid * 2, e1 = tid * 2 + 1;
  float s = v0 + v1;
#pragma unroll
  for (int o = 32; o > 0; o >>= 1) s += __shfl_down(s, o, 64);
  if ((tid & 63) == 0) red[tid >> 6] = s;
  __syncthreads();
  float mean = (red[0] + red[1] + red[2] + red[3]) * (1.0f / (float)DD);
  float d0 = v0 - mean, d1 = v1 - mean;
  float sq = d0 * d0 + d1 * d1;
#pragma unroll
  for (int o = 32; o > 0; o >>= 1) sq += __shfl_down(sq, o, 64);
  __syncthreads();
  if ((tid & 63) == 0) red[tid >> 6] = sq;
  __syncthreads();
  float var = (red[0] + red[1] + red[2] + red[3]) * (1.0f / (float)DD);
  float rstd = rsqrtf(var + 1e-6f);
  float m = npm[row];
  float o0 = (d0 * rstd * g[e0] + bta[e0]) * m;
  float o1 = (d1 * rstd * g[e1] + bta[e1]) * m;
  if (WF32) ((float2*)(out + (size_t)row * DD))[tid] = make_float2(o0, o1);
  if (ADDTEM) {
    float2 tv = ((const float2*)(tem + (size_t)row * DD))[tid];
    float a0 = o0 + tv.x, a1 = o1 + tv.y;
    ((float2*)(out2 + (size_t)row * DD))[tid] = make_float2(a0, a1);
    ((unsigned*)(out_bf + (size_t)row * DD))[tid] = pk2(a0, a1);
  } else if (WBF) {
    ((unsigned*)(out_bf + (size_t)row * DD))[tid] = pk2(o0, o1);
  }
}

extern "C" void kernel_launch(void* const* d_in, const int* in_sizes, int n_in,
                              void* d_out, int out_size, void* d_ws,
                              size_t ws_size, hipStream_t stream) {
  const int* etype = (const int*)d_in[0];
  const float* etime = (const float*)d_in[1];
  const float* npm = (const float*)d_in[2];
  const float* emb = (const float*)d_in[3];
  const float* Wq = (const float*)d_in[4];
  const float* Wk = (const float*)d_in[5];
  const float* Wv = (const float*)d_in[6];
  const float* fc_w = (const float*)d_in[7];
  const float* fc_b = (const float*)d_in[8];
  const float* ln1_g = (const float*)d_in[9];
  const float* ln1_b = (const float*)d_in[10];
  const float* W1 = (const float*)d_in[11];
  const float* b1 = (const float*)d_in[12];
  const float* W2 = (const float*)d_in[13];
  const float* b2 = (const float*)d_in[14];
  const float* ln2_g = (const float*)d_in[15];
  const float* ln2_b = (const float*)d_in[16];

  float* x = (float*)d_out;
  char* ws = (char*)d_ws;
  const size_t SZF = (size_t)MM * DD * sizeof(float);
  const size_t SZB = (size_t)MM * DD * sizeof(short);
  float* tem = (float*)ws; ws += SZF;
  float* xa  = (float*)ws; ws += SZF;
  unsigned short* xab = (unsigned short*)ws; ws += SZB;
  unsigned short* xbf = (unsigned short*)ws; ws += SZB;
  unsigned short* qkv = (unsigned short*)ws; ws += (size_t)MM * 1536 * 2;
  unsigned short* vT  = (unsigned short*)ws; ws += (size_t)BB * NH * 64 * LL * 2;
  unsigned short* ao  = (unsigned short*)ws; ws += SZB;
  unsigned short* hb  = (unsigned short*)ws; ws += (size_t)MM * DINNER * 2;
  unsigned short* ybb = (unsigned short*)ws; ws += SZB;  // bf16 LN input
  unsigned short* qkvT = (unsigned short*)ws; ws += (size_t)NLAYERS * 1536 * 512 * 2;
  unsigned short* fcT  = (unsigned short*)ws; ws += (size_t)NLAYERS * 512 * 512 * 2;
  unsigned short* W1T  = (unsigned short*)ws; ws += (size_t)NLAYERS * 2048 * 512 * 2;
  unsigned short* W2T  = (unsigned short*)ws; ws += (size_t)NLAYERS * 512 * 2048 * 2;
  float* meanVpart = (float*)ws; ws += (size_t)32 * 8 * 64 * sizeof(float);
  unsigned short* opart = (unsigned short*)ws; ws += (size_t)2048 * 64 * 64 * 2;
  float* ml = (float*)ws; ws += (size_t)2048 * 128 * sizeof(float);

  init_kernel<<<MM, 512, 0, stream>>>(etype, etime, npm, emb, tem, xa, xab);

  wtrans_kernel<<<dim3(16, 16, NLAYERS), 256, 0, stream>>>(
      Wq, qkvT + 0 * 512 * 512, 512, 512, 512L * 512, 1536L * 512);
  wtrans_kernel<<<dim3(16, 16, NLAYERS), 256, 0, stream>>>(
      Wk, qkvT + 1 * 512 * 512, 512, 512, 512L * 512, 1536L * 512);
  wtrans_kernel<<<dim3(16, 16, NLAYERS), 256, 0, stream>>>(
      Wv, qkvT + 2 * 512 * 512, 512, 512, 512L * 512, 1536L * 512);
  wtrans_kernel<<<dim3(16, 16, NLAYERS), 256, 0, stream>>>(
      fc_w, fcT, 512, 512, 512L * 512, 512L * 512);
  wtrans_kernel<<<dim3(64, 16, NLAYERS), 256, 0, stream>>>(
      W1, W1T, 512, 2048, 512L * 2048, 2048L * 512);
  wtrans_kernel<<<dim3(16, 64, NLAYERS), 256, 0, stream>>>(
      W2, W2T, 2048, 512, 2048L * 512, 512L * 2048);

  for (int l = 0; l < NLAYERS; l++) {
    // QKV (grid 1536, 64x128 tiles: 6 blocks/CU)
    gemm_kernel<64, 128, false, false, false, true, false>
        <<<128 * 12, 256, 0, stream>>>(
            xab, qkvT + (size_t)l * 1536 * 512, nullptr, nullptr, 0, qkv, 1536,
            MM, 1536, 512);

    vtrans_kernel<<<dim3(32, 32), 256, 0, stream>>>(qkv, vT);
    meanv_kernel<<<32 * 8, 256, 0, stream>>>(vT, meanVpart);
    attn_kernel<<<2048, 256, 0, stream>>>(qkv, vT, etype, opart, ml);
    amerge_kernel<<<1024, 256, 0, stream>>>(opart, ml, meanVpart, ao);

    // fc: +bias +residual(xa fp32) -> bf16 ybb   (grid 1024, 64x64 tiles)
    gemm_kernel<64, 64, true, true, false, true, false>
        <<<128 * 8, 256, 0, stream>>>(
            ao, fcT + (size_t)l * 512 * 512, fc_b + (size_t)l * 512, xa, 512,
            ybb, 512, MM, 512, 512);
    // LN1: bf16 out only
    ln_kernel<false, false, true><<<MM, 256, 0, stream>>>(
        ybb, ln1_g + (size_t)l * 512, ln1_b + (size_t)l * 512, npm, nullptr,
        nullptr, nullptr, xbf);

    // FFN1 (grid 1024, 128x128 tiles)
    gemm_kernel<128, 128, true, false, true, true, false>
        <<<64 * 16, 256, 0, stream>>>(
            xbf, W1T + (size_t)l * 2048 * 512, b1 + (size_t)l * 2048, nullptr,
            0, hb, 2048, MM, 2048, 512);
    // FFN2: +bias +residual(xbf bf16) -> bf16 ybb  (grid 1024, 64x64 tiles)
    gemm_kernel<64, 64, true, true, false, true, true>
        <<<128 * 8, 256, 0, stream>>>(
            hb, W2T + (size_t)l * 512 * 2048, b2 + (size_t)l * 512, xbf, 512,
            ybb, 512, MM, 512, 2048);
    if (l + 1 < NLAYERS) {
      // LN2: xa (fp32) + xab (bf16) for next layer; x not needed yet
      ln_kernel<true, false, false><<<MM, 256, 0, stream>>>(
          ybb, ln2_g + (size_t)l * 512, ln2_b + (size_t)l * 512, npm, tem,
          nullptr, xa, xab);
    } else {
      // final layer: only the fp32 output x
      ln_kernel<false, true, false><<<MM, 256, 0, stream>>>(
          ybb, ln2_g + (size_t)l * 512, ln2_b + (size_t)l * 512, npm, nullptr,
          x, nullptr, nullptr);
    }
  }
}

// Round 18
// 931.668 us; speedup vs baseline: 1.1408x; 1.0272x over previous
//
#include <hip/hip_runtime.h>
#include <math.h>

#define BB 4
#define LL 2048
#define DD 512
#define NH 8
#define DINNER 2048
#define NLAYERS 4
#define MM (BB * LL)  // 8192

typedef __attribute__((ext_vector_type(8))) __bf16 bf16x8;
typedef __attribute__((ext_vector_type(4))) float f32x4;
typedef __attribute__((ext_vector_type(4))) unsigned short us4;

__device__ __forceinline__ unsigned short f2b(float f) {
  union { __bf16 h; unsigned short u; } v;
  v.h = (__bf16)f;  // native RNE convert
  return v.u;
}
__device__ __forceinline__ float b2f(unsigned short h) {
  union { unsigned u; float f; } v; v.u = ((unsigned)h) << 16; return v.f;
}
__device__ __forceinline__ unsigned pk2(float lo, float hi) {
  return (unsigned)f2b(lo) | ((unsigned)f2b(hi) << 16);
}
__device__ __forceinline__ float exp2f_fast(float x) {
  float r; asm("v_exp_f32 %0, %1" : "=v"(r) : "v"(x)); return r;
}

__device__ __forceinline__ void gload16(const void* g, void* l) {
  __builtin_amdgcn_global_load_lds(
      (const __attribute__((address_space(1))) void*)g,
      (__attribute__((address_space(3))) void*)l, 16, 0, 0);
}

// ---- init: temporal enc + embedding gather; emits xa = emb+tem directly ----
__global__ __launch_bounds__(512) void init_kernel(
    const int* __restrict__ etype, const float* __restrict__ etime,
    const float* __restrict__ npm, const float* __restrict__ emb,
    float* __restrict__ tem, float* __restrict__ xa,
    unsigned short* __restrict__ xab) {
  int row = blockIdx.x;
  int d = threadIdx.x;
  float t = etime[row];
  float mask = npm[row];
  int dd = d & ~1;
  float pv = expf(9.210340371976184f * ((float)dd * (1.0f / (float)DD)));
  float r = t / pv;
  float val = (d & 1) ? cosf(r) : sinf(r);
  float tv = val * mask;
  tem[(size_t)row * DD + d] = tv;
  int ty = etype[row];
  float a = emb[(size_t)ty * DD + d] + tv;
  xa[(size_t)row * DD + d] = a;
  xab[(size_t)row * DD + d] = f2b(a);
}

// ---------------- weight transpose+convert: fp32 [K][N] -> bf16 [N][K] ----
__global__ __launch_bounds__(256) void wtrans_kernel(
    const float* __restrict__ in, unsigned short* __restrict__ out,
    int K, int N, long in_ls, long out_ls) {
  __shared__ float t[32][33];
  int l = blockIdx.z;
  int n0 = blockIdx.x * 32, k0 = blockIdx.y * 32;
  int tx = threadIdx.x & 31, ty = threadIdx.x >> 5;
  const float* ip = in + (size_t)l * in_ls;
  unsigned short* op = out + (size_t)l * out_ls;
#pragma unroll
  for (int r = ty; r < 32; r += 8)
    t[r][tx] = ip[(size_t)(k0 + r) * N + n0 + tx];
  __syncthreads();
#pragma unroll
  for (int r = ty; r < 32; r += 8)
    op[(size_t)(n0 + r) * K + k0 + tx] = f2b(t[tx][r]);
}

// ---- MFMA GEMM, 2-phase pipelined, XCD-chunked 1D grid (T1 swizzle) ----
// C[M,N] = A(bf16 [M,K]) @ WT(bf16 [N,K])^T.  1D grid = (M/BM)*(N/BN),
// nwg % 8 == 0. Tile variants: 128x128, 64x128, 64x64.
// RESB16: residual read as bf16 (packed) instead of fp32.
template <int BM, int BN, bool BIAS, bool RES, bool GELU_, bool OBF16,
          bool RESB16>
__global__ __launch_bounds__(256) void gemm_kernel(
    const unsigned short* __restrict__ A, const unsigned short* __restrict__ WT,
    const float* __restrict__ bias, const void* __restrict__ resv, int ldres,
    void* __restrict__ Cv, int ldc, int M, int N, int K) {
  __shared__ unsigned short As[2][BM * 32];
  __shared__ unsigned short Bs[2][BN * 32];
  constexpr int MT = (BM == 128) ? 4 : ((BN == 64) ? 2 : 4);
  constexpr int NT = (BM == 128 && BN == 128) ? 4 : 2;
  int tid = threadIdx.x;
  int w = tid >> 6, l = tid & 63;
  int li = l & 15, g = l >> 4;
  // XCD-chunked bijective remap (nwg divisible by 8)
  int nwg = gridDim.x;
  int bid = blockIdx.x;
  int wg = (bid & 7) * (nwg >> 3) + (bid >> 3);
  int gx = N / BN;
  int row0 = (wg / gx) * BM, col0 = (wg % gx) * BN;
  int wm = (BM == 128) ? (w & 1) * 64 : ((BN == 64) ? (w >> 1) * 32 : 0);
  int wnb = (BM == 128) ? (w >> 1) * 64 : ((BN == 64) ? (w & 1) * 32 : w * 32);
  f32x4 acc[MT][NT];
#pragma unroll
  for (int i = 0; i < MT; i++)
#pragma unroll
    for (int j = 0; j < NT; j++) acc[i][j] = (f32x4){0.f, 0.f, 0.f, 0.f};

  int lr = l >> 2;
  int lc = (l & 3) ^ (lr & 3);

  auto stage = [&](int bb, int kb) {
    int k0 = kb * 32;
    if (BM == 128) {
#pragma unroll
      for (int i = 0; i < 2; i++) {
        int ai = w * 2 + i;
        gload16(A + (size_t)(row0 + ai * 16 + lr) * K + k0 + lc * 8,
                &As[bb][ai * 512]);
      }
    } else {
      gload16(A + (size_t)(row0 + w * 16 + lr) * K + k0 + lc * 8,
              &As[bb][w * 512]);
    }
    if (BN == 128) {
#pragma unroll
      for (int i = 0; i < 2; i++) {
        int bi = w * 2 + i;
        gload16(WT + (size_t)(col0 + bi * 16 + lr) * K + k0 + lc * 8,
                &Bs[bb][bi * 512]);
      }
    } else {
      gload16(WT + (size_t)(col0 + w * 16 + lr) * K + k0 + lc * 8,
              &Bs[bb][w * 512]);
    }
  };

  int nk = K >> 5;
  stage(0, 0);
  __syncthreads();
  int buf = 0;
  for (int kb = 0; kb < nk; kb++) {
    if (kb + 1 < nk) stage(buf ^ 1, kb + 1);
    bf16x8 af[MT], bf_[NT];
#pragma unroll
    for (int mt = 0; mt < MT; mt++) {
      int r = wm + mt * 16 + li;
      af[mt] = *(const bf16x8*)&As[buf][r * 32 + ((g ^ (r & 3)) * 8)];
    }
#pragma unroll
    for (int nt = 0; nt < NT; nt++) {
      int r = wnb + nt * 16 + li;
      bf_[nt] = *(const bf16x8*)&Bs[buf][r * 32 + ((g ^ (r & 3)) * 8)];
    }
#pragma unroll
    for (int mt = 0; mt < MT; mt++)
#pragma unroll
      for (int nt = 0; nt < NT; nt++)
        acc[mt][nt] = __builtin_amdgcn_mfma_f32_16x16x32_bf16(
            af[mt], bf_[nt], acc[mt][nt], 0, 0, 0);
    __syncthreads();
    buf ^= 1;
  }
#pragma unroll
  for (int mt = 0; mt < MT; mt++) {
#pragma unroll
    for (int nt = 0; nt < NT; nt++) {
#pragma unroll
      for (int r = 0; r < 4; r++) {
        int row = row0 + wm + mt * 16 + g * 4 + r;
        int col = col0 + wnb + nt * 16 + li;
        float v = acc[mt][nt][r];
        if (BIAS) v += bias[col];
        if (RES) {
          if (RESB16)
            v += b2f(((const unsigned short*)resv)[(size_t)row * ldres + col]);
          else
            v += ((const float*)resv)[(size_t)row * ldres + col];
        }
        if (GELU_) v = 0.5f * v * (1.0f + erff(v * 0.70710678118654752f));
        if (OBF16)
          ((unsigned short*)Cv)[(size_t)row * ldc + col] = f2b(v);
        else
          ((float*)Cv)[(size_t)row * ldc + col] = v;
      }
    }
  }
}

// ---- transpose v slice -> vT [bh*64+d][L] + fused meanV partial sums ----
// grid (32 L-chunks, 32 bh). Partial sum per (bh, chunk) over its 64 keys.
__global__ __launch_bounds__(256) void vtrans_kernel(
    const unsigned short* __restrict__ qkv, unsigned short* __restrict__ vT,
    float* __restrict__ meanVpart) {
  __shared__ unsigned short t[64][65];
  __shared__ float red[4][64];
  int bh = blockIdx.y;
  int b = bh >> 3, h = bh & 7;
  int l0 = blockIdx.x * 64;
  int tid = threadIdx.x;
  int rr = tid >> 4, c4 = (tid & 15) * 4;
#pragma unroll
  for (int pass = 0; pass < 4; pass++) {
    int r = pass * 16 + rr;
    us4 v = *(const us4*)&qkv[(size_t)(b * LL + l0 + r) * 1536 + 1024 +
                              h * 64 + c4];
    t[r][c4] = v[0];
    t[r][c4 + 1] = v[1];
    t[r][c4 + 2] = v[2];
    t[r][c4 + 3] = v[3];
  }
  __syncthreads();
#pragma unroll
  for (int pass = 0; pass < 4; pass++) {
    int r = pass * 16 + rr;  // vT row (d)
    us4 v = {t[c4][r], t[c4 + 1][r], t[c4 + 2][r], t[c4 + 3][r]};
    *(us4*)&vT[((size_t)bh * 64 + r) * LL + l0 + c4] = v;
  }
  // fused meanV partial: sum over this chunk's 64 keys per d
  int p = tid >> 6, d = tid & 63;
  float s = 0.f;
#pragma unroll
  for (int i = 0; i < 16; i++) s += b2f(t[p * 16 + i][d]);
  red[p][d] = s;
  __syncthreads();
  if (p == 0)
    meanVpart[((size_t)bh * 32 + blockIdx.x) * 64 + d] =
        red[0][d] + red[1][d] + red[2][d] + red[3][d];
}

// ---- MFMA flash attention, 2-way KEY-SPLIT (r10 proven structure) ----
__global__ __launch_bounds__(256) void attn_kernel(
    const unsigned short* __restrict__ qkv, const unsigned short* __restrict__ vT,
    const int* __restrict__ etype, unsigned short* __restrict__ opart,
    float* __restrict__ ml) {
  __shared__ unsigned short Ks[2][64 * 64];  // [buf][key*64+d], swizzled 8KB
  __shared__ unsigned short Ps[64][72];
  int hwbid = blockIdx.x;
  int work = (hwbid & 7) * 256 + (hwbid >> 3);  // XCD-chunked (bijective)
  int bh = work >> 6;
  int rem = work & 63;
  int qt = 31 - (rem >> 1);  // LPT: big q-tiles first
  int half = rem & 1;
  int h = bh & 7, b = bh >> 3;
  int q0 = qt * 64;
  int nt = qt + 1;
  int ha = (nt + 1) >> 1;  // half A gets ceil(nt/2), always nonempty
  int j0 = half ? ha : 0;
  int j1 = half ? nt : ha;
  int pidx = (bh * 32 + qt) * 2 + half;
  int tid = threadIdx.x, w = tid >> 6, l = tid & 63;
  int g = l >> 4, li = l & 15;
  const float SC = 0.125f * 1.44269504f;  // scale * log2(e)

  f32x4 o[4];
#pragma unroll
  for (int n = 0; n < 4; n++) o[n] = (f32x4){0.f, 0.f, 0.f, 0.f};
  float mreg[4], lreg[4];
#pragma unroll
  for (int r = 0; r < 4; r++) { mreg[r] = -3.0e38f; lreg[r] = 0.f; }

  if (j0 < j1) {
    const unsigned short* qrp =
        qkv + (size_t)(b * LL + q0 + w * 16 + li) * 1536 + h * 64;
    bf16x8 aq0 = *(const bf16x8*)&qrp[g * 8];
    bf16x8 aq1 = *(const bf16x8*)&qrp[32 + g * 8];

    // prologue: stage tile j0 into buf 0
#pragma unroll
    for (int e = 0; e < 2; e++) {
      int idx = e * 256 + tid;
      int r = idx >> 3;
      int src = (l & 7) ^ (r & 7);
      gload16(
          qkv + (size_t)(b * LL + j0 * 64 + r) * 1536 + 512 + h * 64 + src * 8,
          &Ks[0][(e * 256 + w * 64) * 8]);
    }
    __syncthreads();

    int cur = 0;
    for (int j = j0; j < j1; j++) {
      int k0 = j << 6;
      if (j + 1 < j1) {
#pragma unroll
        for (int e = 0; e < 2; e++) {
          int idx = e * 256 + tid;
          int r = idx >> 3;
          int src = (l & 7) ^ (r & 7);
          gload16(qkv + (size_t)(b * LL + k0 + 64 + r) * 1536 + 512 + h * 64 +
                      src * 8,
                  &Ks[cur ^ 1][(e * 256 + w * 64) * 8]);
        }
      }
      // V frags + pad bias, issued early (L2-resident)
      bf16x8 bv0[4], bv1[4];
      float pb[4];
#pragma unroll
      for (int n = 0; n < 4; n++) {
        const unsigned short* vp =
            vT + ((size_t)(bh * 64 + n * 16 + li)) * LL + k0;
        bv0[n] = *(const bf16x8*)&vp[g * 8];
        bv1[n] = *(const bf16x8*)&vp[32 + g * 8];
        pb[n] = (etype[b * LL + k0 + n * 16 + li] == 0) ? -1.0e9f : 0.f;
      }
      // S = Q K^T from swizzled LDS
      f32x4 s[4];
#pragma unroll
      for (int n = 0; n < 4; n++) {
        int rK = n * 16 + li;
        const unsigned short* kb = &Ks[cur][rK * 64];
        bf16x8 bk0 = *(const bf16x8*)&kb[(g ^ (rK & 7)) * 8];
        bf16x8 bk1 = *(const bf16x8*)&kb[((g + 4) ^ (rK & 7)) * 8];
        f32x4 a = (f32x4){0.f, 0.f, 0.f, 0.f};
        __builtin_amdgcn_s_setprio(1);
        a = __builtin_amdgcn_mfma_f32_16x16x32_bf16(aq0, bk0, a, 0, 0, 0);
        a = __builtin_amdgcn_mfma_f32_16x16x32_bf16(aq1, bk1, a, 0, 0, 0);
        __builtin_amdgcn_s_setprio(0);
        s[n] = a;
      }
      // scale + mask: fast path off-diagonal (pad bias only)
      if (j == qt) {
#pragma unroll
        for (int n = 0; n < 4; n++) {
          int key = k0 + n * 16 + li;
#pragma unroll
          for (int r = 0; r < 4; r++) {
            int qrow = q0 + w * 16 + g * 4 + r;
            float sv = fmaf(s[n][r], SC, pb[n]);
            if (key > qrow) sv = -1.0e9f;
            s[n][r] = sv;
          }
        }
      } else {
#pragma unroll
        for (int n = 0; n < 4; n++)
#pragma unroll
          for (int r = 0; r < 4; r++) s[n][r] = fmaf(s[n][r], SC, pb[n]);
      }
      // wave-parallel online softmax (reduce across 16 li lanes), exp2 domain
      float pm[4], corr[4], psum[4];
#pragma unroll
      for (int r = 0; r < 4; r++)
        pm[r] = fmaxf(fmaxf(s[0][r], s[1][r]), fmaxf(s[2][r], s[3][r]));
#pragma unroll
      for (int msk = 1; msk <= 8; msk <<= 1)
#pragma unroll
        for (int r = 0; r < 4; r++)
          pm[r] = fmaxf(pm[r], __shfl_xor(pm[r], msk, 64));
#pragma unroll
      for (int r = 0; r < 4; r++) {
        float mnew = fmaxf(mreg[r], pm[r]);
        corr[r] = exp2f_fast(mreg[r] - mnew);
        mreg[r] = mnew;
        float ps = 0.f;
#pragma unroll
        for (int n = 0; n < 4; n++) {
          float p = exp2f_fast(s[n][r] - mnew);
          s[n][r] = p;
          ps += p;
        }
        psum[r] = ps;
      }
#pragma unroll
      for (int msk = 1; msk <= 8; msk <<= 1)
#pragma unroll
        for (int r = 0; r < 4; r++) psum[r] += __shfl_xor(psum[r], msk, 64);
#pragma unroll
      for (int r = 0; r < 4; r++) lreg[r] = lreg[r] * corr[r] + psum[r];
      // P -> LDS (own-wave rows only; same-wave ordering via lgkmcnt)
#pragma unroll
      for (int n = 0; n < 4; n++)
#pragma unroll
        for (int r = 0; r < 4; r++)
          Ps[w * 16 + g * 4 + r][n * 16 + li] = f2b(s[n][r]);
      // rescale O
#pragma unroll
      for (int n = 0; n < 4; n++)
#pragma unroll
        for (int r = 0; r < 4; r++) o[n][r] *= corr[r];
      // PV: A = P rows (LDS), B = V frags (regs)
      bf16x8 ap0 = *(const bf16x8*)&Ps[w * 16 + li][g * 8];
      bf16x8 ap1 = *(const bf16x8*)&Ps[w * 16 + li][32 + g * 8];
      __builtin_amdgcn_s_setprio(1);
#pragma unroll
      for (int n = 0; n < 4; n++) {
        o[n] = __builtin_amdgcn_mfma_f32_16x16x32_bf16(ap0, bv0[n], o[n], 0, 0, 0);
        o[n] = __builtin_amdgcn_mfma_f32_16x16x32_bf16(ap1, bv1[n], o[n], 0, 0, 0);
      }
      __builtin_amdgcn_s_setprio(0);
      __syncthreads();  // drains prefetch (vmcnt) + Ks/Ps traffic
      cur ^= 1;
    }
  }
  // epilogue: l-normalized partial O (bf16) + per-row (m,l)
#pragma unroll
  for (int r = 0; r < 4; r++) {
    int qrl = w * 16 + g * 4 + r;
    float inv = (lreg[r] > 0.f) ? 1.0f / lreg[r] : 0.f;
#pragma unroll
    for (int n = 0; n < 4; n++)
      opart[((size_t)pidx * 64 + qrl) * 64 + n * 16 + li] = f2b(o[n][r] * inv);
    if (li == 0) {
      ml[(size_t)pidx * 128 + qrl] = mreg[r];
      ml[(size_t)pidx * 128 + 64 + qrl] = lreg[r];
    }
  }
}

// ---- merge the two key-split halves (packed 2-wide, static) ----
__global__ __launch_bounds__(256) void amerge_kernel(
    const unsigned short* __restrict__ opart, const float* __restrict__ ml,
    const float* __restrict__ meanVpart, unsigned short* __restrict__ ao) {
  int blk = blockIdx.x;  // bh*32 + qt  (1024 blocks)
  int bh = blk >> 5, qt = blk & 31;
  int b = bh >> 3, h = bh & 7;
  int tid = threadIdx.x;
  int d2 = (tid & 31) * 2;
  int pA = blk * 2, pB = blk * 2 + 1;
  for (int rr = tid >> 5; rr < 64; rr += 8) {
    float mA = ml[(size_t)pA * 128 + rr], lA = ml[(size_t)pA * 128 + 64 + rr];
    float mB = ml[(size_t)pB * 128 + rr], lB = ml[(size_t)pB * 128 + 64 + rr];
    float m = fmaxf(mA, mB);
    float v0, v1;
    if (m <= -1.0e8f) {
      // fully-masked row: uniform softmax over all keys = meanV
      float s0 = 0.f, s1 = 0.f;
      for (int cc = 0; cc < 32; cc++) {
        s0 += meanVpart[((size_t)bh * 32 + cc) * 64 + d2];
        s1 += meanVpart[((size_t)bh * 32 + cc) * 64 + d2 + 1];
      }
      v0 = s0 * (1.0f / (float)LL);
      v1 = s1 * (1.0f / (float)LL);
    } else {
      float a0 = 0.f, a1 = 0.f, wsum = 0.f;
      if (lA > 0.f) {
        float wA = exp2f_fast(mA - m) * lA;
        unsigned ua = *(const unsigned*)&opart[((size_t)pA * 64 + rr) * 64 + d2];
        a0 += b2f((unsigned short)ua) * wA;
        a1 += b2f((unsigned short)(ua >> 16)) * wA;
        wsum += wA;
      }
      if (lB > 0.f) {
        float wB = exp2f_fast(mB - m) * lB;
        unsigned ub = *(const unsigned*)&opart[((size_t)pB * 64 + rr) * 64 + d2];
        a0 += b2f((unsigned short)ub) * wB;
        a1 += b2f((unsigned short)(ub >> 16)) * wB;
        wsum += wB;
      }
      float inv = 1.0f / wsum;
      v0 = a0 * inv;
      v1 = a1 * inv;
    }
    int qr = qt * 64 + rr;
    *(unsigned*)&ao[(size_t)(b * LL + qr) * DD + h * 64 + d2] = pk2(v0, v1);
  }
}

// ---- LayerNorm (+npm), bf16 input. WF32: write fp32 out; WBF: write bf16;
// ADDTEM: also emit xa=x+tem (fp32) + xab (bf16). ----
template <bool ADDTEM, bool WF32, bool WBF>
__global__ __launch_bounds__(256) void ln_kernel(
    const unsigned short* __restrict__ in, const float* __restrict__ g,
    const float* __restrict__ bta, const float* __restrict__ npm,
    const float* __restrict__ tem, float* __restrict__ out,
    float* __restrict__ out2, unsigned short* __restrict__ out_bf) {
  __shared__ float red[4];
  int row = blockIdx.x;
  int tid = threadIdx.x;
  unsigned u = ((const unsigned*)(in + (size_t)row * DD))[tid];
  float v0 = b2f((unsigned short)u), v1 = b2f((unsigned short)(u >> 16));
  int e0 = tid * 2, e1 = tid * 2 + 1;
  float s = v0 + v1;
#pragma unroll
  for (int o = 32; o > 0; o >>= 1) s += __shfl_down(s, o, 64);
  if ((tid & 63) == 0) red[tid >> 6] = s;
  __syncthreads();
  float mean = (red[0] + red[1] + red[2] + red[3]) * (1.0f / (float)DD);
  float d0 = v0 - mean, d1 = v1 - mean;
  float sq = d0 * d0 + d1 * d1;
#pragma unroll
  for (int o = 32; o > 0; o >>= 1) sq += __shfl_down(sq, o, 64);
  __syncthreads();
  if ((tid & 63) == 0) red[tid >> 6] = sq;
  __syncthreads();
  float var = (red[0] + red[1] + red[2] + red[3]) * (1.0f / (float)DD);
  float rstd = rsqrtf(var + 1e-6f);
  float m = npm[row];
  float o0 = (d0 * rstd * g[e0] + bta[e0]) * m;
  float o1 = (d1 * rstd * g[e1] + bta[e1]) * m;
  if (WF32) ((float2*)(out + (size_t)row * DD))[tid] = make_float2(o0, o1);
  if (ADDTEM) {
    float2 tv = ((const float2*)(tem + (size_t)row * DD))[tid];
    float a0 = o0 + tv.x, a1 = o1 + tv.y;
    ((float2*)(out2 + (size_t)row * DD))[tid] = make_float2(a0, a1);
    ((unsigned*)(out_bf + (size_t)row * DD))[tid] = pk2(a0, a1);
  } else if (WBF) {
    ((unsigned*)(out_bf + (size_t)row * DD))[tid] = pk2(o0, o1);
  }
}

extern "C" void kernel_launch(void* const* d_in, const int* in_sizes, int n_in,
                              void* d_out, int out_size, void* d_ws,
                              size_t ws_size, hipStream_t stream) {
  const int* etype = (const int*)d_in[0];
  const float* etime = (const float*)d_in[1];
  const float* npm = (const float*)d_in[2];
  const float* emb = (const float*)d_in[3];
  const float* Wq = (const float*)d_in[4];
  const float* Wk = (const float*)d_in[5];
  const float* Wv = (const float*)d_in[6];
  const float* fc_w = (const float*)d_in[7];
  const float* fc_b = (const float*)d_in[8];
  const float* ln1_g = (const float*)d_in[9];
  const float* ln1_b = (const float*)d_in[10];
  const float* W1 = (const float*)d_in[11];
  const float* b1 = (const float*)d_in[12];
  const float* W2 = (const float*)d_in[13];
  const float* b2 = (const float*)d_in[14];
  const float* ln2_g = (const float*)d_in[15];
  const float* ln2_b = (const float*)d_in[16];

  float* x = (float*)d_out;
  char* ws = (char*)d_ws;
  const size_t SZF = (size_t)MM * DD * sizeof(float);
  const size_t SZB = (size_t)MM * DD * sizeof(short);
  float* tem = (float*)ws; ws += SZF;
  float* xa  = (float*)ws; ws += SZF;
  unsigned short* xab = (unsigned short*)ws; ws += SZB;
  unsigned short* xbf = (unsigned short*)ws; ws += SZB;
  unsigned short* qkv = (unsigned short*)ws; ws += (size_t)MM * 1536 * 2;
  unsigned short* vT  = (unsigned short*)ws; ws += (size_t)BB * NH * 64 * LL * 2;
  unsigned short* ao  = (unsigned short*)ws; ws += SZB;
  unsigned short* hb  = (unsigned short*)ws; ws += (size_t)MM * DINNER * 2;
  unsigned short* ybb = (unsigned short*)ws; ws += SZB;  // bf16 LN input
  unsigned short* qkvT = (unsigned short*)ws; ws += (size_t)NLAYERS * 1536 * 512 * 2;
  unsigned short* fcT  = (unsigned short*)ws; ws += (size_t)NLAYERS * 512 * 512 * 2;
  unsigned short* W1T  = (unsigned short*)ws; ws += (size_t)NLAYERS * 2048 * 512 * 2;
  unsigned short* W2T  = (unsigned short*)ws; ws += (size_t)NLAYERS * 512 * 2048 * 2;
  float* meanVpart = (float*)ws; ws += (size_t)32 * 32 * 64 * sizeof(float);
  unsigned short* opart = (unsigned short*)ws; ws += (size_t)2048 * 64 * 64 * 2;
  float* ml = (float*)ws; ws += (size_t)2048 * 128 * sizeof(float);

  init_kernel<<<MM, 512, 0, stream>>>(etype, etime, npm, emb, tem, xa, xab);

  wtrans_kernel<<<dim3(16, 16, NLAYERS), 256, 0, stream>>>(
      Wq, qkvT + 0 * 512 * 512, 512, 512, 512L * 512, 1536L * 512);
  wtrans_kernel<<<dim3(16, 16, NLAYERS), 256, 0, stream>>>(
      Wk, qkvT + 1 * 512 * 512, 512, 512, 512L * 512, 1536L * 512);
  wtrans_kernel<<<dim3(16, 16, NLAYERS), 256, 0, stream>>>(
      Wv, qkvT + 2 * 512 * 512, 512, 512, 512L * 512, 1536L * 512);
  wtrans_kernel<<<dim3(16, 16, NLAYERS), 256, 0, stream>>>(
      fc_w, fcT, 512, 512, 512L * 512, 512L * 512);
  wtrans_kernel<<<dim3(64, 16, NLAYERS), 256, 0, stream>>>(
      W1, W1T, 512, 2048, 512L * 2048, 2048L * 512);
  wtrans_kernel<<<dim3(16, 64, NLAYERS), 256, 0, stream>>>(
      W2, W2T, 2048, 512, 2048L * 512, 512L * 2048);

  for (int l = 0; l < NLAYERS; l++) {
    // QKV (grid 1536, 64x128 tiles)
    gemm_kernel<64, 128, false, false, false, true, false>
        <<<128 * 12, 256, 0, stream>>>(
            xab, qkvT + (size_t)l * 1536 * 512, nullptr, nullptr, 0, qkv, 1536,
            MM, 1536, 512);

    vtrans_kernel<<<dim3(32, 32), 256, 0, stream>>>(qkv, vT, meanVpart);
    attn_kernel<<<2048, 256, 0, stream>>>(qkv, vT, etype, opart, ml);
    amerge_kernel<<<1024, 256, 0, stream>>>(opart, ml, meanVpart, ao);

    // fc: +bias +residual(xa fp32) -> bf16 ybb   (grid 1024, 64x64 tiles)
    gemm_kernel<64, 64, true, true, false, true, false>
        <<<128 * 8, 256, 0, stream>>>(
            ao, fcT + (size_t)l * 512 * 512, fc_b + (size_t)l * 512, xa, 512,
            ybb, 512, MM, 512, 512);
    // LN1: bf16 out only
    ln_kernel<false, false, true><<<MM, 256, 0, stream>>>(
        ybb, ln1_g + (size_t)l * 512, ln1_b + (size_t)l * 512, npm, nullptr,
        nullptr, nullptr, xbf);

    // FFN1 (grid 2048, 64x128 tiles)
    gemm_kernel<64, 128, true, false, true, true, false>
        <<<128 * 16, 256, 0, stream>>>(
            xbf, W1T + (size_t)l * 2048 * 512, b1 + (size_t)l * 2048, nullptr,
            0, hb, 2048, MM, 2048, 512);
    // FFN2: +bias +residual(xbf bf16) -> bf16 ybb  (grid 1024, 64x64 tiles)
    gemm_kernel<64, 64, true, true, false, true, true>
        <<<128 * 8, 256, 0, stream>>>(
            hb, W2T + (size_t)l * 512 * 2048, b2 + (size_t)l * 512, xbf, 512,
            ybb, 512, MM, 512, 2048);
    if (l + 1 < NLAYERS) {
      // LN2: xa (fp32) + xab (bf16) for next layer
      ln_kernel<true, false, false><<<MM, 256, 0, stream>>>(
          ybb, ln2_g + (size_t)l * 512, ln2_b + (size_t)l * 512, npm, tem,
          nullptr, xa, xab);
    } else {
      // final layer: only the fp32 output x
      ln_kernel<false, true, false><<<MM, 256, 0, stream>>>(
          ybb, ln2_g + (size_t)l * 512, ln2_b + (size_t)l * 512, npm, nullptr,
          x, nullptr, nullptr);
    }
  }
}

// Round 19
// 901.676 us; speedup vs baseline: 1.1787x; 1.0333x over previous
//
#include <hip/hip_runtime.h>
#include <math.h>

#define BB 4
#define LL 2048
#define DD 512
#define NH 8
#define DINNER 2048
#define NLAYERS 4
#define MM (BB * LL)  // 8192

typedef __attribute__((ext_vector_type(8))) __bf16 bf16x8;
typedef __attribute__((ext_vector_type(4))) float f32x4;
typedef __attribute__((ext_vector_type(4))) unsigned short us4;

__device__ __forceinline__ unsigned short f2b(float f) {
  union { __bf16 h; unsigned short u; } v;
  v.h = (__bf16)f;  // native RNE convert
  return v.u;
}
__device__ __forceinline__ float b2f(unsigned short h) {
  union { unsigned u; float f; } v; v.u = ((unsigned)h) << 16; return v.f;
}
__device__ __forceinline__ unsigned pk2(float lo, float hi) {
  return (unsigned)f2b(lo) | ((unsigned)f2b(hi) << 16);
}
__device__ __forceinline__ float exp2f_fast(float x) {
  float r; asm("v_exp_f32 %0, %1" : "=v"(r) : "v"(x)); return r;
}

__device__ __forceinline__ void gload16(const void* g, void* l) {
  __builtin_amdgcn_global_load_lds(
      (const __attribute__((address_space(1))) void*)g,
      (__attribute__((address_space(3))) void*)l, 16, 0, 0);
}

// ---- init: temporal enc + embedding gather; emits xa = emb+tem directly ----
__global__ __launch_bounds__(512) void init_kernel(
    const int* __restrict__ etype, const float* __restrict__ etime,
    const float* __restrict__ npm, const float* __restrict__ emb,
    float* __restrict__ tem, float* __restrict__ xa,
    unsigned short* __restrict__ xab) {
  int row = blockIdx.x;
  int d = threadIdx.x;
  float t = etime[row];
  float mask = npm[row];
  int dd = d & ~1;
  float pv = expf(9.210340371976184f * ((float)dd * (1.0f / (float)DD)));
  float r = t / pv;
  float val = (d & 1) ? cosf(r) : sinf(r);
  float tv = val * mask;
  tem[(size_t)row * DD + d] = tv;
  int ty = etype[row];
  float a = emb[(size_t)ty * DD + d] + tv;
  xa[(size_t)row * DD + d] = a;
  xab[(size_t)row * DD + d] = f2b(a);
}

// ---------------- weight transpose+convert: fp32 [K][N] -> bf16 [N][K] ----
__global__ __launch_bounds__(256) void wtrans_kernel(
    const float* __restrict__ in, unsigned short* __restrict__ out,
    int K, int N, long in_ls, long out_ls) {
  __shared__ float t[32][33];
  int l = blockIdx.z;
  int n0 = blockIdx.x * 32, k0 = blockIdx.y * 32;
  int tx = threadIdx.x & 31, ty = threadIdx.x >> 5;
  const float* ip = in + (size_t)l * in_ls;
  unsigned short* op = out + (size_t)l * out_ls;
#pragma unroll
  for (int r = ty; r < 32; r += 8)
    t[r][tx] = ip[(size_t)(k0 + r) * N + n0 + tx];
  __syncthreads();
#pragma unroll
  for (int r = ty; r < 32; r += 8)
    op[(size_t)(n0 + r) * K + k0 + tx] = f2b(t[tx][r]);
}

// ---- MFMA GEMM, 2-phase pipelined, XCD-chunked 1D grid (T1 swizzle) ----
// C[M,N] = A(bf16 [M,K]) @ WT(bf16 [N,K])^T.  1D grid = (M/BM)*(N/BN),
// nwg % 8 == 0. BK in {32, 64}; BK=64 only for 64x64 tiles (halves the
// barrier count for latency-bound narrow-N shapes).
// RESB16: residual read as bf16 (packed) instead of fp32.
template <int BM, int BN, int BK, bool BIAS, bool RES, bool GELU_, bool OBF16,
          bool RESB16>
__global__ __launch_bounds__(256) void gemm_kernel(
    const unsigned short* __restrict__ A, const unsigned short* __restrict__ WT,
    const float* __restrict__ bias, const void* __restrict__ resv, int ldres,
    void* __restrict__ Cv, int ldc, int M, int N, int K) {
  __shared__ unsigned short As[2][BM * BK];
  __shared__ unsigned short Bs[2][BN * BK];
  constexpr int MT = (BM == 128) ? 4 : ((BN == 64) ? 2 : 4);
  constexpr int NT = (BM == 128 && BN == 128) ? 4 : 2;
  constexpr int KK = BK / 32;  // mfma K=32 sub-steps per k-step
  int tid = threadIdx.x;
  int w = tid >> 6, l = tid & 63;
  int li = l & 15, g = l >> 4;
  // XCD-chunked bijective remap (nwg divisible by 8)
  int nwg = gridDim.x;
  int bid = blockIdx.x;
  int wg = (bid & 7) * (nwg >> 3) + (bid >> 3);
  int gx = N / BN;
  int row0 = (wg / gx) * BM, col0 = (wg % gx) * BN;
  int wm = (BM == 128) ? (w & 1) * 64 : ((BN == 64) ? (w >> 1) * 32 : 0);
  int wnb = (BM == 128) ? (w >> 1) * 64 : ((BN == 64) ? (w & 1) * 32 : w * 32);
  f32x4 acc[MT][NT];
#pragma unroll
  for (int i = 0; i < MT; i++)
#pragma unroll
    for (int j = 0; j < NT; j++) acc[i][j] = (f32x4){0.f, 0.f, 0.f, 0.f};

  int lr = l >> 2;
  int lc = (l & 3) ^ (lr & 3);

  auto stage = [&](int bb, int kb) {
    int k0 = kb * BK;
    if (BK == 64) {
      // 64 rows x 8 chunks of 16B; src chunk XOR-swizzled per row
#pragma unroll
      for (int e = 0; e < 2; e++) {
        int slot = e * 256 + tid;
        int r = slot >> 3, c = slot & 7;
        int src = c ^ (r & 7);
        gload16(A + (size_t)(row0 + r) * K + k0 + src * 8,
                &As[bb][slot * 8]);
        gload16(WT + (size_t)(col0 + r) * K + k0 + src * 8,
                &Bs[bb][slot * 8]);
      }
    } else {
      if (BM == 128) {
#pragma unroll
        for (int i = 0; i < 2; i++) {
          int ai = w * 2 + i;
          gload16(A + (size_t)(row0 + ai * 16 + lr) * K + k0 + lc * 8,
                  &As[bb][ai * 512]);
        }
      } else {
        gload16(A + (size_t)(row0 + w * 16 + lr) * K + k0 + lc * 8,
                &As[bb][w * 512]);
      }
      if (BN == 128) {
#pragma unroll
        for (int i = 0; i < 2; i++) {
          int bi = w * 2 + i;
          gload16(WT + (size_t)(col0 + bi * 16 + lr) * K + k0 + lc * 8,
                  &Bs[bb][bi * 512]);
        }
      } else {
        gload16(WT + (size_t)(col0 + w * 16 + lr) * K + k0 + lc * 8,
                &Bs[bb][w * 512]);
      }
    }
  };

  int nk = K / BK;
  stage(0, 0);
  __syncthreads();
  int buf = 0;
  for (int kb = 0; kb < nk; kb++) {
    if (kb + 1 < nk) stage(buf ^ 1, kb + 1);
    bf16x8 af[MT][KK], bf_[NT][KK];
#pragma unroll
    for (int mt = 0; mt < MT; mt++) {
      int r = wm + mt * 16 + li;
#pragma unroll
      for (int kk = 0; kk < KK; kk++) {
        int off = (BK == 64) ? (r * 64 + ((((kk << 2) | g) ^ (r & 7)) * 8))
                             : (r * 32 + ((g ^ (r & 3)) * 8));
        af[mt][kk] = *(const bf16x8*)&As[buf][off];
      }
    }
#pragma unroll
    for (int nt = 0; nt < NT; nt++) {
      int r = wnb + nt * 16 + li;
#pragma unroll
      for (int kk = 0; kk < KK; kk++) {
        int off = (BK == 64) ? (r * 64 + ((((kk << 2) | g) ^ (r & 7)) * 8))
                             : (r * 32 + ((g ^ (r & 3)) * 8));
        bf_[nt][kk] = *(const bf16x8*)&Bs[buf][off];
      }
    }
#pragma unroll
    for (int kk = 0; kk < KK; kk++)
#pragma unroll
      for (int mt = 0; mt < MT; mt++)
#pragma unroll
        for (int nt = 0; nt < NT; nt++)
          acc[mt][nt] = __builtin_amdgcn_mfma_f32_16x16x32_bf16(
              af[mt][kk], bf_[nt][kk], acc[mt][nt], 0, 0, 0);
    __syncthreads();
    buf ^= 1;
  }
#pragma unroll
  for (int mt = 0; mt < MT; mt++) {
#pragma unroll
    for (int nt = 0; nt < NT; nt++) {
#pragma unroll
      for (int r = 0; r < 4; r++) {
        int row = row0 + wm + mt * 16 + g * 4 + r;
        int col = col0 + wnb + nt * 16 + li;
        float v = acc[mt][nt][r];
        if (BIAS) v += bias[col];
        if (RES) {
          if (RESB16)
            v += b2f(((const unsigned short*)resv)[(size_t)row * ldres + col]);
          else
            v += ((const float*)resv)[(size_t)row * ldres + col];
        }
        if (GELU_) v = 0.5f * v * (1.0f + erff(v * 0.70710678118654752f));
        if (OBF16)
          ((unsigned short*)Cv)[(size_t)row * ldc + col] = f2b(v);
        else
          ((float*)Cv)[(size_t)row * ldc + col] = v;
      }
    }
  }
}

// ---- transpose v slice -> vT [bh*64+d][L] + fused meanV partial sums ----
// grid (32 L-chunks, 32 bh). Partial sum per (bh, chunk) over its 64 keys.
__global__ __launch_bounds__(256) void vtrans_kernel(
    const unsigned short* __restrict__ qkv, unsigned short* __restrict__ vT,
    float* __restrict__ meanVpart) {
  __shared__ unsigned short t[64][65];
  __shared__ float red[4][64];
  int bh = blockIdx.y;
  int b = bh >> 3, h = bh & 7;
  int l0 = blockIdx.x * 64;
  int tid = threadIdx.x;
  int rr = tid >> 4, c4 = (tid & 15) * 4;
#pragma unroll
  for (int pass = 0; pass < 4; pass++) {
    int r = pass * 16 + rr;
    us4 v = *(const us4*)&qkv[(size_t)(b * LL + l0 + r) * 1536 + 1024 +
                              h * 64 + c4];
    t[r][c4] = v[0];
    t[r][c4 + 1] = v[1];
    t[r][c4 + 2] = v[2];
    t[r][c4 + 3] = v[3];
  }
  __syncthreads();
#pragma unroll
  for (int pass = 0; pass < 4; pass++) {
    int r = pass * 16 + rr;  // vT row (d)
    us4 v = {t[c4][r], t[c4 + 1][r], t[c4 + 2][r], t[c4 + 3][r]};
    *(us4*)&vT[((size_t)bh * 64 + r) * LL + l0 + c4] = v;
  }
  // fused meanV partial: sum over this chunk's 64 keys per d
  int p = tid >> 6, d = tid & 63;
  float s = 0.f;
#pragma unroll
  for (int i = 0; i < 16; i++) s += b2f(t[p * 16 + i][d]);
  red[p][d] = s;
  __syncthreads();
  if (p == 0)
    meanVpart[((size_t)bh * 32 + blockIdx.x) * 64 + d] =
        red[0][d] + red[1][d] + red[2][d] + red[3][d];
}

// ---- MFMA flash attention, 2-way KEY-SPLIT (r10 proven structure) ----
__global__ __launch_bounds__(256) void attn_kernel(
    const unsigned short* __restrict__ qkv, const unsigned short* __restrict__ vT,
    const int* __restrict__ etype, unsigned short* __restrict__ opart,
    float* __restrict__ ml) {
  __shared__ unsigned short Ks[2][64 * 64];  // [buf][key*64+d], swizzled 8KB
  __shared__ unsigned short Ps[64][72];
  int hwbid = blockIdx.x;
  int work = (hwbid & 7) * 256 + (hwbid >> 3);  // XCD-chunked (bijective)
  int bh = work >> 6;
  int rem = work & 63;
  int qt = 31 - (rem >> 1);  // LPT: big q-tiles first
  int half = rem & 1;
  int h = bh & 7, b = bh >> 3;
  int q0 = qt * 64;
  int nt = qt + 1;
  int ha = (nt + 1) >> 1;  // half A gets ceil(nt/2), always nonempty
  int j0 = half ? ha : 0;
  int j1 = half ? nt : ha;
  int pidx = (bh * 32 + qt) * 2 + half;
  int tid = threadIdx.x, w = tid >> 6, l = tid & 63;
  int g = l >> 4, li = l & 15;
  const float SC = 0.125f * 1.44269504f;  // scale * log2(e)

  f32x4 o[4];
#pragma unroll
  for (int n = 0; n < 4; n++) o[n] = (f32x4){0.f, 0.f, 0.f, 0.f};
  float mreg[4], lreg[4];
#pragma unroll
  for (int r = 0; r < 4; r++) { mreg[r] = -3.0e38f; lreg[r] = 0.f; }

  if (j0 < j1) {
    const unsigned short* qrp =
        qkv + (size_t)(b * LL + q0 + w * 16 + li) * 1536 + h * 64;
    bf16x8 aq0 = *(const bf16x8*)&qrp[g * 8];
    bf16x8 aq1 = *(const bf16x8*)&qrp[32 + g * 8];

    // prologue: stage tile j0 into buf 0
#pragma unroll
    for (int e = 0; e < 2; e++) {
      int idx = e * 256 + tid;
      int r = idx >> 3;
      int src = (l & 7) ^ (r & 7);
      gload16(
          qkv + (size_t)(b * LL + j0 * 64 + r) * 1536 + 512 + h * 64 + src * 8,
          &Ks[0][(e * 256 + w * 64) * 8]);
    }
    __syncthreads();

    int cur = 0;
    for (int j = j0; j < j1; j++) {
      int k0 = j << 6;
      if (j + 1 < j1) {
#pragma unroll
        for (int e = 0; e < 2; e++) {
          int idx = e * 256 + tid;
          int r = idx >> 3;
          int src = (l & 7) ^ (r & 7);
          gload16(qkv + (size_t)(b * LL + k0 + 64 + r) * 1536 + 512 + h * 64 +
                      src * 8,
                  &Ks[cur ^ 1][(e * 256 + w * 64) * 8]);
        }
      }
      // V frags + pad bias, issued early (L2-resident)
      bf16x8 bv0[4], bv1[4];
      float pb[4];
#pragma unroll
      for (int n = 0; n < 4; n++) {
        const unsigned short* vp =
            vT + ((size_t)(bh * 64 + n * 16 + li)) * LL + k0;
        bv0[n] = *(const bf16x8*)&vp[g * 8];
        bv1[n] = *(const bf16x8*)&vp[32 + g * 8];
        pb[n] = (etype[b * LL + k0 + n * 16 + li] == 0) ? -1.0e9f : 0.f;
      }
      // S = Q K^T from swizzled LDS
      f32x4 s[4];
#pragma unroll
      for (int n = 0; n < 4; n++) {
        int rK = n * 16 + li;
        const unsigned short* kb = &Ks[cur][rK * 64];
        bf16x8 bk0 = *(const bf16x8*)&kb[(g ^ (rK & 7)) * 8];
        bf16x8 bk1 = *(const bf16x8*)&kb[((g + 4) ^ (rK & 7)) * 8];
        f32x4 a = (f32x4){0.f, 0.f, 0.f, 0.f};
        __builtin_amdgcn_s_setprio(1);
        a = __builtin_amdgcn_mfma_f32_16x16x32_bf16(aq0, bk0, a, 0, 0, 0);
        a = __builtin_amdgcn_mfma_f32_16x16x32_bf16(aq1, bk1, a, 0, 0, 0);
        __builtin_amdgcn_s_setprio(0);
        s[n] = a;
      }
      // scale + mask: fast path off-diagonal (pad bias only)
      if (j == qt) {
#pragma unroll
        for (int n = 0; n < 4; n++) {
          int key = k0 + n * 16 + li;
#pragma unroll
          for (int r = 0; r < 4; r++) {
            int qrow = q0 + w * 16 + g * 4 + r;
            float sv = fmaf(s[n][r], SC, pb[n]);
            if (key > qrow) sv = -1.0e9f;
            s[n][r] = sv;
          }
        }
      } else {
#pragma unroll
        for (int n = 0; n < 4; n++)
#pragma unroll
          for (int r = 0; r < 4; r++) s[n][r] = fmaf(s[n][r], SC, pb[n]);
      }
      // wave-parallel online softmax (reduce across 16 li lanes), exp2 domain
      float pm[4], corr[4], psum[4];
#pragma unroll
      for (int r = 0; r < 4; r++)
        pm[r] = fmaxf(fmaxf(s[0][r], s[1][r]), fmaxf(s[2][r], s[3][r]));
#pragma unroll
      for (int msk = 1; msk <= 8; msk <<= 1)
#pragma unroll
        for (int r = 0; r < 4; r++)
          pm[r] = fmaxf(pm[r], __shfl_xor(pm[r], msk, 64));
#pragma unroll
      for (int r = 0; r < 4; r++) {
        float mnew = fmaxf(mreg[r], pm[r]);
        corr[r] = exp2f_fast(mreg[r] - mnew);
        mreg[r] = mnew;
        float ps = 0.f;
#pragma unroll
        for (int n = 0; n < 4; n++) {
          float p = exp2f_fast(s[n][r] - mnew);
          s[n][r] = p;
          ps += p;
        }
        psum[r] = ps;
      }
#pragma unroll
      for (int msk = 1; msk <= 8; msk <<= 1)
#pragma unroll
        for (int r = 0; r < 4; r++) psum[r] += __shfl_xor(psum[r], msk, 64);
#pragma unroll
      for (int r = 0; r < 4; r++) lreg[r] = lreg[r] * corr[r] + psum[r];
      // P -> LDS (own-wave rows only; same-wave ordering via lgkmcnt)
#pragma unroll
      for (int n = 0; n < 4; n++)
#pragma unroll
        for (int r = 0; r < 4; r++)
          Ps[w * 16 + g * 4 + r][n * 16 + li] = f2b(s[n][r]);
      // rescale O
#pragma unroll
      for (int n = 0; n < 4; n++)
#pragma unroll
        for (int r = 0; r < 4; r++) o[n][r] *= corr[r];
      // PV: A = P rows (LDS), B = V frags (regs)
      bf16x8 ap0 = *(const bf16x8*)&Ps[w * 16 + li][g * 8];
      bf16x8 ap1 = *(const bf16x8*)&Ps[w * 16 + li][32 + g * 8];
      __builtin_amdgcn_s_setprio(1);
#pragma unroll
      for (int n = 0; n < 4; n++) {
        o[n] = __builtin_amdgcn_mfma_f32_16x16x32_bf16(ap0, bv0[n], o[n], 0, 0, 0);
        o[n] = __builtin_amdgcn_mfma_f32_16x16x32_bf16(ap1, bv1[n], o[n], 0, 0, 0);
      }
      __builtin_amdgcn_s_setprio(0);
      __syncthreads();  // drains prefetch (vmcnt) + Ks/Ps traffic
      cur ^= 1;
    }
  }
  // epilogue: l-normalized partial O (bf16) + per-row (m,l)
#pragma unroll
  for (int r = 0; r < 4; r++) {
    int qrl = w * 16 + g * 4 + r;
    float inv = (lreg[r] > 0.f) ? 1.0f / lreg[r] : 0.f;
#pragma unroll
    for (int n = 0; n < 4; n++)
      opart[((size_t)pidx * 64 + qrl) * 64 + n * 16 + li] = f2b(o[n][r] * inv);
    if (li == 0) {
      ml[(size_t)pidx * 128 + qrl] = mreg[r];
      ml[(size_t)pidx * 128 + 64 + qrl] = lreg[r];
    }
  }
}

// ---- merge the two key-split halves (packed 2-wide, static) ----
__global__ __launch_bounds__(256) void amerge_kernel(
    const unsigned short* __restrict__ opart, const float* __restrict__ ml,
    const float* __restrict__ meanVpart, unsigned short* __restrict__ ao) {
  int blk = blockIdx.x;  // bh*32 + qt  (1024 blocks)
  int bh = blk >> 5, qt = blk & 31;
  int b = bh >> 3, h = bh & 7;
  int tid = threadIdx.x;
  int d2 = (tid & 31) * 2;
  int pA = blk * 2, pB = blk * 2 + 1;
  for (int rr = tid >> 5; rr < 64; rr += 8) {
    float mA = ml[(size_t)pA * 128 + rr], lA = ml[(size_t)pA * 128 + 64 + rr];
    float mB = ml[(size_t)pB * 128 + rr], lB = ml[(size_t)pB * 128 + 64 + rr];
    float m = fmaxf(mA, mB);
    float v0, v1;
    if (m <= -1.0e8f) {
      // fully-masked row: uniform softmax over all keys = meanV
      float s0 = 0.f, s1 = 0.f;
      for (int cc = 0; cc < 32; cc++) {
        s0 += meanVpart[((size_t)bh * 32 + cc) * 64 + d2];
        s1 += meanVpart[((size_t)bh * 32 + cc) * 64 + d2 + 1];
      }
      v0 = s0 * (1.0f / (float)LL);
      v1 = s1 * (1.0f / (float)LL);
    } else {
      float a0 = 0.f, a1 = 0.f, wsum = 0.f;
      if (lA > 0.f) {
        float wA = exp2f_fast(mA - m) * lA;
        unsigned ua = *(const unsigned*)&opart[((size_t)pA * 64 + rr) * 64 + d2];
        a0 += b2f((unsigned short)ua) * wA;
        a1 += b2f((unsigned short)(ua >> 16)) * wA;
        wsum += wA;
      }
      if (lB > 0.f) {
        float wB = exp2f_fast(mB - m) * lB;
        unsigned ub = *(const unsigned*)&opart[((size_t)pB * 64 + rr) * 64 + d2];
        a0 += b2f((unsigned short)ub) * wB;
        a1 += b2f((unsigned short)(ub >> 16)) * wB;
        wsum += wB;
      }
      float inv = 1.0f / wsum;
      v0 = a0 * inv;
      v1 = a1 * inv;
    }
    int qr = qt * 64 + rr;
    *(unsigned*)&ao[(size_t)(b * LL + qr) * DD + h * 64 + d2] = pk2(v0, v1);
  }
}

// ---- LayerNorm (+npm), bf16 input. WF32: write fp32 out; WBF: write bf16;
// ADDTEM: also emit xa=x+tem (fp32) + xab (bf16). ----
template <bool ADDTEM, bool WF32, bool WBF>
__global__ __launch_bounds__(256) void ln_kernel(
    const unsigned short* __restrict__ in, const float* __restrict__ g,
    const float* __restrict__ bta, const float* __restrict__ npm,
    const float* __restrict__ tem, float* __restrict__ out,
    float* __restrict__ out2, unsigned short* __restrict__ out_bf) {
  __shared__ float red[4];
  int row = blockIdx.x;
  int tid = threadIdx.x;
  unsigned u = ((const unsigned*)(in + (size_t)row * DD))[tid];
  float v0 = b2f((unsigned short)u), v1 = b2f((unsigned short)(u >> 16));
  int e0 = tid * 2, e1 = tid * 2 + 1;
  float s = v0 + v1;
#pragma unroll
  for (int o = 32; o > 0; o >>= 1) s += __shfl_down(s, o, 64);
  if ((tid & 63) == 0) red[tid >> 6] = s;
  __syncthreads();
  float mean = (red[0] + red[1] + red[2] + red[3]) * (1.0f / (float)DD);
  float d0 = v0 - mean, d1 = v1 - mean;
  float sq = d0 * d0 + d1 * d1;
#pragma unroll
  for (int o = 32; o > 0; o >>= 1) sq += __shfl_down(sq, o, 64);
  __syncthreads();
  if ((tid & 63) == 0) red[tid >> 6] = sq;
  __syncthreads();
  float var = (red[0] + red[1] + red[2] + red[3]) * (1.0f / (float)DD);
  float rstd = rsqrtf(var + 1e-6f);
  float m = npm[row];
  float o0 = (d0 * rstd * g[e0] + bta[e0]) * m;
  float o1 = (d1 * rstd * g[e1] + bta[e1]) * m;
  if (WF32) ((float2*)(out + (size_t)row * DD))[tid] = make_float2(o0, o1);
  if (ADDTEM) {
    float2 tv = ((const float2*)(tem + (size_t)row * DD))[tid];
    float a0 = o0 + tv.x, a1 = o1 + tv.y;
    ((float2*)(out2 + (size_t)row * DD))[tid] = make_float2(a0, a1);
    ((unsigned*)(out_bf + (size_t)row * DD))[tid] = pk2(a0, a1);
  } else if (WBF) {
    ((unsigned*)(out_bf + (size_t)row * DD))[tid] = pk2(o0, o1);
  }
}

extern "C" void kernel_launch(void* const* d_in, const int* in_sizes, int n_in,
                              void* d_out, int out_size, void* d_ws,
                              size_t ws_size, hipStream_t stream) {
  const int* etype = (const int*)d_in[0];
  const float* etime = (const float*)d_in[1];
  const float* npm = (const float*)d_in[2];
  const float* emb = (const float*)d_in[3];
  const float* Wq = (const float*)d_in[4];
  const float* Wk = (const float*)d_in[5];
  const float* Wv = (const float*)d_in[6];
  const float* fc_w = (const float*)d_in[7];
  const float* fc_b = (const float*)d_in[8];
  const float* ln1_g = (const float*)d_in[9];
  const float* ln1_b = (const float*)d_in[10];
  const float* W1 = (const float*)d_in[11];
  const float* b1 = (const float*)d_in[12];
  const float* W2 = (const float*)d_in[13];
  const float* b2 = (const float*)d_in[14];
  const float* ln2_g = (const float*)d_in[15];
  const float* ln2_b = (const float*)d_in[16];

  float* x = (float*)d_out;
  char* ws = (char*)d_ws;
  const size_t SZF = (size_t)MM * DD * sizeof(float);
  const size_t SZB = (size_t)MM * DD * sizeof(short);
  float* tem = (float*)ws; ws += SZF;
  float* xa  = (float*)ws; ws += SZF;
  unsigned short* xab = (unsigned short*)ws; ws += SZB;
  unsigned short* xbf = (unsigned short*)ws; ws += SZB;
  unsigned short* qkv = (unsigned short*)ws; ws += (size_t)MM * 1536 * 2;
  unsigned short* vT  = (unsigned short*)ws; ws += (size_t)BB * NH * 64 * LL * 2;
  unsigned short* ao  = (unsigned short*)ws; ws += SZB;
  unsigned short* hb  = (unsigned short*)ws; ws += (size_t)MM * DINNER * 2;
  unsigned short* ybb = (unsigned short*)ws; ws += SZB;  // bf16 LN input
  unsigned short* qkvT = (unsigned short*)ws; ws += (size_t)NLAYERS * 1536 * 512 * 2;
  unsigned short* fcT  = (unsigned short*)ws; ws += (size_t)NLAYERS * 512 * 512 * 2;
  unsigned short* W1T  = (unsigned short*)ws; ws += (size_t)NLAYERS * 2048 * 512 * 2;
  unsigned short* W2T  = (unsigned short*)ws; ws += (size_t)NLAYERS * 512 * 2048 * 2;
  float* meanVpart = (float*)ws; ws += (size_t)32 * 32 * 64 * sizeof(float);
  unsigned short* opart = (unsigned short*)ws; ws += (size_t)2048 * 64 * 64 * 2;
  float* ml = (float*)ws; ws += (size_t)2048 * 128 * sizeof(float);

  init_kernel<<<MM, 512, 0, stream>>>(etype, etime, npm, emb, tem, xa, xab);

  wtrans_kernel<<<dim3(16, 16, NLAYERS), 256, 0, stream>>>(
      Wq, qkvT + 0 * 512 * 512, 512, 512, 512L * 512, 1536L * 512);
  wtrans_kernel<<<dim3(16, 16, NLAYERS), 256, 0, stream>>>(
      Wk, qkvT + 1 * 512 * 512, 512, 512, 512L * 512, 1536L * 512);
  wtrans_kernel<<<dim3(16, 16, NLAYERS), 256, 0, stream>>>(
      Wv, qkvT + 2 * 512 * 512, 512, 512, 512L * 512, 1536L * 512);
  wtrans_kernel<<<dim3(16, 16, NLAYERS), 256, 0, stream>>>(
      fc_w, fcT, 512, 512, 512L * 512, 512L * 512);
  wtrans_kernel<<<dim3(64, 16, NLAYERS), 256, 0, stream>>>(
      W1, W1T, 512, 2048, 512L * 2048, 2048L * 512);
  wtrans_kernel<<<dim3(16, 64, NLAYERS), 256, 0, stream>>>(
      W2, W2T, 2048, 512, 2048L * 512, 512L * 2048);

  for (int l = 0; l < NLAYERS; l++) {
    // QKV (grid 1536, 64x128 tiles, BK=32)
    gemm_kernel<64, 128, 32, false, false, false, true, false>
        <<<128 * 12, 256, 0, stream>>>(
            xab, qkvT + (size_t)l * 1536 * 512, nullptr, nullptr, 0, qkv, 1536,
            MM, 1536, 512);

    vtrans_kernel<<<dim3(32, 32), 256, 0, stream>>>(qkv, vT, meanVpart);
    attn_kernel<<<2048, 256, 0, stream>>>(qkv, vT, etype, opart, ml);
    amerge_kernel<<<1024, 256, 0, stream>>>(opart, ml, meanVpart, ao);

    // fc: +bias +residual(xa fp32) -> bf16 ybb (grid 1024, 64x64, BK=64)
    gemm_kernel<64, 64, 64, true, true, false, true, false>
        <<<128 * 8, 256, 0, stream>>>(
            ao, fcT + (size_t)l * 512 * 512, fc_b + (size_t)l * 512, xa, 512,
            ybb, 512, MM, 512, 512);
    // LN1: bf16 out only
    ln_kernel<false, false, true><<<MM, 256, 0, stream>>>(
        ybb, ln1_g + (size_t)l * 512, ln1_b + (size_t)l * 512, npm, nullptr,
        nullptr, nullptr, xbf);

    // FFN1 (grid 2048, 64x128 tiles, BK=32)
    gemm_kernel<64, 128, 32, true, false, true, true, false>
        <<<128 * 16, 256, 0, stream>>>(
            xbf, W1T + (size_t)l * 2048 * 512, b1 + (size_t)l * 2048, nullptr,
            0, hb, 2048, MM, 2048, 512);
    // FFN2: +bias +residual(xbf bf16) -> bf16 ybb (grid 1024, 64x64, BK=64)
    gemm_kernel<64, 64, 64, true, true, false, true, true>
        <<<128 * 8, 256, 0, stream>>>(
            hb, W2T + (size_t)l * 512 * 2048, b2 + (size_t)l * 512, xbf, 512,
            ybb, 512, MM, 512, 2048);
    if (l + 1 < NLAYERS) {
      // LN2: xa (fp32) + xab (bf16) for next layer
      ln_kernel<true, false, false><<<MM, 256, 0, stream>>>(
          ybb, ln2_g + (size_t)l * 512, ln2_b + (size_t)l * 512, npm, tem,
          nullptr, xa, xab);
    } else {
      // final layer: only the fp32 output x
      ln_kernel<false, true, false><<<MM, 256, 0, stream>>>(
          ybb, ln2_g + (size_t)l * 512, ln2_b + (size_t)l * 512, npm, nullptr,
          x, nullptr, nullptr);
    }
  }
}

// Round 20
// 886.923 us; speedup vs baseline: 1.1983x; 1.0166x over previous
//
#include <hip/hip_runtime.h>
#include <math.h>

#define BB 4
#define LL 2048
#define DD 512
#define NH 8
#define DINNER 2048
#define NLAYERS 4
#define MM (BB * LL)  // 8192

typedef __attribute__((ext_vector_type(8))) __bf16 bf16x8;
typedef __attribute__((ext_vector_type(4))) float f32x4;
typedef __attribute__((ext_vector_type(4))) unsigned short us4;

__device__ __forceinline__ unsigned short f2b(float f) {
  union { __bf16 h; unsigned short u; } v;
  v.h = (__bf16)f;  // native RNE convert
  return v.u;
}
__device__ __forceinline__ float b2f(unsigned short h) {
  union { unsigned u; float f; } v; v.u = ((unsigned)h) << 16; return v.f;
}
__device__ __forceinline__ unsigned pk2(float lo, float hi) {
  return (unsigned)f2b(lo) | ((unsigned)f2b(hi) << 16);
}
__device__ __forceinline__ float exp2f_fast(float x) {
  float r; asm("v_exp_f32 %0, %1" : "=v"(r) : "v"(x)); return r;
}

__device__ __forceinline__ void gload16(const void* g, void* l) {
  __builtin_amdgcn_global_load_lds(
      (const __attribute__((address_space(1))) void*)g,
      (__attribute__((address_space(3))) void*)l, 16, 0, 0);
}

// ---- init: temporal enc + embedding gather; emits xa = emb+tem directly ----
__global__ __launch_bounds__(512) void init_kernel(
    const int* __restrict__ etype, const float* __restrict__ etime,
    const float* __restrict__ npm, const float* __restrict__ emb,
    float* __restrict__ tem, float* __restrict__ xa,
    unsigned short* __restrict__ xab) {
  int row = blockIdx.x;
  int d = threadIdx.x;
  float t = etime[row];
  float mask = npm[row];
  int dd = d & ~1;
  float pv = expf(9.210340371976184f * ((float)dd * (1.0f / (float)DD)));
  float r = t / pv;
  float val = (d & 1) ? cosf(r) : sinf(r);
  float tv = val * mask;
  tem[(size_t)row * DD + d] = tv;
  int ty = etype[row];
  float a = emb[(size_t)ty * DD + d] + tv;
  xa[(size_t)row * DD + d] = a;
  xab[(size_t)row * DD + d] = f2b(a);
}

// ---- weight transpose+convert (vectorized): fp32 [K][N] -> bf16 [N][K] ----
// 256 threads per 32x32 tile: one float4 load + one us4 store per thread.
__global__ __launch_bounds__(256) void wtrans_kernel(
    const float* __restrict__ in, unsigned short* __restrict__ out,
    int K, int N, long in_ls, long out_ls) {
  __shared__ unsigned short t[32][36];
  int l = blockIdx.z;
  int n0 = blockIdx.x * 32, k0 = blockIdx.y * 32;
  int tid = threadIdx.x;
  int r = tid >> 3, c4 = (tid & 7) * 4;
  const float* ip = in + (size_t)l * in_ls;
  unsigned short* op = out + (size_t)l * out_ls;
  float4 v = *(const float4*)&ip[(size_t)(k0 + r) * N + n0 + c4];
  t[r][c4] = f2b(v.x);
  t[r][c4 + 1] = f2b(v.y);
  t[r][c4 + 2] = f2b(v.z);
  t[r][c4 + 3] = f2b(v.w);
  __syncthreads();
  us4 o = {t[c4][r], t[c4 + 1][r], t[c4 + 2][r], t[c4 + 3][r]};
  *(us4*)&op[(size_t)(n0 + r) * K + k0 + c4] = o;
}

// ---- MFMA GEMM, 2-phase pipelined, XCD-chunked 1D grid (T1 swizzle) ----
// C[M,N] = A(bf16 [M,K]) @ WT(bf16 [N,K])^T.  1D grid = (M/BM)*(N/BN),
// nwg % 8 == 0. BK in {32, 64}; BK=64 only for 64x64 tiles (halves the
// barrier count for latency-bound shapes).
// RESB16: residual read as bf16 (packed) instead of fp32.
template <int BM, int BN, int BK, bool BIAS, bool RES, bool GELU_, bool OBF16,
          bool RESB16>
__global__ __launch_bounds__(256) void gemm_kernel(
    const unsigned short* __restrict__ A, const unsigned short* __restrict__ WT,
    const float* __restrict__ bias, const void* __restrict__ resv, int ldres,
    void* __restrict__ Cv, int ldc, int M, int N, int K) {
  __shared__ unsigned short As[2][BM * BK];
  __shared__ unsigned short Bs[2][BN * BK];
  constexpr int MT = (BM == 128) ? 4 : ((BN == 64) ? 2 : 4);
  constexpr int NT = (BM == 128 && BN == 128) ? 4 : 2;
  constexpr int KK = BK / 32;  // mfma K=32 sub-steps per k-step
  int tid = threadIdx.x;
  int w = tid >> 6, l = tid & 63;
  int li = l & 15, g = l >> 4;
  // XCD-chunked bijective remap (nwg divisible by 8)
  int nwg = gridDim.x;
  int bid = blockIdx.x;
  int wg = (bid & 7) * (nwg >> 3) + (bid >> 3);
  int gx = N / BN;
  int row0 = (wg / gx) * BM, col0 = (wg % gx) * BN;
  int wm = (BM == 128) ? (w & 1) * 64 : ((BN == 64) ? (w >> 1) * 32 : 0);
  int wnb = (BM == 128) ? (w >> 1) * 64 : ((BN == 64) ? (w & 1) * 32 : w * 32);
  f32x4 acc[MT][NT];
#pragma unroll
  for (int i = 0; i < MT; i++)
#pragma unroll
    for (int j = 0; j < NT; j++) acc[i][j] = (f32x4){0.f, 0.f, 0.f, 0.f};

  int lr = l >> 2;
  int lc = (l & 3) ^ (lr & 3);

  auto stage = [&](int bb, int kb) {
    int k0 = kb * BK;
    if (BK == 64) {
      // 64 rows x 8 chunks of 16B; src chunk XOR-swizzled per row
#pragma unroll
      for (int e = 0; e < 2; e++) {
        int slot = e * 256 + tid;
        int r = slot >> 3, c = slot & 7;
        int src = c ^ (r & 7);
        gload16(A + (size_t)(row0 + r) * K + k0 + src * 8,
                &As[bb][slot * 8]);
        gload16(WT + (size_t)(col0 + r) * K + k0 + src * 8,
                &Bs[bb][slot * 8]);
      }
    } else {
      if (BM == 128) {
#pragma unroll
        for (int i = 0; i < 2; i++) {
          int ai = w * 2 + i;
          gload16(A + (size_t)(row0 + ai * 16 + lr) * K + k0 + lc * 8,
                  &As[bb][ai * 512]);
        }
      } else {
        gload16(A + (size_t)(row0 + w * 16 + lr) * K + k0 + lc * 8,
                &As[bb][w * 512]);
      }
      if (BN == 128) {
#pragma unroll
        for (int i = 0; i < 2; i++) {
          int bi = w * 2 + i;
          gload16(WT + (size_t)(col0 + bi * 16 + lr) * K + k0 + lc * 8,
                  &Bs[bb][bi * 512]);
        }
      } else {
        gload16(WT + (size_t)(col0 + w * 16 + lr) * K + k0 + lc * 8,
                &Bs[bb][w * 512]);
      }
    }
  };

  int nk = K / BK;
  stage(0, 0);
  __syncthreads();
  int buf = 0;
  for (int kb = 0; kb < nk; kb++) {
    if (kb + 1 < nk) stage(buf ^ 1, kb + 1);
    bf16x8 af[MT][KK], bf_[NT][KK];
#pragma unroll
    for (int mt = 0; mt < MT; mt++) {
      int r = wm + mt * 16 + li;
#pragma unroll
      for (int kk = 0; kk < KK; kk++) {
        int off = (BK == 64) ? (r * 64 + ((((kk << 2) | g) ^ (r & 7)) * 8))
                             : (r * 32 + ((g ^ (r & 3)) * 8));
        af[mt][kk] = *(const bf16x8*)&As[buf][off];
      }
    }
#pragma unroll
    for (int nt = 0; nt < NT; nt++) {
      int r = wnb + nt * 16 + li;
#pragma unroll
      for (int kk = 0; kk < KK; kk++) {
        int off = (BK == 64) ? (r * 64 + ((((kk << 2) | g) ^ (r & 7)) * 8))
                             : (r * 32 + ((g ^ (r & 3)) * 8));
        bf_[nt][kk] = *(const bf16x8*)&Bs[buf][off];
      }
    }
#pragma unroll
    for (int kk = 0; kk < KK; kk++)
#pragma unroll
      for (int mt = 0; mt < MT; mt++)
#pragma unroll
        for (int nt = 0; nt < NT; nt++)
          acc[mt][nt] = __builtin_amdgcn_mfma_f32_16x16x32_bf16(
              af[mt][kk], bf_[nt][kk], acc[mt][nt], 0, 0, 0);
    __syncthreads();
    buf ^= 1;
  }
#pragma unroll
  for (int mt = 0; mt < MT; mt++) {
#pragma unroll
    for (int nt = 0; nt < NT; nt++) {
#pragma unroll
      for (int r = 0; r < 4; r++) {
        int row = row0 + wm + mt * 16 + g * 4 + r;
        int col = col0 + wnb + nt * 16 + li;
        float v = acc[mt][nt][r];
        if (BIAS) v += bias[col];
        if (RES) {
          if (RESB16)
            v += b2f(((const unsigned short*)resv)[(size_t)row * ldres + col]);
          else
            v += ((const float*)resv)[(size_t)row * ldres + col];
        }
        if (GELU_) v = 0.5f * v * (1.0f + erff(v * 0.70710678118654752f));
        if (OBF16)
          ((unsigned short*)Cv)[(size_t)row * ldc + col] = f2b(v);
        else
          ((float*)Cv)[(size_t)row * ldc + col] = v;
      }
    }
  }
}

// ---- transpose v slice -> vT [bh*64+d][L] + fused meanV partial sums ----
// grid (32 L-chunks, 32 bh). Partial sum per (bh, chunk) over its 64 keys.
__global__ __launch_bounds__(256) void vtrans_kernel(
    const unsigned short* __restrict__ qkv, unsigned short* __restrict__ vT,
    float* __restrict__ meanVpart) {
  __shared__ unsigned short t[64][65];
  __shared__ float red[4][64];
  int bh = blockIdx.y;
  int b = bh >> 3, h = bh & 7;
  int l0 = blockIdx.x * 64;
  int tid = threadIdx.x;
  int rr = tid >> 4, c4 = (tid & 15) * 4;
#pragma unroll
  for (int pass = 0; pass < 4; pass++) {
    int r = pass * 16 + rr;
    us4 v = *(const us4*)&qkv[(size_t)(b * LL + l0 + r) * 1536 + 1024 +
                              h * 64 + c4];
    t[r][c4] = v[0];
    t[r][c4 + 1] = v[1];
    t[r][c4 + 2] = v[2];
    t[r][c4 + 3] = v[3];
  }
  __syncthreads();
#pragma unroll
  for (int pass = 0; pass < 4; pass++) {
    int r = pass * 16 + rr;  // vT row (d)
    us4 v = {t[c4][r], t[c4 + 1][r], t[c4 + 2][r], t[c4 + 3][r]};
    *(us4*)&vT[((size_t)bh * 64 + r) * LL + l0 + c4] = v;
  }
  // fused meanV partial: sum over this chunk's 64 keys per d
  int p = tid >> 6, d = tid & 63;
  float s = 0.f;
#pragma unroll
  for (int i = 0; i < 16; i++) s += b2f(t[p * 16 + i][d]);
  red[p][d] = s;
  __syncthreads();
  if (p == 0)
    meanVpart[((size_t)bh * 32 + blockIdx.x) * 64 + d] =
        red[0][d] + red[1][d] + red[2][d] + red[3][d];
}

// ---- MFMA flash attention, 2-way KEY-SPLIT (r10 proven structure) ----
__global__ __launch_bounds__(256) void attn_kernel(
    const unsigned short* __restrict__ qkv, const unsigned short* __restrict__ vT,
    const int* __restrict__ etype, unsigned short* __restrict__ opart,
    float* __restrict__ ml) {
  __shared__ unsigned short Ks[2][64 * 64];  // [buf][key*64+d], swizzled 8KB
  __shared__ unsigned short Ps[64][72];
  int hwbid = blockIdx.x;
  int work = (hwbid & 7) * 256 + (hwbid >> 3);  // XCD-chunked (bijective)
  int bh = work >> 6;
  int rem = work & 63;
  int qt = 31 - (rem >> 1);  // LPT: big q-tiles first
  int half = rem & 1;
  int h = bh & 7, b = bh >> 3;
  int q0 = qt * 64;
  int nt = qt + 1;
  int ha = (nt + 1) >> 1;  // half A gets ceil(nt/2), always nonempty
  int j0 = half ? ha : 0;
  int j1 = half ? nt : ha;
  int pidx = (bh * 32 + qt) * 2 + half;
  int tid = threadIdx.x, w = tid >> 6, l = tid & 63;
  int g = l >> 4, li = l & 15;
  const float SC = 0.125f * 1.44269504f;  // scale * log2(e)

  f32x4 o[4];
#pragma unroll
  for (int n = 0; n < 4; n++) o[n] = (f32x4){0.f, 0.f, 0.f, 0.f};
  float mreg[4], lreg[4];
#pragma unroll
  for (int r = 0; r < 4; r++) { mreg[r] = -3.0e38f; lreg[r] = 0.f; }

  if (j0 < j1) {
    const unsigned short* qrp =
        qkv + (size_t)(b * LL + q0 + w * 16 + li) * 1536 + h * 64;
    bf16x8 aq0 = *(const bf16x8*)&qrp[g * 8];
    bf16x8 aq1 = *(const bf16x8*)&qrp[32 + g * 8];

    // prologue: stage tile j0 into buf 0
#pragma unroll
    for (int e = 0; e < 2; e++) {
      int idx = e * 256 + tid;
      int r = idx >> 3;
      int src = (l & 7) ^ (r & 7);
      gload16(
          qkv + (size_t)(b * LL + j0 * 64 + r) * 1536 + 512 + h * 64 + src * 8,
          &Ks[0][(e * 256 + w * 64) * 8]);
    }
    __syncthreads();

    int cur = 0;
    for (int j = j0; j < j1; j++) {
      int k0 = j << 6;
      if (j + 1 < j1) {
#pragma unroll
        for (int e = 0; e < 2; e++) {
          int idx = e * 256 + tid;
          int r = idx >> 3;
          int src = (l & 7) ^ (r & 7);
          gload16(qkv + (size_t)(b * LL + k0 + 64 + r) * 1536 + 512 + h * 64 +
                      src * 8,
                  &Ks[cur ^ 1][(e * 256 + w * 64) * 8]);
        }
      }
      // V frags + pad bias, issued early (L2-resident)
      bf16x8 bv0[4], bv1[4];
      float pb[4];
#pragma unroll
      for (int n = 0; n < 4; n++) {
        const unsigned short* vp =
            vT + ((size_t)(bh * 64 + n * 16 + li)) * LL + k0;
        bv0[n] = *(const bf16x8*)&vp[g * 8];
        bv1[n] = *(const bf16x8*)&vp[32 + g * 8];
        pb[n] = (etype[b * LL + k0 + n * 16 + li] == 0) ? -1.0e9f : 0.f;
      }
      // S = Q K^T from swizzled LDS
      f32x4 s[4];
#pragma unroll
      for (int n = 0; n < 4; n++) {
        int rK = n * 16 + li;
        const unsigned short* kb = &Ks[cur][rK * 64];
        bf16x8 bk0 = *(const bf16x8*)&kb[(g ^ (rK & 7)) * 8];
        bf16x8 bk1 = *(const bf16x8*)&kb[((g + 4) ^ (rK & 7)) * 8];
        f32x4 a = (f32x4){0.f, 0.f, 0.f, 0.f};
        __builtin_amdgcn_s_setprio(1);
        a = __builtin_amdgcn_mfma_f32_16x16x32_bf16(aq0, bk0, a, 0, 0, 0);
        a = __builtin_amdgcn_mfma_f32_16x16x32_bf16(aq1, bk1, a, 0, 0, 0);
        __builtin_amdgcn_s_setprio(0);
        s[n] = a;
      }
      // scale + mask: fast path off-diagonal (pad bias only)
      if (j == qt) {
#pragma unroll
        for (int n = 0; n < 4; n++) {
          int key = k0 + n * 16 + li;
#pragma unroll
          for (int r = 0; r < 4; r++) {
            int qrow = q0 + w * 16 + g * 4 + r;
            float sv = fmaf(s[n][r], SC, pb[n]);
            if (key > qrow) sv = -1.0e9f;
            s[n][r] = sv;
          }
        }
      } else {
#pragma unroll
        for (int n = 0; n < 4; n++)
#pragma unroll
          for (int r = 0; r < 4; r++) s[n][r] = fmaf(s[n][r], SC, pb[n]);
      }
      // wave-parallel online softmax (reduce across 16 li lanes), exp2 domain
      float pm[4], corr[4], psum[4];
#pragma unroll
      for (int r = 0; r < 4; r++)
        pm[r] = fmaxf(fmaxf(s[0][r], s[1][r]), fmaxf(s[2][r], s[3][r]));
#pragma unroll
      for (int msk = 1; msk <= 8; msk <<= 1)
#pragma unroll
        for (int r = 0; r < 4; r++)
          pm[r] = fmaxf(pm[r], __shfl_xor(pm[r], msk, 64));
#pragma unroll
      for (int r = 0; r < 4; r++) {
        float mnew = fmaxf(mreg[r], pm[r]);
        corr[r] = exp2f_fast(mreg[r] - mnew);
        mreg[r] = mnew;
        float ps = 0.f;
#pragma unroll
        for (int n = 0; n < 4; n++) {
          float p = exp2f_fast(s[n][r] - mnew);
          s[n][r] = p;
          ps += p;
        }
        psum[r] = ps;
      }
#pragma unroll
      for (int msk = 1; msk <= 8; msk <<= 1)
#pragma unroll
        for (int r = 0; r < 4; r++) psum[r] += __shfl_xor(psum[r], msk, 64);
#pragma unroll
      for (int r = 0; r < 4; r++) lreg[r] = lreg[r] * corr[r] + psum[r];
      // P -> LDS (own-wave rows only; same-wave ordering via lgkmcnt)
#pragma unroll
      for (int n = 0; n < 4; n++)
#pragma unroll
        for (int r = 0; r < 4; r++)
          Ps[w * 16 + g * 4 + r][n * 16 + li] = f2b(s[n][r]);
      // rescale O
#pragma unroll
      for (int n = 0; n < 4; n++)
#pragma unroll
        for (int r = 0; r < 4; r++) o[n][r] *= corr[r];
      // PV: A = P rows (LDS), B = V frags (regs)
      bf16x8 ap0 = *(const bf16x8*)&Ps[w * 16 + li][g * 8];
      bf16x8 ap1 = *(const bf16x8*)&Ps[w * 16 + li][32 + g * 8];
      __builtin_amdgcn_s_setprio(1);
#pragma unroll
      for (int n = 0; n < 4; n++) {
        o[n] = __builtin_amdgcn_mfma_f32_16x16x32_bf16(ap0, bv0[n], o[n], 0, 0, 0);
        o[n] = __builtin_amdgcn_mfma_f32_16x16x32_bf16(ap1, bv1[n], o[n], 0, 0, 0);
      }
      __builtin_amdgcn_s_setprio(0);
      __syncthreads();  // drains prefetch (vmcnt) + Ks/Ps traffic
      cur ^= 1;
    }
  }
  // epilogue: l-normalized partial O (bf16) + per-row (m,l)
#pragma unroll
  for (int r = 0; r < 4; r++) {
    int qrl = w * 16 + g * 4 + r;
    float inv = (lreg[r] > 0.f) ? 1.0f / lreg[r] : 0.f;
#pragma unroll
    for (int n = 0; n < 4; n++)
      opart[((size_t)pidx * 64 + qrl) * 64 + n * 16 + li] = f2b(o[n][r] * inv);
    if (li == 0) {
      ml[(size_t)pidx * 128 + qrl] = mreg[r];
      ml[(size_t)pidx * 128 + 64 + qrl] = lreg[r];
    }
  }
}

// ---- merge the two key-split halves (packed 2-wide, static) ----
__global__ __launch_bounds__(256) void amerge_kernel(
    const unsigned short* __restrict__ opart, const float* __restrict__ ml,
    const float* __restrict__ meanVpart, unsigned short* __restrict__ ao) {
  int blk = blockIdx.x;  // bh*32 + qt  (1024 blocks)
  int bh = blk >> 5, qt = blk & 31;
  int b = bh >> 3, h = bh & 7;
  int tid = threadIdx.x;
  int d2 = (tid & 31) * 2;
  int pA = blk * 2, pB = blk * 2 + 1;
  for (int rr = tid >> 5; rr < 64; rr += 8) {
    float mA = ml[(size_t)pA * 128 + rr], lA = ml[(size_t)pA * 128 + 64 + rr];
    float mB = ml[(size_t)pB * 128 + rr], lB = ml[(size_t)pB * 128 + 64 + rr];
    float m = fmaxf(mA, mB);
    float v0, v1;
    if (m <= -1.0e8f) {
      // fully-masked row: uniform softmax over all keys = meanV
      float s0 = 0.f, s1 = 0.f;
      for (int cc = 0; cc < 32; cc++) {
        s0 += meanVpart[((size_t)bh * 32 + cc) * 64 + d2];
        s1 += meanVpart[((size_t)bh * 32 + cc) * 64 + d2 + 1];
      }
      v0 = s0 * (1.0f / (float)LL);
      v1 = s1 * (1.0f / (float)LL);
    } else {
      float a0 = 0.f, a1 = 0.f, wsum = 0.f;
      if (lA > 0.f) {
        float wA = exp2f_fast(mA - m) * lA;
        unsigned ua = *(const unsigned*)&opart[((size_t)pA * 64 + rr) * 64 + d2];
        a0 += b2f((unsigned short)ua) * wA;
        a1 += b2f((unsigned short)(ua >> 16)) * wA;
        wsum += wA;
      }
      if (lB > 0.f) {
        float wB = exp2f_fast(mB - m) * lB;
        unsigned ub = *(const unsigned*)&opart[((size_t)pB * 64 + rr) * 64 + d2];
        a0 += b2f((unsigned short)ub) * wB;
        a1 += b2f((unsigned short)(ub >> 16)) * wB;
        wsum += wB;
      }
      float inv = 1.0f / wsum;
      v0 = a0 * inv;
      v1 = a1 * inv;
    }
    int qr = qt * 64 + rr;
    *(unsigned*)&ao[(size_t)(b * LL + qr) * DD + h * 64 + d2] = pk2(v0, v1);
  }
}

// ---- LayerNorm (+npm), bf16 input. WF32: write fp32 out; WBF: write bf16;
// ADDTEM: also emit xa=x+tem (fp32) + xab (bf16). ----
template <bool ADDTEM, bool WF32, bool WBF>
__global__ __launch_bounds__(256) void ln_kernel(
    const unsigned short* __restrict__ in, const float* __restrict__ g,
    const float* __restrict__ bta, const float* __restrict__ npm,
    const float* __restrict__ tem, float* __restrict__ out,
    float* __restrict__ out2, unsigned short* __restrict__ out_bf) {
  __shared__ float red[4];
  int row = blockIdx.x;
  int tid = threadIdx.x;
  unsigned u = ((const unsigned*)(in + (size_t)row * DD))[tid];
  float v0 = b2f((unsigned short)u), v1 = b2f((unsigned short)(u >> 16));
  int e0 = tid * 2, e1 = tid * 2 + 1;
  float s = v0 + v1;
#pragma unroll
  for (int o = 32; o > 0; o >>= 1) s += __shfl_down(s, o, 64);
  if ((tid & 63) == 0) red[tid >> 6] = s;
  __syncthreads();
  float mean = (red[0] + red[1] + red[2] + red[3]) * (1.0f / (float)DD);
  float d0 = v0 - mean, d1 = v1 - mean;
  float sq = d0 * d0 + d1 * d1;
#pragma unroll
  for (int o = 32; o > 0; o >>= 1) sq += __shfl_down(sq, o, 64);
  __syncthreads();
  if ((tid & 63) == 0) red[tid >> 6] = sq;
  __syncthreads();
  float var = (red[0] + red[1] + red[2] + red[3]) * (1.0f / (float)DD);
  float rstd = rsqrtf(var + 1e-6f);
  float m = npm[row];
  float o0 = (d0 * rstd * g[e0] + bta[e0]) * m;
  float o1 = (d1 * rstd * g[e1] + bta[e1]) * m;
  if (WF32) ((float2*)(out + (size_t)row * DD))[tid] = make_float2(o0, o1);
  if (ADDTEM) {
    float2 tv = ((const float2*)(tem + (size_t)row * DD))[tid];
    float a0 = o0 + tv.x, a1 = o1 + tv.y;
    ((float2*)(out2 + (size_t)row * DD))[tid] = make_float2(a0, a1);
    ((unsigned*)(out_bf + (size_t)row * DD))[tid] = pk2(a0, a1);
  } else if (WBF) {
    ((unsigned*)(out_bf + (size_t)row * DD))[tid] = pk2(o0, o1);
  }
}

extern "C" void kernel_launch(void* const* d_in, const int* in_sizes, int n_in,
                              void* d_out, int out_size, void* d_ws,
                              size_t ws_size, hipStream_t stream) {
  const int* etype = (const int*)d_in[0];
  const float* etime = (const float*)d_in[1];
  const float* npm = (const float*)d_in[2];
  const float* emb = (const float*)d_in[3];
  const float* Wq = (const float*)d_in[4];
  const float* Wk = (const float*)d_in[5];
  const float* Wv = (const float*)d_in[6];
  const float* fc_w = (const float*)d_in[7];
  const float* fc_b = (const float*)d_in[8];
  const float* ln1_g = (const float*)d_in[9];
  const float* ln1_b = (const float*)d_in[10];
  const float* W1 = (const float*)d_in[11];
  const float* b1 = (const float*)d_in[12];
  const float* W2 = (const float*)d_in[13];
  const float* b2 = (const float*)d_in[14];
  const float* ln2_g = (const float*)d_in[15];
  const float* ln2_b = (const float*)d_in[16];

  float* x = (float*)d_out;
  char* ws = (char*)d_ws;
  const size_t SZF = (size_t)MM * DD * sizeof(float);
  const size_t SZB = (size_t)MM * DD * sizeof(short);
  float* tem = (float*)ws; ws += SZF;
  float* xa  = (float*)ws; ws += SZF;
  unsigned short* xab = (unsigned short*)ws; ws += SZB;
  unsigned short* xbf = (unsigned short*)ws; ws += SZB;
  unsigned short* qkv = (unsigned short*)ws; ws += (size_t)MM * 1536 * 2;
  unsigned short* vT  = (unsigned short*)ws; ws += (size_t)BB * NH * 64 * LL * 2;
  unsigned short* ao  = (unsigned short*)ws; ws += SZB;
  unsigned short* hb  = (unsigned short*)ws; ws += (size_t)MM * DINNER * 2;
  unsigned short* ybb = (unsigned short*)ws; ws += SZB;  // bf16 LN input
  unsigned short* qkvT = (unsigned short*)ws; ws += (size_t)NLAYERS * 1536 * 512 * 2;
  unsigned short* fcT  = (unsigned short*)ws; ws += (size_t)NLAYERS * 512 * 512 * 2;
  unsigned short* W1T  = (unsigned short*)ws; ws += (size_t)NLAYERS * 2048 * 512 * 2;
  unsigned short* W2T  = (unsigned short*)ws; ws += (size_t)NLAYERS * 512 * 2048 * 2;
  float* meanVpart = (float*)ws; ws += (size_t)32 * 32 * 64 * sizeof(float);
  unsigned short* opart = (unsigned short*)ws; ws += (size_t)2048 * 64 * 64 * 2;
  float* ml = (float*)ws; ws += (size_t)2048 * 128 * sizeof(float);

  init_kernel<<<MM, 512, 0, stream>>>(etype, etime, npm, emb, tem, xa, xab);

  wtrans_kernel<<<dim3(16, 16, NLAYERS), 256, 0, stream>>>(
      Wq, qkvT + 0 * 512 * 512, 512, 512, 512L * 512, 1536L * 512);
  wtrans_kernel<<<dim3(16, 16, NLAYERS), 256, 0, stream>>>(
      Wk, qkvT + 1 * 512 * 512, 512, 512, 512L * 512, 1536L * 512);
  wtrans_kernel<<<dim3(16, 16, NLAYERS), 256, 0, stream>>>(
      Wv, qkvT + 2 * 512 * 512, 512, 512, 512L * 512, 1536L * 512);
  wtrans_kernel<<<dim3(16, 16, NLAYERS), 256, 0, stream>>>(
      fc_w, fcT, 512, 512, 512L * 512, 512L * 512);
  wtrans_kernel<<<dim3(64, 16, NLAYERS), 256, 0, stream>>>(
      W1, W1T, 512, 2048, 512L * 2048, 2048L * 512);
  wtrans_kernel<<<dim3(16, 64, NLAYERS), 256, 0, stream>>>(
      W2, W2T, 2048, 512, 2048L * 512, 512L * 2048);

  for (int l = 0; l < NLAYERS; l++) {
    // QKV (grid 3072, 64x64x64 tiles)
    gemm_kernel<64, 64, 64, false, false, false, true, false>
        <<<128 * 24, 256, 0, stream>>>(
            xab, qkvT + (size_t)l * 1536 * 512, nullptr, nullptr, 0, qkv, 1536,
            MM, 1536, 512);

    vtrans_kernel<<<dim3(32, 32), 256, 0, stream>>>(qkv, vT, meanVpart);
    attn_kernel<<<2048, 256, 0, stream>>>(qkv, vT, etype, opart, ml);
    amerge_kernel<<<1024, 256, 0, stream>>>(opart, ml, meanVpart, ao);

    // fc: +bias +residual(xa fp32) -> bf16 ybb (grid 1024, 64x64x64)
    gemm_kernel<64, 64, 64, true, true, false, true, false>
        <<<128 * 8, 256, 0, stream>>>(
            ao, fcT + (size_t)l * 512 * 512, fc_b + (size_t)l * 512, xa, 512,
            ybb, 512, MM, 512, 512);
    // LN1: bf16 out only
    ln_kernel<false, false, true><<<MM, 256, 0, stream>>>(
        ybb, ln1_g + (size_t)l * 512, ln1_b + (size_t)l * 512, npm, nullptr,
        nullptr, nullptr, xbf);

    // FFN1 (grid 4096, 64x64x64 tiles)
    gemm_kernel<64, 64, 64, true, false, true, true, false>
        <<<128 * 32, 256, 0, stream>>>(
            xbf, W1T + (size_t)l * 2048 * 512, b1 + (size_t)l * 2048, nullptr,
            0, hb, 2048, MM, 2048, 512);
    // FFN2: +bias +residual(xbf bf16) -> bf16 ybb (grid 1024, 64x64x64)
    gemm_kernel<64, 64, 64, true, true, false, true, true>
        <<<128 * 8, 256, 0, stream>>>(
            hb, W2T + (size_t)l * 512 * 2048, b2 + (size_t)l * 512, xbf, 512,
            ybb, 512, MM, 512, 2048);
    if (l + 1 < NLAYERS) {
      // LN2: xa (fp32) + xab (bf16) for next layer
      ln_kernel<true, false, false><<<MM, 256, 0, stream>>>(
          ybb, ln2_g + (size_t)l * 512, ln2_b + (size_t)l * 512, npm, tem,
          nullptr, xa, xab);
    } else {
      // final layer: only the fp32 output x
      ln_kernel<false, true, false><<<MM, 256, 0, stream>>>(
          ybb, ln2_g + (size_t)l * 512, ln2_b + (size_t)l * 512, npm, nullptr,
          x, nullptr, nullptr);
    }
  }
}

// Round 21
// 877.610 us; speedup vs baseline: 1.2110x; 1.0106x over previous
//
#include <hip/hip_runtime.h>
#include <math.h>

#define BB 4
#define LL 2048
#define DD 512
#define NH 8
#define DINNER 2048
#define NLAYERS 4
#define MM (BB * LL)  // 8192

typedef __attribute__((ext_vector_type(8))) __bf16 bf16x8;
typedef __attribute__((ext_vector_type(4))) float f32x4;
typedef __attribute__((ext_vector_type(4))) unsigned short us4;

__device__ __forceinline__ unsigned short f2b(float f) {
  union { __bf16 h; unsigned short u; } v;
  v.h = (__bf16)f;  // native RNE convert
  return v.u;
}
__device__ __forceinline__ float b2f(unsigned short h) {
  union { unsigned u; float f; } v; v.u = ((unsigned)h) << 16; return v.f;
}
__device__ __forceinline__ unsigned pk2(float lo, float hi) {
  return (unsigned)f2b(lo) | ((unsigned)f2b(hi) << 16);
}
__device__ __forceinline__ float exp2f_fast(float x) {
  float r; asm("v_exp_f32 %0, %1" : "=v"(r) : "v"(x)); return r;
}

__device__ __forceinline__ void gload16(const void* g, void* l) {
  __builtin_amdgcn_global_load_lds(
      (const __attribute__((address_space(1))) void*)g,
      (__attribute__((address_space(3))) void*)l, 16, 0, 0);
}

// ---- init: temporal enc + embedding gather; emits xab = bf16(emb+tem) ----
__global__ __launch_bounds__(512) void init_kernel(
    const int* __restrict__ etype, const float* __restrict__ etime,
    const float* __restrict__ npm, const float* __restrict__ emb,
    float* __restrict__ tem, unsigned short* __restrict__ xab) {
  int row = blockIdx.x;
  int d = threadIdx.x;
  float t = etime[row];
  float mask = npm[row];
  int dd = d & ~1;
  float pv = expf(9.210340371976184f * ((float)dd * (1.0f / (float)DD)));
  float r = t / pv;
  float val = (d & 1) ? cosf(r) : sinf(r);
  float tv = val * mask;
  tem[(size_t)row * DD + d] = tv;
  int ty = etype[row];
  float a = emb[(size_t)ty * DD + d] + tv;
  xab[(size_t)row * DD + d] = f2b(a);
}

// ---- weight transpose+convert (vectorized): fp32 [K][N] -> bf16 [N][K] ----
__global__ __launch_bounds__(256) void wtrans_kernel(
    const float* __restrict__ in, unsigned short* __restrict__ out,
    int K, int N, long in_ls, long out_ls) {
  __shared__ unsigned short t[32][36];
  int l = blockIdx.z;
  int n0 = blockIdx.x * 32, k0 = blockIdx.y * 32;
  int tid = threadIdx.x;
  int r = tid >> 3, c4 = (tid & 7) * 4;
  const float* ip = in + (size_t)l * in_ls;
  unsigned short* op = out + (size_t)l * out_ls;
  float4 v = *(const float4*)&ip[(size_t)(k0 + r) * N + n0 + c4];
  t[r][c4] = f2b(v.x);
  t[r][c4 + 1] = f2b(v.y);
  t[r][c4 + 2] = f2b(v.z);
  t[r][c4 + 3] = f2b(v.w);
  __syncthreads();
  us4 o = {t[c4][r], t[c4 + 1][r], t[c4 + 2][r], t[c4 + 3][r]};
  *(us4*)&op[(size_t)(n0 + r) * K + k0 + c4] = o;
}

// ---- MFMA GEMM, 2-phase pipelined, XCD-chunked 1D grid (T1 swizzle) ----
// C[M,N] = A(bf16 [M,K]) @ WT(bf16 [N,K])^T.  1D grid = (M/BM)*(N/BN),
// nwg % 8 == 0. BK in {32, 64}; BK=64 only for 64x64 tiles.
// RESB16: residual read as bf16 (packed) instead of fp32.
template <int BM, int BN, int BK, bool BIAS, bool RES, bool GELU_, bool OBF16,
          bool RESB16>
__global__ __launch_bounds__(256) void gemm_kernel(
    const unsigned short* __restrict__ A, const unsigned short* __restrict__ WT,
    const float* __restrict__ bias, const void* __restrict__ resv, int ldres,
    void* __restrict__ Cv, int ldc, int M, int N, int K) {
  __shared__ unsigned short As[2][BM * BK];
  __shared__ unsigned short Bs[2][BN * BK];
  constexpr int MT = (BM == 128) ? 4 : ((BN == 64) ? 2 : 4);
  constexpr int NT = (BM == 128 && BN == 128) ? 4 : 2;
  constexpr int KK = BK / 32;  // mfma K=32 sub-steps per k-step
  int tid = threadIdx.x;
  int w = tid >> 6, l = tid & 63;
  int li = l & 15, g = l >> 4;
  // XCD-chunked bijective remap (nwg divisible by 8)
  int nwg = gridDim.x;
  int bid = blockIdx.x;
  int wg = (bid & 7) * (nwg >> 3) + (bid >> 3);
  int gx = N / BN;
  int row0 = (wg / gx) * BM, col0 = (wg % gx) * BN;
  int wm = (BM == 128) ? (w & 1) * 64 : ((BN == 64) ? (w >> 1) * 32 : 0);
  int wnb = (BM == 128) ? (w >> 1) * 64 : ((BN == 64) ? (w & 1) * 32 : w * 32);
  f32x4 acc[MT][NT];
#pragma unroll
  for (int i = 0; i < MT; i++)
#pragma unroll
    for (int j = 0; j < NT; j++) acc[i][j] = (f32x4){0.f, 0.f, 0.f, 0.f};

  int lr = l >> 2;
  int lc = (l & 3) ^ (lr & 3);

  auto stage = [&](int bb, int kb) {
    int k0 = kb * BK;
    if (BK == 64) {
      // 64 rows x 8 chunks of 16B; src chunk XOR-swizzled per row
#pragma unroll
      for (int e = 0; e < 2; e++) {
        int slot = e * 256 + tid;
        int r = slot >> 3, c = slot & 7;
        int src = c ^ (r & 7);
        gload16(A + (size_t)(row0 + r) * K + k0 + src * 8,
                &As[bb][slot * 8]);
        gload16(WT + (size_t)(col0 + r) * K + k0 + src * 8,
                &Bs[bb][slot * 8]);
      }
    } else {
      if (BM == 128) {
#pragma unroll
        for (int i = 0; i < 2; i++) {
          int ai = w * 2 + i;
          gload16(A + (size_t)(row0 + ai * 16 + lr) * K + k0 + lc * 8,
                  &As[bb][ai * 512]);
        }
      } else {
        gload16(A + (size_t)(row0 + w * 16 + lr) * K + k0 + lc * 8,
                &As[bb][w * 512]);
      }
      if (BN == 128) {
#pragma unroll
        for (int i = 0; i < 2; i++) {
          int bi = w * 2 + i;
          gload16(WT + (size_t)(col0 + bi * 16 + lr) * K + k0 + lc * 8,
                  &Bs[bb][bi * 512]);
        }
      } else {
        gload16(WT + (size_t)(col0 + w * 16 + lr) * K + k0 + lc * 8,
                &Bs[bb][w * 512]);
      }
    }
  };

  int nk = K / BK;
  stage(0, 0);
  __syncthreads();
  int buf = 0;
  for (int kb = 0; kb < nk; kb++) {
    if (kb + 1 < nk) stage(buf ^ 1, kb + 1);
    bf16x8 af[MT][KK], bf_[NT][KK];
#pragma unroll
    for (int mt = 0; mt < MT; mt++) {
      int r = wm + mt * 16 + li;
#pragma unroll
      for (int kk = 0; kk < KK; kk++) {
        int off = (BK == 64) ? (r * 64 + ((((kk << 2) | g) ^ (r & 7)) * 8))
                             : (r * 32 + ((g ^ (r & 3)) * 8));
        af[mt][kk] = *(const bf16x8*)&As[buf][off];
      }
    }
#pragma unroll
    for (int nt = 0; nt < NT; nt++) {
      int r = wnb + nt * 16 + li;
#pragma unroll
      for (int kk = 0; kk < KK; kk++) {
        int off = (BK == 64) ? (r * 64 + ((((kk << 2) | g) ^ (r & 7)) * 8))
                             : (r * 32 + ((g ^ (r & 3)) * 8));
        bf_[nt][kk] = *(const bf16x8*)&Bs[buf][off];
      }
    }
#pragma unroll
    for (int kk = 0; kk < KK; kk++)
#pragma unroll
      for (int mt = 0; mt < MT; mt++)
#pragma unroll
        for (int nt = 0; nt < NT; nt++)
          acc[mt][nt] = __builtin_amdgcn_mfma_f32_16x16x32_bf16(
              af[mt][kk], bf_[nt][kk], acc[mt][nt], 0, 0, 0);
    __syncthreads();
    buf ^= 1;
  }
#pragma unroll
  for (int mt = 0; mt < MT; mt++) {
#pragma unroll
    for (int nt = 0; nt < NT; nt++) {
#pragma unroll
      for (int r = 0; r < 4; r++) {
        int row = row0 + wm + mt * 16 + g * 4 + r;
        int col = col0 + wnb + nt * 16 + li;
        float v = acc[mt][nt][r];
        if (BIAS) v += bias[col];
        if (RES) {
          if (RESB16)
            v += b2f(((const unsigned short*)resv)[(size_t)row * ldres + col]);
          else
            v += ((const float*)resv)[(size_t)row * ldres + col];
        }
        if (GELU_) v = 0.5f * v * (1.0f + erff(v * 0.70710678118654752f));
        if (OBF16)
          ((unsigned short*)Cv)[(size_t)row * ldc + col] = f2b(v);
        else
          ((float*)Cv)[(size_t)row * ldc + col] = v;
      }
    }
  }
}

// ---- transpose v slice -> vT [bh*64+d][L] + fused meanV partial sums ----
// grid (32 L-chunks, 32 bh). Partial sum per (bh, chunk) over its 64 keys.
__global__ __launch_bounds__(256) void vtrans_kernel(
    const unsigned short* __restrict__ qkv, unsigned short* __restrict__ vT,
    float* __restrict__ meanVpart) {
  __shared__ unsigned short t[64][65];
  __shared__ float red[4][64];
  int bh = blockIdx.y;
  int b = bh >> 3, h = bh & 7;
  int l0 = blockIdx.x * 64;
  int tid = threadIdx.x;
  int rr = tid >> 4, c4 = (tid & 15) * 4;
#pragma unroll
  for (int pass = 0; pass < 4; pass++) {
    int r = pass * 16 + rr;
    us4 v = *(const us4*)&qkv[(size_t)(b * LL + l0 + r) * 1536 + 1024 +
                              h * 64 + c4];
    t[r][c4] = v[0];
    t[r][c4 + 1] = v[1];
    t[r][c4 + 2] = v[2];
    t[r][c4 + 3] = v[3];
  }
  __syncthreads();
#pragma unroll
  for (int pass = 0; pass < 4; pass++) {
    int r = pass * 16 + rr;  // vT row (d)
    us4 v = {t[c4][r], t[c4 + 1][r], t[c4 + 2][r], t[c4 + 3][r]};
    *(us4*)&vT[((size_t)bh * 64 + r) * LL + l0 + c4] = v;
  }
  // fused meanV partial: sum over this chunk's 64 keys per d
  int p = tid >> 6, d = tid & 63;
  float s = 0.f;
#pragma unroll
  for (int i = 0; i < 16; i++) s += b2f(t[p * 16 + i][d]);
  red[p][d] = s;
  __syncthreads();
  if (p == 0)
    meanVpart[((size_t)bh * 32 + blockIdx.x) * 64 + d] =
        red[0][d] + red[1][d] + red[2][d] + red[3][d];
}

// ---- MFMA flash attention, 2-way KEY-SPLIT (r10 proven structure) ----
__global__ __launch_bounds__(256) void attn_kernel(
    const unsigned short* __restrict__ qkv, const unsigned short* __restrict__ vT,
    const int* __restrict__ etype, unsigned short* __restrict__ opart,
    float* __restrict__ ml) {
  __shared__ unsigned short Ks[2][64 * 64];  // [buf][key*64+d], swizzled 8KB
  __shared__ unsigned short Ps[64][72];
  int hwbid = blockIdx.x;
  int work = (hwbid & 7) * 256 + (hwbid >> 3);  // XCD-chunked (bijective)
  int bh = work >> 6;
  int rem = work & 63;
  int qt = 31 - (rem >> 1);  // LPT: big q-tiles first
  int half = rem & 1;
  int h = bh & 7, b = bh >> 3;
  int q0 = qt * 64;
  int nt = qt + 1;
  int ha = (nt + 1) >> 1;  // half A gets ceil(nt/2), always nonempty
  int j0 = half ? ha : 0;
  int j1 = half ? nt : ha;
  int pidx = (bh * 32 + qt) * 2 + half;
  int tid = threadIdx.x, w = tid >> 6, l = tid & 63;
  int g = l >> 4, li = l & 15;
  const float SC = 0.125f * 1.44269504f;  // scale * log2(e)

  f32x4 o[4];
#pragma unroll
  for (int n = 0; n < 4; n++) o[n] = (f32x4){0.f, 0.f, 0.f, 0.f};
  float mreg[4], lreg[4];
#pragma unroll
  for (int r = 0; r < 4; r++) { mreg[r] = -3.0e38f; lreg[r] = 0.f; }

  if (j0 < j1) {
    const unsigned short* qrp =
        qkv + (size_t)(b * LL + q0 + w * 16 + li) * 1536 + h * 64;
    bf16x8 aq0 = *(const bf16x8*)&qrp[g * 8];
    bf16x8 aq1 = *(const bf16x8*)&qrp[32 + g * 8];

    // prologue: stage tile j0 into buf 0
#pragma unroll
    for (int e = 0; e < 2; e++) {
      int idx = e * 256 + tid;
      int r = idx >> 3;
      int src = (l & 7) ^ (r & 7);
      gload16(
          qkv + (size_t)(b * LL + j0 * 64 + r) * 1536 + 512 + h * 64 + src * 8,
          &Ks[0][(e * 256 + w * 64) * 8]);
    }
    __syncthreads();

    int cur = 0;
    for (int j = j0; j < j1; j++) {
      int k0 = j << 6;
      if (j + 1 < j1) {
#pragma unroll
        for (int e = 0; e < 2; e++) {
          int idx = e * 256 + tid;
          int r = idx >> 3;
          int src = (l & 7) ^ (r & 7);
          gload16(qkv + (size_t)(b * LL + k0 + 64 + r) * 1536 + 512 + h * 64 +
                      src * 8,
                  &Ks[cur ^ 1][(e * 256 + w * 64) * 8]);
        }
      }
      // V frags + pad bias, issued early (L2-resident)
      bf16x8 bv0[4], bv1[4];
      float pb[4];
#pragma unroll
      for (int n = 0; n < 4; n++) {
        const unsigned short* vp =
            vT + ((size_t)(bh * 64 + n * 16 + li)) * LL + k0;
        bv0[n] = *(const bf16x8*)&vp[g * 8];
        bv1[n] = *(const bf16x8*)&vp[32 + g * 8];
        pb[n] = (etype[b * LL + k0 + n * 16 + li] == 0) ? -1.0e9f : 0.f;
      }
      // S = Q K^T from swizzled LDS
      f32x4 s[4];
#pragma unroll
      for (int n = 0; n < 4; n++) {
        int rK = n * 16 + li;
        const unsigned short* kb = &Ks[cur][rK * 64];
        bf16x8 bk0 = *(const bf16x8*)&kb[(g ^ (rK & 7)) * 8];
        bf16x8 bk1 = *(const bf16x8*)&kb[((g + 4) ^ (rK & 7)) * 8];
        f32x4 a = (f32x4){0.f, 0.f, 0.f, 0.f};
        __builtin_amdgcn_s_setprio(1);
        a = __builtin_amdgcn_mfma_f32_16x16x32_bf16(aq0, bk0, a, 0, 0, 0);
        a = __builtin_amdgcn_mfma_f32_16x16x32_bf16(aq1, bk1, a, 0, 0, 0);
        __builtin_amdgcn_s_setprio(0);
        s[n] = a;
      }
      // scale + mask: fast path off-diagonal (pad bias only)
      if (j == qt) {
#pragma unroll
        for (int n = 0; n < 4; n++) {
          int key = k0 + n * 16 + li;
#pragma unroll
          for (int r = 0; r < 4; r++) {
            int qrow = q0 + w * 16 + g * 4 + r;
            float sv = fmaf(s[n][r], SC, pb[n]);
            if (key > qrow) sv = -1.0e9f;
            s[n][r] = sv;
          }
        }
      } else {
#pragma unroll
        for (int n = 0; n < 4; n++)
#pragma unroll
          for (int r = 0; r < 4; r++) s[n][r] = fmaf(s[n][r], SC, pb[n]);
      }
      // wave-parallel online softmax (reduce across 16 li lanes), exp2 domain
      float pm[4], corr[4], psum[4];
#pragma unroll
      for (int r = 0; r < 4; r++)
        pm[r] = fmaxf(fmaxf(s[0][r], s[1][r]), fmaxf(s[2][r], s[3][r]));
#pragma unroll
      for (int msk = 1; msk <= 8; msk <<= 1)
#pragma unroll
        for (int r = 0; r < 4; r++)
          pm[r] = fmaxf(pm[r], __shfl_xor(pm[r], msk, 64));
#pragma unroll
      for (int r = 0; r < 4; r++) {
        float mnew = fmaxf(mreg[r], pm[r]);
        corr[r] = exp2f_fast(mreg[r] - mnew);
        mreg[r] = mnew;
        float ps = 0.f;
#pragma unroll
        for (int n = 0; n < 4; n++) {
          float p = exp2f_fast(s[n][r] - mnew);
          s[n][r] = p;
          ps += p;
        }
        psum[r] = ps;
      }
#pragma unroll
      for (int msk = 1; msk <= 8; msk <<= 1)
#pragma unroll
        for (int r = 0; r < 4; r++) psum[r] += __shfl_xor(psum[r], msk, 64);
#pragma unroll
      for (int r = 0; r < 4; r++) lreg[r] = lreg[r] * corr[r] + psum[r];
      // P -> LDS (own-wave rows only; same-wave ordering via lgkmcnt)
#pragma unroll
      for (int n = 0; n < 4; n++)
#pragma unroll
        for (int r = 0; r < 4; r++)
          Ps[w * 16 + g * 4 + r][n * 16 + li] = f2b(s[n][r]);
      // rescale O
#pragma unroll
      for (int n = 0; n < 4; n++)
#pragma unroll
        for (int r = 0; r < 4; r++) o[n][r] *= corr[r];
      // PV: A = P rows (LDS), B = V frags (regs)
      bf16x8 ap0 = *(const bf16x8*)&Ps[w * 16 + li][g * 8];
      bf16x8 ap1 = *(const bf16x8*)&Ps[w * 16 + li][32 + g * 8];
      __builtin_amdgcn_s_setprio(1);
#pragma unroll
      for (int n = 0; n < 4; n++) {
        o[n] = __builtin_amdgcn_mfma_f32_16x16x32_bf16(ap0, bv0[n], o[n], 0, 0, 0);
        o[n] = __builtin_amdgcn_mfma_f32_16x16x32_bf16(ap1, bv1[n], o[n], 0, 0, 0);
      }
      __builtin_amdgcn_s_setprio(0);
      __syncthreads();  // drains prefetch (vmcnt) + Ks/Ps traffic
      cur ^= 1;
    }
  }
  // epilogue: l-normalized partial O (bf16) + per-row (m,l)
#pragma unroll
  for (int r = 0; r < 4; r++) {
    int qrl = w * 16 + g * 4 + r;
    float inv = (lreg[r] > 0.f) ? 1.0f / lreg[r] : 0.f;
#pragma unroll
    for (int n = 0; n < 4; n++)
      opart[((size_t)pidx * 64 + qrl) * 64 + n * 16 + li] = f2b(o[n][r] * inv);
    if (li == 0) {
      ml[(size_t)pidx * 128 + qrl] = mreg[r];
      ml[(size_t)pidx * 128 + 64 + qrl] = lreg[r];
    }
  }
}

// ---- merge the two key-split halves (packed 2-wide, static) ----
__global__ __launch_bounds__(256) void amerge_kernel(
    const unsigned short* __restrict__ opart, const float* __restrict__ ml,
    const float* __restrict__ meanVpart, unsigned short* __restrict__ ao) {
  int blk = blockIdx.x;  // bh*32 + qt  (1024 blocks)
  int bh = blk >> 5, qt = blk & 31;
  int b = bh >> 3, h = bh & 7;
  int tid = threadIdx.x;
  int d2 = (tid & 31) * 2;
  int pA = blk * 2, pB = blk * 2 + 1;
  for (int rr = tid >> 5; rr < 64; rr += 8) {
    float mA = ml[(size_t)pA * 128 + rr], lA = ml[(size_t)pA * 128 + 64 + rr];
    float mB = ml[(size_t)pB * 128 + rr], lB = ml[(size_t)pB * 128 + 64 + rr];
    float m = fmaxf(mA, mB);
    float v0, v1;
    if (m <= -1.0e8f) {
      // fully-masked row: uniform softmax over all keys = meanV
      float s0 = 0.f, s1 = 0.f;
      for (int cc = 0; cc < 32; cc++) {
        s0 += meanVpart[((size_t)bh * 32 + cc) * 64 + d2];
        s1 += meanVpart[((size_t)bh * 32 + cc) * 64 + d2 + 1];
      }
      v0 = s0 * (1.0f / (float)LL);
      v1 = s1 * (1.0f / (float)LL);
    } else {
      float a0 = 0.f, a1 = 0.f, wsum = 0.f;
      if (lA > 0.f) {
        float wA = exp2f_fast(mA - m) * lA;
        unsigned ua = *(const unsigned*)&opart[((size_t)pA * 64 + rr) * 64 + d2];
        a0 += b2f((unsigned short)ua) * wA;
        a1 += b2f((unsigned short)(ua >> 16)) * wA;
        wsum += wA;
      }
      if (lB > 0.f) {
        float wB = exp2f_fast(mB - m) * lB;
        unsigned ub = *(const unsigned*)&opart[((size_t)pB * 64 + rr) * 64 + d2];
        a0 += b2f((unsigned short)ub) * wB;
        a1 += b2f((unsigned short)(ub >> 16)) * wB;
        wsum += wB;
      }
      float inv = 1.0f / wsum;
      v0 = a0 * inv;
      v1 = a1 * inv;
    }
    int qr = qt * 64 + rr;
    *(unsigned*)&ao[(size_t)(b * LL + qr) * DD + h * 64 + d2] = pk2(v0, v1);
  }
}

// ---- LayerNorm (+npm), bf16 input. WF32: write fp32 out; WBF: write bf16;
// ADDTEM: emit xab = bf16(x+tem) only. ----
template <bool ADDTEM, bool WF32, bool WBF>
__global__ __launch_bounds__(256) void ln_kernel(
    const unsigned short* __restrict__ in, const float* __restrict__ g,
    const float* __restrict__ bta, const float* __restrict__ npm,
    const float* __restrict__ tem, float* __restrict__ out,
    unsigned short* __restrict__ out_bf) {
  __shared__ float red[4];
  int row = blockIdx.x;
  int tid = threadIdx.x;
  unsigned u = ((const unsigned*)(in + (size_t)row * DD))[tid];
  float v0 = b2f((unsigned short)u), v1 = b2f((unsigned short)(u >> 16));
  int e0 = tid * 2, e1 = tid * 2 + 1;
  float s = v0 + v1;
#pragma unroll
  for (int o = 32; o > 0; o >>= 1) s += __shfl_down(s, o, 64);
  if ((tid & 63) == 0) red[tid >> 6] = s;
  __syncthreads();
  float mean = (red[0] + red[1] + red[2] + red[3]) * (1.0f / (float)DD);
  float d0 = v0 - mean, d1 = v1 - mean;
  float sq = d0 * d0 + d1 * d1;
#pragma unroll
  for (int o = 32; o > 0; o >>= 1) sq += __shfl_down(sq, o, 64);
  __syncthreads();
  if ((tid & 63) == 0) red[tid >> 6] = sq;
  __syncthreads();
  float var = (red[0] + red[1] + red[2] + red[3]) * (1.0f / (float)DD);
  float rstd = rsqrtf(var + 1e-6f);
  float m = npm[row];
  float o0 = (d0 * rstd * g[e0] + bta[e0]) * m;
  float o1 = (d1 * rstd * g[e1] + bta[e1]) * m;
  if (WF32) ((float2*)(out + (size_t)row * DD))[tid] = make_float2(o0, o1);
  if (ADDTEM) {
    float2 tv = ((const float2*)(tem + (size_t)row * DD))[tid];
    ((unsigned*)(out_bf + (size_t)row * DD))[tid] =
        pk2(o0 + tv.x, o1 + tv.y);
  } else if (WBF) {
    ((unsigned*)(out_bf + (size_t)row * DD))[tid] = pk2(o0, o1);
  }
}

extern "C" void kernel_launch(void* const* d_in, const int* in_sizes, int n_in,
                              void* d_out, int out_size, void* d_ws,
                              size_t ws_size, hipStream_t stream) {
  const int* etype = (const int*)d_in[0];
  const float* etime = (const float*)d_in[1];
  const float* npm = (const float*)d_in[2];
  const float* emb = (const float*)d_in[3];
  const float* Wq = (const float*)d_in[4];
  const float* Wk = (const float*)d_in[5];
  const float* Wv = (const float*)d_in[6];
  const float* fc_w = (const float*)d_in[7];
  const float* fc_b = (const float*)d_in[8];
  const float* ln1_g = (const float*)d_in[9];
  const float* ln1_b = (const float*)d_in[10];
  const float* W1 = (const float*)d_in[11];
  const float* b1 = (const float*)d_in[12];
  const float* W2 = (const float*)d_in[13];
  const float* b2 = (const float*)d_in[14];
  const float* ln2_g = (const float*)d_in[15];
  const float* ln2_b = (const float*)d_in[16];

  float* x = (float*)d_out;
  char* ws = (char*)d_ws;
  const size_t SZF = (size_t)MM * DD * sizeof(float);
  const size_t SZB = (size_t)MM * DD * sizeof(short);
  float* tem = (float*)ws; ws += SZF;
  unsigned short* xab = (unsigned short*)ws; ws += SZB;
  unsigned short* xbf = (unsigned short*)ws; ws += SZB;
  unsigned short* qkv = (unsigned short*)ws; ws += (size_t)MM * 1536 * 2;
  unsigned short* vT  = (unsigned short*)ws; ws += (size_t)BB * NH * 64 * LL * 2;
  unsigned short* ao  = (unsigned short*)ws; ws += SZB;
  unsigned short* hb  = (unsigned short*)ws; ws += (size_t)MM * DINNER * 2;
  unsigned short* ybb = (unsigned short*)ws; ws += SZB;  // bf16 LN input
  unsigned short* qkvT = (unsigned short*)ws; ws += (size_t)NLAYERS * 1536 * 512 * 2;
  unsigned short* fcT  = (unsigned short*)ws; ws += (size_t)NLAYERS * 512 * 512 * 2;
  unsigned short* W1T  = (unsigned short*)ws; ws += (size_t)NLAYERS * 2048 * 512 * 2;
  unsigned short* W2T  = (unsigned short*)ws; ws += (size_t)NLAYERS * 512 * 2048 * 2;
  float* meanVpart = (float*)ws; ws += (size_t)32 * 32 * 64 * sizeof(float);
  unsigned short* opart = (unsigned short*)ws; ws += (size_t)2048 * 64 * 64 * 2;
  float* ml = (float*)ws; ws += (size_t)2048 * 128 * sizeof(float);

  init_kernel<<<MM, 512, 0, stream>>>(etype, etime, npm, emb, tem, xab);

  wtrans_kernel<<<dim3(16, 16, NLAYERS), 256, 0, stream>>>(
      Wq, qkvT + 0 * 512 * 512, 512, 512, 512L * 512, 1536L * 512);
  wtrans_kernel<<<dim3(16, 16, NLAYERS), 256, 0, stream>>>(
      Wk, qkvT + 1 * 512 * 512, 512, 512, 512L * 512, 1536L * 512);
  wtrans_kernel<<<dim3(16, 16, NLAYERS), 256, 0, stream>>>(
      Wv, qkvT + 2 * 512 * 512, 512, 512, 512L * 512, 1536L * 512);
  wtrans_kernel<<<dim3(16, 16, NLAYERS), 256, 0, stream>>>(
      fc_w, fcT, 512, 512, 512L * 512, 512L * 512);
  wtrans_kernel<<<dim3(64, 16, NLAYERS), 256, 0, stream>>>(
      W1, W1T, 512, 2048, 512L * 2048, 2048L * 512);
  wtrans_kernel<<<dim3(16, 64, NLAYERS), 256, 0, stream>>>(
      W2, W2T, 2048, 512, 2048L * 512, 512L * 2048);

  for (int l = 0; l < NLAYERS; l++) {
    // QKV (grid 3072, 64x64x64 tiles)
    gemm_kernel<64, 64, 64, false, false, false, true, false>
        <<<128 * 24, 256, 0, stream>>>(
            xab, qkvT + (size_t)l * 1536 * 512, nullptr, nullptr, 0, qkv, 1536,
            MM, 1536, 512);

    vtrans_kernel<<<dim3(32, 32), 256, 0, stream>>>(qkv, vT, meanVpart);
    attn_kernel<<<2048, 256, 0, stream>>>(qkv, vT, etype, opart, ml);
    amerge_kernel<<<1024, 256, 0, stream>>>(opart, ml, meanVpart, ao);

    // fc: +bias +residual(xab bf16) -> bf16 ybb (grid 1024, 64x64x64)
    gemm_kernel<64, 64, 64, true, true, false, true, true>
        <<<128 * 8, 256, 0, stream>>>(
            ao, fcT + (size_t)l * 512 * 512, fc_b + (size_t)l * 512, xab, 512,
            ybb, 512, MM, 512, 512);
    // LN1: bf16 out only
    ln_kernel<false, false, true><<<MM, 256, 0, stream>>>(
        ybb, ln1_g + (size_t)l * 512, ln1_b + (size_t)l * 512, npm, nullptr,
        nullptr, xbf);

    // FFN1 (grid 4096, 64x64x64 tiles)
    gemm_kernel<64, 64, 64, true, false, true, true, false>
        <<<128 * 32, 256, 0, stream>>>(
            xbf, W1T + (size_t)l * 2048 * 512, b1 + (size_t)l * 2048, nullptr,
            0, hb, 2048, MM, 2048, 512);
    // FFN2: +bias +residual(xbf bf16) -> bf16 ybb (grid 1024, 64x64x64)
    gemm_kernel<64, 64, 64, true, true, false, true, true>
        <<<128 * 8, 256, 0, stream>>>(
            hb, W2T + (size_t)l * 512 * 2048, b2 + (size_t)l * 512, xbf, 512,
            ybb, 512, MM, 512, 2048);
    if (l + 1 < NLAYERS) {
      // LN2: xab (bf16 of x+tem) for next layer
      ln_kernel<true, false, false><<<MM, 256, 0, stream>>>(
          ybb, ln2_g + (size_t)l * 512, ln2_b + (size_t)l * 512, npm, tem,
          nullptr, xab);
    } else {
      // final layer: only the fp32 output x
      ln_kernel<false, true, false><<<MM, 256, 0, stream>>>(
          ybb, ln2_g + (size_t)l * 512, ln2_b + (size_t)l * 512, npm, nullptr,
          x, nullptr);
    }
  }
}

// Round 22
// 872.357 us; speedup vs baseline: 1.2183x; 1.0060x over previous
//
#include <hip/hip_runtime.h>
#include <math.h>

#define BB 4
#define LL 2048
#define DD 512
#define NH 8
#define DINNER 2048
#define NLAYERS 4
#define MM (BB * LL)  // 8192

typedef __attribute__((ext_vector_type(8))) __bf16 bf16x8;
typedef __attribute__((ext_vector_type(4))) float f32x4;
typedef __attribute__((ext_vector_type(4))) unsigned short us4;

__device__ __forceinline__ unsigned short f2b(float f) {
  union { __bf16 h; unsigned short u; } v;
  v.h = (__bf16)f;  // native RNE convert
  return v.u;
}
__device__ __forceinline__ float b2f(unsigned short h) {
  union { unsigned u; float f; } v; v.u = ((unsigned)h) << 16; return v.f;
}
__device__ __forceinline__ unsigned pk2(float lo, float hi) {
  return (unsigned)f2b(lo) | ((unsigned)f2b(hi) << 16);
}
__device__ __forceinline__ float exp2f_fast(float x) {
  float r; asm("v_exp_f32 %0, %1" : "=v"(r) : "v"(x)); return r;
}

__device__ __forceinline__ void gload16(const void* g, void* l) {
  __builtin_amdgcn_global_load_lds(
      (const __attribute__((address_space(1))) void*)g,
      (__attribute__((address_space(3))) void*)l, 16, 0, 0);
}

// ---- init: temporal enc + embedding gather; emits xab = bf16(emb+tem) ----
__global__ __launch_bounds__(512) void init_kernel(
    const int* __restrict__ etype, const float* __restrict__ etime,
    const float* __restrict__ npm, const float* __restrict__ emb,
    float* __restrict__ tem, unsigned short* __restrict__ xab) {
  int row = blockIdx.x;
  int d = threadIdx.x;
  float t = etime[row];
  float mask = npm[row];
  int dd = d & ~1;
  float pv = expf(9.210340371976184f * ((float)dd * (1.0f / (float)DD)));
  float r = t / pv;
  float val = (d & 1) ? cosf(r) : sinf(r);
  float tv = val * mask;
  tem[(size_t)row * DD + d] = tv;
  int ty = etype[row];
  float a = emb[(size_t)ty * DD + d] + tv;
  xab[(size_t)row * DD + d] = f2b(a);
}

// ---- weight transpose+convert (vectorized): fp32 [K][N] -> bf16 [N][K] ----
__global__ __launch_bounds__(256) void wtrans_kernel(
    const float* __restrict__ in, unsigned short* __restrict__ out,
    int K, int N, long in_ls, long out_ls) {
  __shared__ unsigned short t[32][36];
  int l = blockIdx.z;
  int n0 = blockIdx.x * 32, k0 = blockIdx.y * 32;
  int tid = threadIdx.x;
  int r = tid >> 3, c4 = (tid & 7) * 4;
  const float* ip = in + (size_t)l * in_ls;
  unsigned short* op = out + (size_t)l * out_ls;
  float4 v = *(const float4*)&ip[(size_t)(k0 + r) * N + n0 + c4];
  t[r][c4] = f2b(v.x);
  t[r][c4 + 1] = f2b(v.y);
  t[r][c4 + 2] = f2b(v.z);
  t[r][c4 + 3] = f2b(v.w);
  __syncthreads();
  us4 o = {t[c4][r], t[c4 + 1][r], t[c4 + 2][r], t[c4 + 3][r]};
  *(us4*)&op[(size_t)(n0 + r) * K + k0 + c4] = o;
}

// ---- MFMA GEMM, 2-phase pipelined, XCD-chunked 1D grid (T1 swizzle) ----
// C[M,N] = A(bf16 [M,K]) @ WT(bf16 [N,K])^T.  1D grid = (M/BM)*(N/BN),
// nwg % 8 == 0. BK in {32, 64}; BK=64 only for 64x64 tiles.
// RESB16: residual read as bf16 (packed) instead of fp32.
template <int BM, int BN, int BK, bool BIAS, bool RES, bool GELU_, bool OBF16,
          bool RESB16>
__global__ __launch_bounds__(256) void gemm_kernel(
    const unsigned short* __restrict__ A, const unsigned short* __restrict__ WT,
    const float* __restrict__ bias, const void* __restrict__ resv, int ldres,
    void* __restrict__ Cv, int ldc, int M, int N, int K) {
  __shared__ unsigned short As[2][BM * BK];
  __shared__ unsigned short Bs[2][BN * BK];
  constexpr int MT = (BM == 128) ? 4 : ((BN == 64) ? 2 : 4);
  constexpr int NT = (BM == 128 && BN == 128) ? 4 : 2;
  constexpr int KK = BK / 32;  // mfma K=32 sub-steps per k-step
  int tid = threadIdx.x;
  int w = tid >> 6, l = tid & 63;
  int li = l & 15, g = l >> 4;
  // XCD-chunked bijective remap (nwg divisible by 8)
  int nwg = gridDim.x;
  int bid = blockIdx.x;
  int wg = (bid & 7) * (nwg >> 3) + (bid >> 3);
  int gx = N / BN;
  int row0 = (wg / gx) * BM, col0 = (wg % gx) * BN;
  int wm = (BM == 128) ? (w & 1) * 64 : ((BN == 64) ? (w >> 1) * 32 : 0);
  int wnb = (BM == 128) ? (w >> 1) * 64 : ((BN == 64) ? (w & 1) * 32 : w * 32);
  f32x4 acc[MT][NT];
#pragma unroll
  for (int i = 0; i < MT; i++)
#pragma unroll
    for (int j = 0; j < NT; j++) acc[i][j] = (f32x4){0.f, 0.f, 0.f, 0.f};

  int lr = l >> 2;
  int lc = (l & 3) ^ (lr & 3);

  auto stage = [&](int bb, int kb) {
    int k0 = kb * BK;
    if (BK == 64) {
      // 64 rows x 8 chunks of 16B; src chunk XOR-swizzled per row
#pragma unroll
      for (int e = 0; e < 2; e++) {
        int slot = e * 256 + tid;
        int r = slot >> 3, c = slot & 7;
        int src = c ^ (r & 7);
        gload16(A + (size_t)(row0 + r) * K + k0 + src * 8,
                &As[bb][slot * 8]);
        gload16(WT + (size_t)(col0 + r) * K + k0 + src * 8,
                &Bs[bb][slot * 8]);
      }
    } else {
      if (BM == 128) {
#pragma unroll
        for (int i = 0; i < 2; i++) {
          int ai = w * 2 + i;
          gload16(A + (size_t)(row0 + ai * 16 + lr) * K + k0 + lc * 8,
                  &As[bb][ai * 512]);
        }
      } else {
        gload16(A + (size_t)(row0 + w * 16 + lr) * K + k0 + lc * 8,
                &As[bb][w * 512]);
      }
      if (BN == 128) {
#pragma unroll
        for (int i = 0; i < 2; i++) {
          int bi = w * 2 + i;
          gload16(WT + (size_t)(col0 + bi * 16 + lr) * K + k0 + lc * 8,
                  &Bs[bb][bi * 512]);
        }
      } else {
        gload16(WT + (size_t)(col0 + w * 16 + lr) * K + k0 + lc * 8,
                &Bs[bb][w * 512]);
      }
    }
  };

  int nk = K / BK;
  stage(0, 0);
  __syncthreads();
  int buf = 0;
  for (int kb = 0; kb < nk; kb++) {
    if (kb + 1 < nk) stage(buf ^ 1, kb + 1);
    bf16x8 af[MT][KK], bf_[NT][KK];
#pragma unroll
    for (int mt = 0; mt < MT; mt++) {
      int r = wm + mt * 16 + li;
#pragma unroll
      for (int kk = 0; kk < KK; kk++) {
        int off = (BK == 64) ? (r * 64 + ((((kk << 2) | g) ^ (r & 7)) * 8))
                             : (r * 32 + ((g ^ (r & 3)) * 8));
        af[mt][kk] = *(const bf16x8*)&As[buf][off];
      }
    }
#pragma unroll
    for (int nt = 0; nt < NT; nt++) {
      int r = wnb + nt * 16 + li;
#pragma unroll
      for (int kk = 0; kk < KK; kk++) {
        int off = (BK == 64) ? (r * 64 + ((((kk << 2) | g) ^ (r & 7)) * 8))
                             : (r * 32 + ((g ^ (r & 3)) * 8));
        bf_[nt][kk] = *(const bf16x8*)&Bs[buf][off];
      }
    }
#pragma unroll
    for (int kk = 0; kk < KK; kk++)
#pragma unroll
      for (int mt = 0; mt < MT; mt++)
#pragma unroll
        for (int nt = 0; nt < NT; nt++)
          acc[mt][nt] = __builtin_amdgcn_mfma_f32_16x16x32_bf16(
              af[mt][kk], bf_[nt][kk], acc[mt][nt], 0, 0, 0);
    __syncthreads();
    buf ^= 1;
  }
#pragma unroll
  for (int mt = 0; mt < MT; mt++) {
#pragma unroll
    for (int nt = 0; nt < NT; nt++) {
#pragma unroll
      for (int r = 0; r < 4; r++) {
        int row = row0 + wm + mt * 16 + g * 4 + r;
        int col = col0 + wnb + nt * 16 + li;
        float v = acc[mt][nt][r];
        if (BIAS) v += bias[col];
        if (RES) {
          if (RESB16)
            v += b2f(((const unsigned short*)resv)[(size_t)row * ldres + col]);
          else
            v += ((const float*)resv)[(size_t)row * ldres + col];
        }
        if (GELU_) v = 0.5f * v * (1.0f + erff(v * 0.70710678118654752f));
        if (OBF16)
          ((unsigned short*)Cv)[(size_t)row * ldc + col] = f2b(v);
        else
          ((float*)Cv)[(size_t)row * ldc + col] = v;
      }
    }
  }
}

// ---- transpose v slice -> vT [bh*64+d][L] + fused meanV partial sums ----
// grid (32 L-chunks, 32 bh). Partial sum per (bh, chunk) over its 64 keys.
__global__ __launch_bounds__(256) void vtrans_kernel(
    const unsigned short* __restrict__ qkv, unsigned short* __restrict__ vT,
    float* __restrict__ meanVpart) {
  __shared__ unsigned short t[64][65];
  __shared__ float red[4][64];
  int bh = blockIdx.y;
  int b = bh >> 3, h = bh & 7;
  int l0 = blockIdx.x * 64;
  int tid = threadIdx.x;
  int rr = tid >> 4, c4 = (tid & 15) * 4;
#pragma unroll
  for (int pass = 0; pass < 4; pass++) {
    int r = pass * 16 + rr;
    us4 v = *(const us4*)&qkv[(size_t)(b * LL + l0 + r) * 1536 + 1024 +
                              h * 64 + c4];
    t[r][c4] = v[0];
    t[r][c4 + 1] = v[1];
    t[r][c4 + 2] = v[2];
    t[r][c4 + 3] = v[3];
  }
  __syncthreads();
#pragma unroll
  for (int pass = 0; pass < 4; pass++) {
    int r = pass * 16 + rr;  // vT row (d)
    us4 v = {t[c4][r], t[c4 + 1][r], t[c4 + 2][r], t[c4 + 3][r]};
    *(us4*)&vT[((size_t)bh * 64 + r) * LL + l0 + c4] = v;
  }
  // fused meanV partial: sum over this chunk's 64 keys per d
  int p = tid >> 6, d = tid & 63;
  float s = 0.f;
#pragma unroll
  for (int i = 0; i < 16; i++) s += b2f(t[p * 16 + i][d]);
  red[p][d] = s;
  __syncthreads();
  if (p == 0)
    meanVpart[((size_t)bh * 32 + blockIdx.x) * 64 + d] =
        red[0][d] + red[1][d] + red[2][d] + red[3][d];
}

// ---- MFMA flash attention, 2-way KEY-SPLIT; l-sum via all-ones MFMA ----
// (replaces the 16-shuffle psum reduce: D = P @ ones gives every lane the
// row sum of P; accumulated with the same corr rescale as O, so the final
// l is just oL at the epilogue. Halves DS-pipe shuffle pressure per tile.)
__global__ __launch_bounds__(256) void attn_kernel(
    const unsigned short* __restrict__ qkv, const unsigned short* __restrict__ vT,
    const int* __restrict__ etype, unsigned short* __restrict__ opart,
    float* __restrict__ ml) {
  __shared__ unsigned short Ks[2][64 * 64];  // [buf][key*64+d], swizzled 8KB
  __shared__ unsigned short Ps[64][72];
  int hwbid = blockIdx.x;
  int work = (hwbid & 7) * 256 + (hwbid >> 3);  // XCD-chunked (bijective)
  int bh = work >> 6;
  int rem = work & 63;
  int qt = 31 - (rem >> 1);  // LPT: big q-tiles first
  int half = rem & 1;
  int h = bh & 7, b = bh >> 3;
  int q0 = qt * 64;
  int nt = qt + 1;
  int ha = (nt + 1) >> 1;  // half A gets ceil(nt/2), always nonempty
  int j0 = half ? ha : 0;
  int j1 = half ? nt : ha;
  int pidx = (bh * 32 + qt) * 2 + half;
  int tid = threadIdx.x, w = tid >> 6, l = tid & 63;
  int g = l >> 4, li = l & 15;
  const float SC = 0.125f * 1.44269504f;  // scale * log2(e)

  // all-ones bf16 B-fragment (layout-independent row-sum operand)
  union { bf16x8 v; unsigned short u[8]; } ones;
#pragma unroll
  for (int i = 0; i < 8; i++) ones.u[i] = 0x3F80;

  f32x4 o[4];
#pragma unroll
  for (int n = 0; n < 4; n++) o[n] = (f32x4){0.f, 0.f, 0.f, 0.f};
  f32x4 oL = (f32x4){0.f, 0.f, 0.f, 0.f};  // running l per row
  float mreg[4];
#pragma unroll
  for (int r = 0; r < 4; r++) mreg[r] = -3.0e38f;

  if (j0 < j1) {
    const unsigned short* qrp =
        qkv + (size_t)(b * LL + q0 + w * 16 + li) * 1536 + h * 64;
    bf16x8 aq0 = *(const bf16x8*)&qrp[g * 8];
    bf16x8 aq1 = *(const bf16x8*)&qrp[32 + g * 8];

    // prologue: stage tile j0 into buf 0
#pragma unroll
    for (int e = 0; e < 2; e++) {
      int idx = e * 256 + tid;
      int r = idx >> 3;
      int src = (l & 7) ^ (r & 7);
      gload16(
          qkv + (size_t)(b * LL + j0 * 64 + r) * 1536 + 512 + h * 64 + src * 8,
          &Ks[0][(e * 256 + w * 64) * 8]);
    }
    __syncthreads();

    int cur = 0;
    for (int j = j0; j < j1; j++) {
      int k0 = j << 6;
      if (j + 1 < j1) {
#pragma unroll
        for (int e = 0; e < 2; e++) {
          int idx = e * 256 + tid;
          int r = idx >> 3;
          int src = (l & 7) ^ (r & 7);
          gload16(qkv + (size_t)(b * LL + k0 + 64 + r) * 1536 + 512 + h * 64 +
                      src * 8,
                  &Ks[cur ^ 1][(e * 256 + w * 64) * 8]);
        }
      }
      // V frags + pad bias, issued early (L2-resident)
      bf16x8 bv0[4], bv1[4];
      float pb[4];
#pragma unroll
      for (int n = 0; n < 4; n++) {
        const unsigned short* vp =
            vT + ((size_t)(bh * 64 + n * 16 + li)) * LL + k0;
        bv0[n] = *(const bf16x8*)&vp[g * 8];
        bv1[n] = *(const bf16x8*)&vp[32 + g * 8];
        pb[n] = (etype[b * LL + k0 + n * 16 + li] == 0) ? -1.0e9f : 0.f;
      }
      // S = Q K^T from swizzled LDS
      f32x4 s[4];
#pragma unroll
      for (int n = 0; n < 4; n++) {
        int rK = n * 16 + li;
        const unsigned short* kb = &Ks[cur][rK * 64];
        bf16x8 bk0 = *(const bf16x8*)&kb[(g ^ (rK & 7)) * 8];
        bf16x8 bk1 = *(const bf16x8*)&kb[((g + 4) ^ (rK & 7)) * 8];
        f32x4 a = (f32x4){0.f, 0.f, 0.f, 0.f};
        __builtin_amdgcn_s_setprio(1);
        a = __builtin_amdgcn_mfma_f32_16x16x32_bf16(aq0, bk0, a, 0, 0, 0);
        a = __builtin_amdgcn_mfma_f32_16x16x32_bf16(aq1, bk1, a, 0, 0, 0);
        __builtin_amdgcn_s_setprio(0);
        s[n] = a;
      }
      // scale + mask: fast path off-diagonal (pad bias only)
      if (j == qt) {
#pragma unroll
        for (int n = 0; n < 4; n++) {
          int key = k0 + n * 16 + li;
#pragma unroll
          for (int r = 0; r < 4; r++) {
            int qrow = q0 + w * 16 + g * 4 + r;
            float sv = fmaf(s[n][r], SC, pb[n]);
            if (key > qrow) sv = -1.0e9f;
            s[n][r] = sv;
          }
        }
      } else {
#pragma unroll
        for (int n = 0; n < 4; n++)
#pragma unroll
          for (int r = 0; r < 4; r++) s[n][r] = fmaf(s[n][r], SC, pb[n]);
      }
      // wave-parallel online max (reduce across 16 li lanes), exp2 domain
      float pm[4], corr[4];
#pragma unroll
      for (int r = 0; r < 4; r++)
        pm[r] = fmaxf(fmaxf(s[0][r], s[1][r]), fmaxf(s[2][r], s[3][r]));
#pragma unroll
      for (int msk = 1; msk <= 8; msk <<= 1)
#pragma unroll
        for (int r = 0; r < 4; r++)
          pm[r] = fmaxf(pm[r], __shfl_xor(pm[r], msk, 64));
#pragma unroll
      for (int r = 0; r < 4; r++) {
        float mnew = fmaxf(mreg[r], pm[r]);
        corr[r] = exp2f_fast(mreg[r] - mnew);
        mreg[r] = mnew;
#pragma unroll
        for (int n = 0; n < 4; n++) s[n][r] = exp2f_fast(s[n][r] - mnew);
      }
      // P -> LDS (own-wave rows only; same-wave ordering via lgkmcnt)
#pragma unroll
      for (int n = 0; n < 4; n++)
#pragma unroll
        for (int r = 0; r < 4; r++)
          Ps[w * 16 + g * 4 + r][n * 16 + li] = f2b(s[n][r]);
      // rescale O and oL
#pragma unroll
      for (int n = 0; n < 4; n++)
#pragma unroll
        for (int r = 0; r < 4; r++) o[n][r] *= corr[r];
#pragma unroll
      for (int r = 0; r < 4; r++) oL[r] *= corr[r];
      // PV: A = P rows (LDS), B = V frags (regs); +ones-MFMA row sum -> oL
      bf16x8 ap0 = *(const bf16x8*)&Ps[w * 16 + li][g * 8];
      bf16x8 ap1 = *(const bf16x8*)&Ps[w * 16 + li][32 + g * 8];
      __builtin_amdgcn_s_setprio(1);
#pragma unroll
      for (int n = 0; n < 4; n++) {
        o[n] = __builtin_amdgcn_mfma_f32_16x16x32_bf16(ap0, bv0[n], o[n], 0, 0, 0);
        o[n] = __builtin_amdgcn_mfma_f32_16x16x32_bf16(ap1, bv1[n], o[n], 0, 0, 0);
      }
      oL = __builtin_amdgcn_mfma_f32_16x16x32_bf16(ap0, ones.v, oL, 0, 0, 0);
      oL = __builtin_amdgcn_mfma_f32_16x16x32_bf16(ap1, ones.v, oL, 0, 0, 0);
      __builtin_amdgcn_s_setprio(0);
      __syncthreads();  // drains prefetch (vmcnt) + Ks/Ps traffic
      cur ^= 1;
    }
  }
  // epilogue: l-normalized partial O (bf16) + per-row (m,l)
#pragma unroll
  for (int r = 0; r < 4; r++) {
    int qrl = w * 16 + g * 4 + r;
    float lr_ = oL[r];
    float inv = (lr_ > 0.f) ? 1.0f / lr_ : 0.f;
#pragma unroll
    for (int n = 0; n < 4; n++)
      opart[((size_t)pidx * 64 + qrl) * 64 + n * 16 + li] = f2b(o[n][r] * inv);
    if (li == 0) {
      ml[(size_t)pidx * 128 + qrl] = mreg[r];
      ml[(size_t)pidx * 128 + 64 + qrl] = lr_;
    }
  }
}

// ---- merge the two key-split halves (packed 2-wide, static) ----
__global__ __launch_bounds__(256) void amerge_kernel(
    const unsigned short* __restrict__ opart, const float* __restrict__ ml,
    const float* __restrict__ meanVpart, unsigned short* __restrict__ ao) {
  int blk = blockIdx.x;  // bh*32 + qt  (1024 blocks)
  int bh = blk >> 5, qt = blk & 31;
  int b = bh >> 3, h = bh & 7;
  int tid = threadIdx.x;
  int d2 = (tid & 31) * 2;
  int pA = blk * 2, pB = blk * 2 + 1;
  for (int rr = tid >> 5; rr < 64; rr += 8) {
    float mA = ml[(size_t)pA * 128 + rr], lA = ml[(size_t)pA * 128 + 64 + rr];
    float mB = ml[(size_t)pB * 128 + rr], lB = ml[(size_t)pB * 128 + 64 + rr];
    float m = fmaxf(mA, mB);
    float v0, v1;
    if (m <= -1.0e8f) {
      // fully-masked row: uniform softmax over all keys = meanV
      float s0 = 0.f, s1 = 0.f;
      for (int cc = 0; cc < 32; cc++) {
        s0 += meanVpart[((size_t)bh * 32 + cc) * 64 + d2];
        s1 += meanVpart[((size_t)bh * 32 + cc) * 64 + d2 + 1];
      }
      v0 = s0 * (1.0f / (float)LL);
      v1 = s1 * (1.0f / (float)LL);
    } else {
      float a0 = 0.f, a1 = 0.f, wsum = 0.f;
      if (lA > 0.f) {
        float wA = exp2f_fast(mA - m) * lA;
        unsigned ua = *(const unsigned*)&opart[((size_t)pA * 64 + rr) * 64 + d2];
        a0 += b2f((unsigned short)ua) * wA;
        a1 += b2f((unsigned short)(ua >> 16)) * wA;
        wsum += wA;
      }
      if (lB > 0.f) {
        float wB = exp2f_fast(mB - m) * lB;
        unsigned ub = *(const unsigned*)&opart[((size_t)pB * 64 + rr) * 64 + d2];
        a0 += b2f((unsigned short)ub) * wB;
        a1 += b2f((unsigned short)(ub >> 16)) * wB;
        wsum += wB;
      }
      float inv = 1.0f / wsum;
      v0 = a0 * inv;
      v1 = a1 * inv;
    }
    int qr = qt * 64 + rr;
    *(unsigned*)&ao[(size_t)(b * LL + qr) * DD + h * 64 + d2] = pk2(v0, v1);
  }
}

// ---- LayerNorm (+npm), bf16 input. WF32: write fp32 out; WBF: write bf16;
// ADDTEM: emit xab = bf16(x+tem) only. ----
template <bool ADDTEM, bool WF32, bool WBF>
__global__ __launch_bounds__(256) void ln_kernel(
    const unsigned short* __restrict__ in, const float* __restrict__ g,
    const float* __restrict__ bta, const float* __restrict__ npm,
    const float* __restrict__ tem, float* __restrict__ out,
    unsigned short* __restrict__ out_bf) {
  __shared__ float red[4];
  int row = blockIdx.x;
  int tid = threadIdx.x;
  unsigned u = ((const unsigned*)(in + (size_t)row * DD))[tid];
  float v0 = b2f((unsigned short)u), v1 = b2f((unsigned short)(u >> 16));
  int e0 = tid * 2, e1 = tid * 2 + 1;
  float s = v0 + v1;
#pragma unroll
  for (int o = 32; o > 0; o >>= 1) s += __shfl_down(s, o, 64);
  if ((tid & 63) == 0) red[tid >> 6] = s;
  __syncthreads();
  float mean = (red[0] + red[1] + red[2] + red[3]) * (1.0f / (float)DD);
  float d0 = v0 - mean, d1 = v1 - mean;
  float sq = d0 * d0 + d1 * d1;
#pragma unroll
  for (int o = 32; o > 0; o >>= 1) sq += __shfl_down(sq, o, 64);
  __syncthreads();
  if ((tid & 63) == 0) red[tid >> 6] = sq;
  __syncthreads();
  float var = (red[0] + red[1] + red[2] + red[3]) * (1.0f / (float)DD);
  float rstd = rsqrtf(var + 1e-6f);
  float m = npm[row];
  float o0 = (d0 * rstd * g[e0] + bta[e0]) * m;
  float o1 = (d1 * rstd * g[e1] + bta[e1]) * m;
  if (WF32) ((float2*)(out + (size_t)row * DD))[tid] = make_float2(o0, o1);
  if (ADDTEM) {
    float2 tv = ((const float2*)(tem + (size_t)row * DD))[tid];
    ((unsigned*)(out_bf + (size_t)row * DD))[tid] =
        pk2(o0 + tv.x, o1 + tv.y);
  } else if (WBF) {
    ((unsigned*)(out_bf + (size_t)row * DD))[tid] = pk2(o0, o1);
  }
}

extern "C" void kernel_launch(void* const* d_in, const int* in_sizes, int n_in,
                              void* d_out, int out_size, void* d_ws,
                              size_t ws_size, hipStream_t stream) {
  const int* etype = (const int*)d_in[0];
  const float* etime = (const float*)d_in[1];
  const float* npm = (const float*)d_in[2];
  const float* emb = (const float*)d_in[3];
  const float* Wq = (const float*)d_in[4];
  const float* Wk = (const float*)d_in[5];
  const float* Wv = (const float*)d_in[6];
  const float* fc_w = (const float*)d_in[7];
  const float* fc_b = (const float*)d_in[8];
  const float* ln1_g = (const float*)d_in[9];
  const float* ln1_b = (const float*)d_in[10];
  const float* W1 = (const float*)d_in[11];
  const float* b1 = (const float*)d_in[12];
  const float* W2 = (const float*)d_in[13];
  const float* b2 = (const float*)d_in[14];
  const float* ln2_g = (const float*)d_in[15];
  const float* ln2_b = (const float*)d_in[16];

  float* x = (float*)d_out;
  char* ws = (char*)d_ws;
  const size_t SZF = (size_t)MM * DD * sizeof(float);
  const size_t SZB = (size_t)MM * DD * sizeof(short);
  float* tem = (float*)ws; ws += SZF;
  unsigned short* xab = (unsigned short*)ws; ws += SZB;
  unsigned short* xbf = (unsigned short*)ws; ws += SZB;
  unsigned short* qkv = (unsigned short*)ws; ws += (size_t)MM * 1536 * 2;
  unsigned short* vT  = (unsigned short*)ws; ws += (size_t)BB * NH * 64 * LL * 2;
  unsigned short* ao  = (unsigned short*)ws; ws += SZB;
  unsigned short* hb  = (unsigned short*)ws; ws += (size_t)MM * DINNER * 2;
  unsigned short* ybb = (unsigned short*)ws; ws += SZB;  // bf16 LN input
  unsigned short* qkvT = (unsigned short*)ws; ws += (size_t)NLAYERS * 1536 * 512 * 2;
  unsigned short* fcT  = (unsigned short*)ws; ws += (size_t)NLAYERS * 512 * 512 * 2;
  unsigned short* W1T  = (unsigned short*)ws; ws += (size_t)NLAYERS * 2048 * 512 * 2;
  unsigned short* W2T  = (unsigned short*)ws; ws += (size_t)NLAYERS * 512 * 2048 * 2;
  float* meanVpart = (float*)ws; ws += (size_t)32 * 32 * 64 * sizeof(float);
  unsigned short* opart = (unsigned short*)ws; ws += (size_t)2048 * 64 * 64 * 2;
  float* ml = (float*)ws; ws += (size_t)2048 * 128 * sizeof(float);

  init_kernel<<<MM, 512, 0, stream>>>(etype, etime, npm, emb, tem, xab);

  wtrans_kernel<<<dim3(16, 16, NLAYERS), 256, 0, stream>>>(
      Wq, qkvT + 0 * 512 * 512, 512, 512, 512L * 512, 1536L * 512);
  wtrans_kernel<<<dim3(16, 16, NLAYERS), 256, 0, stream>>>(
      Wk, qkvT + 1 * 512 * 512, 512, 512, 512L * 512, 1536L * 512);
  wtrans_kernel<<<dim3(16, 16, NLAYERS), 256, 0, stream>>>(
      Wv, qkvT + 2 * 512 * 512, 512, 512, 512L * 512, 1536L * 512);
  wtrans_kernel<<<dim3(16, 16, NLAYERS), 256, 0, stream>>>(
      fc_w, fcT, 512, 512, 512L * 512, 512L * 512);
  wtrans_kernel<<<dim3(64, 16, NLAYERS), 256, 0, stream>>>(
      W1, W1T, 512, 2048, 512L * 2048, 2048L * 512);
  wtrans_kernel<<<dim3(16, 64, NLAYERS), 256, 0, stream>>>(
      W2, W2T, 2048, 512, 2048L * 512, 512L * 2048);

  for (int l = 0; l < NLAYERS; l++) {
    // QKV (grid 3072, 64x64x64 tiles)
    gemm_kernel<64, 64, 64, false, false, false, true, false>
        <<<128 * 24, 256, 0, stream>>>(
            xab, qkvT + (size_t)l * 1536 * 512, nullptr, nullptr, 0, qkv, 1536,
            MM, 1536, 512);

    vtrans_kernel<<<dim3(32, 32), 256, 0, stream>>>(qkv, vT, meanVpart);
    attn_kernel<<<2048, 256, 0, stream>>>(qkv, vT, etype, opart, ml);
    amerge_kernel<<<1024, 256, 0, stream>>>(opart, ml, meanVpart, ao);

    // fc: +bias +residual(xab bf16) -> bf16 ybb (grid 1024, 64x64x64)
    gemm_kernel<64, 64, 64, true, true, false, true, true>
        <<<128 * 8, 256, 0, stream>>>(
            ao, fcT + (size_t)l * 512 * 512, fc_b + (size_t)l * 512, xab, 512,
            ybb, 512, MM, 512, 512);
    // LN1: bf16 out only
    ln_kernel<false, false, true><<<MM, 256, 0, stream>>>(
        ybb, ln1_g + (size_t)l * 512, ln1_b + (size_t)l * 512, npm, nullptr,
        nullptr, xbf);

    // FFN1 (grid 4096, 64x64x64 tiles)
    gemm_kernel<64, 64, 64, true, false, true, true, false>
        <<<128 * 32, 256, 0, stream>>>(
            xbf, W1T + (size_t)l * 2048 * 512, b1 + (size_t)l * 2048, nullptr,
            0, hb, 2048, MM, 2048, 512);
    // FFN2: +bias +residual(xbf bf16) -> bf16 ybb (grid 1024, 64x64x64)
    gemm_kernel<64, 64, 64, true, true, false, true, true>
        <<<128 * 8, 256, 0, stream>>>(
            hb, W2T + (size_t)l * 512 * 2048, b2 + (size_t)l * 512, xbf, 512,
            ybb, 512, MM, 512, 2048);
    if (l + 1 < NLAYERS) {
      // LN2: xab (bf16 of x+tem) for next layer
      ln_kernel<true, false, false><<<MM, 256, 0, stream>>>(
          ybb, ln2_g + (size_t)l * 512, ln2_b + (size_t)l * 512, npm, tem,
          nullptr, xab);
    } else {
      // final layer: only the fp32 output x
      ln_kernel<false, true, false><<<MM, 256, 0, stream>>>(
          ybb, ln2_g + (size_t)l * 512, ln2_b + (size_t)l * 512, npm, nullptr,
          x, nullptr);
    }
  }
}

// Round 23
// 869.249 us; speedup vs baseline: 1.2227x; 1.0036x over previous
//
#include <hip/hip_runtime.h>
#include <math.h>

#define BB 4
#define LL 2048
#define DD 512
#define NH 8
#define DINNER 2048
#define NLAYERS 4
#define MM (BB * LL)  // 8192

typedef __attribute__((ext_vector_type(8))) __bf16 bf16x8;
typedef __attribute__((ext_vector_type(4))) float f32x4;
typedef __attribute__((ext_vector_type(4))) unsigned short us4;

__device__ __forceinline__ unsigned short f2b(float f) {
  union { __bf16 h; unsigned short u; } v;
  v.h = (__bf16)f;  // native RNE convert
  return v.u;
}
__device__ __forceinline__ float b2f(unsigned short h) {
  union { unsigned u; float f; } v; v.u = ((unsigned)h) << 16; return v.f;
}
__device__ __forceinline__ unsigned pk2(float lo, float hi) {
  return (unsigned)f2b(lo) | ((unsigned)f2b(hi) << 16);
}
__device__ __forceinline__ float exp2f_fast(float x) {
  float r; asm("v_exp_f32 %0, %1" : "=v"(r) : "v"(x)); return r;
}

__device__ __forceinline__ void gload16(const void* g, void* l) {
  __builtin_amdgcn_global_load_lds(
      (const __attribute__((address_space(1))) void*)g,
      (__attribute__((address_space(3))) void*)l, 16, 0, 0);
}

// ---- init: temporal enc + embedding gather; emits xab = bf16(emb+tem) ----
__global__ __launch_bounds__(512) void init_kernel(
    const int* __restrict__ etype, const float* __restrict__ etime,
    const float* __restrict__ npm, const float* __restrict__ emb,
    float* __restrict__ tem, unsigned short* __restrict__ xab) {
  int row = blockIdx.x;
  int d = threadIdx.x;
  float t = etime[row];
  float mask = npm[row];
  int dd = d & ~1;
  float pv = expf(9.210340371976184f * ((float)dd * (1.0f / (float)DD)));
  float r = t / pv;
  float val = (d & 1) ? cosf(r) : sinf(r);
  float tv = val * mask;
  tem[(size_t)row * DD + d] = tv;
  int ty = etype[row];
  float a = emb[(size_t)ty * DD + d] + tv;
  xab[(size_t)row * DD + d] = f2b(a);
}

// ---- weight transpose+convert (vectorized): fp32 [K][N] -> bf16 [N][K] ----
__global__ __launch_bounds__(256) void wtrans_kernel(
    const float* __restrict__ in, unsigned short* __restrict__ out,
    int K, int N, long in_ls, long out_ls) {
  __shared__ unsigned short t[32][36];
  int l = blockIdx.z;
  int n0 = blockIdx.x * 32, k0 = blockIdx.y * 32;
  int tid = threadIdx.x;
  int r = tid >> 3, c4 = (tid & 7) * 4;
  const float* ip = in + (size_t)l * in_ls;
  unsigned short* op = out + (size_t)l * out_ls;
  float4 v = *(const float4*)&ip[(size_t)(k0 + r) * N + n0 + c4];
  t[r][c4] = f2b(v.x);
  t[r][c4 + 1] = f2b(v.y);
  t[r][c4 + 2] = f2b(v.z);
  t[r][c4 + 3] = f2b(v.w);
  __syncthreads();
  us4 o = {t[c4][r], t[c4 + 1][r], t[c4 + 2][r], t[c4 + 3][r]};
  *(us4*)&op[(size_t)(n0 + r) * K + k0 + c4] = o;
}

// ---- MFMA GEMM, 2-phase pipelined, XCD-chunked 1D grid (T1 swizzle) ----
// C[M,N] = A(bf16 [M,K]) @ WT(bf16 [N,K])^T.  1D grid = (M/BM)*(N/BN),
// nwg % 8 == 0. BK in {32, 64}; BK=64 only for 64x64 tiles.
// RESB16: residual read as bf16 (packed) instead of fp32.
template <int BM, int BN, int BK, bool BIAS, bool RES, bool GELU_, bool OBF16,
          bool RESB16>
__global__ __launch_bounds__(256) void gemm_kernel(
    const unsigned short* __restrict__ A, const unsigned short* __restrict__ WT,
    const float* __restrict__ bias, const void* __restrict__ resv, int ldres,
    void* __restrict__ Cv, int ldc, int M, int N, int K) {
  __shared__ unsigned short As[2][BM * BK];
  __shared__ unsigned short Bs[2][BN * BK];
  constexpr int MT = (BM == 128) ? 4 : ((BN == 64) ? 2 : 4);
  constexpr int NT = (BM == 128 && BN == 128) ? 4 : 2;
  constexpr int KK = BK / 32;  // mfma K=32 sub-steps per k-step
  int tid = threadIdx.x;
  int w = tid >> 6, l = tid & 63;
  int li = l & 15, g = l >> 4;
  // XCD-chunked bijective remap (nwg divisible by 8)
  int nwg = gridDim.x;
  int bid = blockIdx.x;
  int wg = (bid & 7) * (nwg >> 3) + (bid >> 3);
  int gx = N / BN;
  int row0 = (wg / gx) * BM, col0 = (wg % gx) * BN;
  int wm = (BM == 128) ? (w & 1) * 64 : ((BN == 64) ? (w >> 1) * 32 : 0);
  int wnb = (BM == 128) ? (w >> 1) * 64 : ((BN == 64) ? (w & 1) * 32 : w * 32);
  f32x4 acc[MT][NT];
#pragma unroll
  for (int i = 0; i < MT; i++)
#pragma unroll
    for (int j = 0; j < NT; j++) acc[i][j] = (f32x4){0.f, 0.f, 0.f, 0.f};

  int lr = l >> 2;
  int lc = (l & 3) ^ (lr & 3);

  auto stage = [&](int bb, int kb) {
    int k0 = kb * BK;
    if (BK == 64) {
      // 64 rows x 8 chunks of 16B; src chunk XOR-swizzled per row
#pragma unroll
      for (int e = 0; e < 2; e++) {
        int slot = e * 256 + tid;
        int r = slot >> 3, c = slot & 7;
        int src = c ^ (r & 7);
        gload16(A + (size_t)(row0 + r) * K + k0 + src * 8,
                &As[bb][slot * 8]);
        gload16(WT + (size_t)(col0 + r) * K + k0 + src * 8,
                &Bs[bb][slot * 8]);
      }
    } else {
      if (BM == 128) {
#pragma unroll
        for (int i = 0; i < 2; i++) {
          int ai = w * 2 + i;
          gload16(A + (size_t)(row0 + ai * 16 + lr) * K + k0 + lc * 8,
                  &As[bb][ai * 512]);
        }
      } else {
        gload16(A + (size_t)(row0 + w * 16 + lr) * K + k0 + lc * 8,
                &As[bb][w * 512]);
      }
      if (BN == 128) {
#pragma unroll
        for (int i = 0; i < 2; i++) {
          int bi = w * 2 + i;
          gload16(WT + (size_t)(col0 + bi * 16 + lr) * K + k0 + lc * 8,
                  &Bs[bb][bi * 512]);
        }
      } else {
        gload16(WT + (size_t)(col0 + w * 16 + lr) * K + k0 + lc * 8,
                &Bs[bb][w * 512]);
      }
    }
  };

  int nk = K / BK;
  stage(0, 0);
  __syncthreads();
  int buf = 0;
  for (int kb = 0; kb < nk; kb++) {
    if (kb + 1 < nk) stage(buf ^ 1, kb + 1);
    bf16x8 af[MT][KK], bf_[NT][KK];
#pragma unroll
    for (int mt = 0; mt < MT; mt++) {
      int r = wm + mt * 16 + li;
#pragma unroll
      for (int kk = 0; kk < KK; kk++) {
        int off = (BK == 64) ? (r * 64 + ((((kk << 2) | g) ^ (r & 7)) * 8))
                             : (r * 32 + ((g ^ (r & 3)) * 8));
        af[mt][kk] = *(const bf16x8*)&As[buf][off];
      }
    }
#pragma unroll
    for (int nt = 0; nt < NT; nt++) {
      int r = wnb + nt * 16 + li;
#pragma unroll
      for (int kk = 0; kk < KK; kk++) {
        int off = (BK == 64) ? (r * 64 + ((((kk << 2) | g) ^ (r & 7)) * 8))
                             : (r * 32 + ((g ^ (r & 3)) * 8));
        bf_[nt][kk] = *(const bf16x8*)&Bs[buf][off];
      }
    }
#pragma unroll
    for (int kk = 0; kk < KK; kk++)
#pragma unroll
      for (int mt = 0; mt < MT; mt++)
#pragma unroll
        for (int nt = 0; nt < NT; nt++)
          acc[mt][nt] = __builtin_amdgcn_mfma_f32_16x16x32_bf16(
              af[mt][kk], bf_[nt][kk], acc[mt][nt], 0, 0, 0);
    __syncthreads();
    buf ^= 1;
  }
#pragma unroll
  for (int mt = 0; mt < MT; mt++) {
#pragma unroll
    for (int nt = 0; nt < NT; nt++) {
#pragma unroll
      for (int r = 0; r < 4; r++) {
        int row = row0 + wm + mt * 16 + g * 4 + r;
        int col = col0 + wnb + nt * 16 + li;
        float v = acc[mt][nt][r];
        if (BIAS) v += bias[col];
        if (RES) {
          if (RESB16)
            v += b2f(((const unsigned short*)resv)[(size_t)row * ldres + col]);
          else
            v += ((const float*)resv)[(size_t)row * ldres + col];
        }
        if (GELU_) v = 0.5f * v * (1.0f + erff(v * 0.70710678118654752f));
        if (OBF16)
          ((unsigned short*)Cv)[(size_t)row * ldc + col] = f2b(v);
        else
          ((float*)Cv)[(size_t)row * ldc + col] = v;
      }
    }
  }
}

// ---- transpose v slice -> vT [bh*64+d][L] + fused meanV partial sums ----
// grid (32 L-chunks, 32 bh). Partial sum per (bh, chunk) over its 64 keys.
__global__ __launch_bounds__(256) void vtrans_kernel(
    const unsigned short* __restrict__ qkv, unsigned short* __restrict__ vT,
    float* __restrict__ meanVpart) {
  __shared__ unsigned short t[64][65];
  __shared__ float red[4][64];
  int bh = blockIdx.y;
  int b = bh >> 3, h = bh & 7;
  int l0 = blockIdx.x * 64;
  int tid = threadIdx.x;
  int rr = tid >> 4, c4 = (tid & 15) * 4;
#pragma unroll
  for (int pass = 0; pass < 4; pass++) {
    int r = pass * 16 + rr;
    us4 v = *(const us4*)&qkv[(size_t)(b * LL + l0 + r) * 1536 + 1024 +
                              h * 64 + c4];
    t[r][c4] = v[0];
    t[r][c4 + 1] = v[1];
    t[r][c4 + 2] = v[2];
    t[r][c4 + 3] = v[3];
  }
  __syncthreads();
#pragma unroll
  for (int pass = 0; pass < 4; pass++) {
    int r = pass * 16 + rr;  // vT row (d)
    us4 v = {t[c4][r], t[c4 + 1][r], t[c4 + 2][r], t[c4 + 3][r]};
    *(us4*)&vT[((size_t)bh * 64 + r) * LL + l0 + c4] = v;
  }
  // fused meanV partial: sum over this chunk's 64 keys per d
  int p = tid >> 6, d = tid & 63;
  float s = 0.f;
#pragma unroll
  for (int i = 0; i < 16; i++) s += b2f(t[p * 16 + i][d]);
  red[p][d] = s;
  __syncthreads();
  if (p == 0)
    meanVpart[((size_t)bh * 32 + blockIdx.x) * 64 + d] =
        red[0][d] + red[1][d] + red[2][d] + red[3][d];
}

// ---- MFMA flash attention, 2-way KEY-SPLIT; ones-MFMA l-sum + defer-max ----
__global__ __launch_bounds__(256) void attn_kernel(
    const unsigned short* __restrict__ qkv, const unsigned short* __restrict__ vT,
    const int* __restrict__ etype, unsigned short* __restrict__ opart,
    float* __restrict__ ml) {
  __shared__ unsigned short Ks[2][64 * 64];  // [buf][key*64+d], swizzled 8KB
  __shared__ unsigned short Ps[64][72];
  int hwbid = blockIdx.x;
  int work = (hwbid & 7) * 256 + (hwbid >> 3);  // XCD-chunked (bijective)
  int bh = work >> 6;
  int rem = work & 63;
  int qt = 31 - (rem >> 1);  // LPT: big q-tiles first
  int half = rem & 1;
  int h = bh & 7, b = bh >> 3;
  int q0 = qt * 64;
  int nt = qt + 1;
  int ha = (nt + 1) >> 1;  // half A gets ceil(nt/2), always nonempty
  int j0 = half ? ha : 0;
  int j1 = half ? nt : ha;
  int pidx = (bh * 32 + qt) * 2 + half;
  int tid = threadIdx.x, w = tid >> 6, l = tid & 63;
  int g = l >> 4, li = l & 15;
  const float SC = 0.125f * 1.44269504f;  // scale * log2(e)

  // all-ones bf16 B-fragment (layout-independent row-sum operand)
  union { bf16x8 v; unsigned short u[8]; } ones;
#pragma unroll
  for (int i = 0; i < 8; i++) ones.u[i] = 0x3F80;

  f32x4 o[4];
#pragma unroll
  for (int n = 0; n < 4; n++) o[n] = (f32x4){0.f, 0.f, 0.f, 0.f};
  f32x4 oL = (f32x4){0.f, 0.f, 0.f, 0.f};  // running l per row
  float mreg[4];
#pragma unroll
  for (int r = 0; r < 4; r++) mreg[r] = -3.0e38f;

  if (j0 < j1) {
    const unsigned short* qrp =
        qkv + (size_t)(b * LL + q0 + w * 16 + li) * 1536 + h * 64;
    bf16x8 aq0 = *(const bf16x8*)&qrp[g * 8];
    bf16x8 aq1 = *(const bf16x8*)&qrp[32 + g * 8];

    // prologue: stage tile j0 into buf 0
#pragma unroll
    for (int e = 0; e < 2; e++) {
      int idx = e * 256 + tid;
      int r = idx >> 3;
      int src = (l & 7) ^ (r & 7);
      gload16(
          qkv + (size_t)(b * LL + j0 * 64 + r) * 1536 + 512 + h * 64 + src * 8,
          &Ks[0][(e * 256 + w * 64) * 8]);
    }
    __syncthreads();

    int cur = 0;
    for (int j = j0; j < j1; j++) {
      int k0 = j << 6;
      if (j + 1 < j1) {
#pragma unroll
        for (int e = 0; e < 2; e++) {
          int idx = e * 256 + tid;
          int r = idx >> 3;
          int src = (l & 7) ^ (r & 7);
          gload16(qkv + (size_t)(b * LL + k0 + 64 + r) * 1536 + 512 + h * 64 +
                      src * 8,
                  &Ks[cur ^ 1][(e * 256 + w * 64) * 8]);
        }
      }
      // V frags + pad bias, issued early (L2-resident)
      bf16x8 bv0[4], bv1[4];
      float pb[4];
#pragma unroll
      for (int n = 0; n < 4; n++) {
        const unsigned short* vp =
            vT + ((size_t)(bh * 64 + n * 16 + li)) * LL + k0;
        bv0[n] = *(const bf16x8*)&vp[g * 8];
        bv1[n] = *(const bf16x8*)&vp[32 + g * 8];
        pb[n] = (etype[b * LL + k0 + n * 16 + li] == 0) ? -1.0e9f : 0.f;
      }
      // S = Q K^T from swizzled LDS
      f32x4 s[4];
#pragma unroll
      for (int n = 0; n < 4; n++) {
        int rK = n * 16 + li;
        const unsigned short* kb = &Ks[cur][rK * 64];
        bf16x8 bk0 = *(const bf16x8*)&kb[(g ^ (rK & 7)) * 8];
        bf16x8 bk1 = *(const bf16x8*)&kb[((g + 4) ^ (rK & 7)) * 8];
        f32x4 a = (f32x4){0.f, 0.f, 0.f, 0.f};
        __builtin_amdgcn_s_setprio(1);
        a = __builtin_amdgcn_mfma_f32_16x16x32_bf16(aq0, bk0, a, 0, 0, 0);
        a = __builtin_amdgcn_mfma_f32_16x16x32_bf16(aq1, bk1, a, 0, 0, 0);
        __builtin_amdgcn_s_setprio(0);
        s[n] = a;
      }
      // scale + mask: fast path off-diagonal (pad bias only)
      if (j == qt) {
#pragma unroll
        for (int n = 0; n < 4; n++) {
          int key = k0 + n * 16 + li;
#pragma unroll
          for (int r = 0; r < 4; r++) {
            int qrow = q0 + w * 16 + g * 4 + r;
            float sv = fmaf(s[n][r], SC, pb[n]);
            if (key > qrow) sv = -1.0e9f;
            s[n][r] = sv;
          }
        }
      } else {
#pragma unroll
        for (int n = 0; n < 4; n++)
#pragma unroll
          for (int r = 0; r < 4; r++) s[n][r] = fmaf(s[n][r], SC, pb[n]);
      }
      // wave-parallel online max (reduce across 16 li lanes), exp2 domain
      float pm[4];
#pragma unroll
      for (int r = 0; r < 4; r++)
        pm[r] = fmaxf(fmaxf(s[0][r], s[1][r]), fmaxf(s[2][r], s[3][r]));
#pragma unroll
      for (int msk = 1; msk <= 8; msk <<= 1)
#pragma unroll
        for (int r = 0; r < 4; r++)
          pm[r] = fmaxf(pm[r], __shfl_xor(pm[r], msk, 64));
      // defer-max (T13): rescale only when some row's max grew by > 8
      // (P then bounded by 2^8; merge math is exact for any reference m)
      bool need = false;
#pragma unroll
      for (int r = 0; r < 4; r++) need = need || (pm[r] > mreg[r] + 8.0f);
      if (__any(need)) {
#pragma unroll
        for (int r = 0; r < 4; r++) {
          float mnew = fmaxf(mreg[r], pm[r]);
          float corr = exp2f_fast(mreg[r] - mnew);
          mreg[r] = mnew;
#pragma unroll
          for (int n = 0; n < 4; n++) o[n][r] *= corr;
          oL[r] *= corr;
        }
      }
#pragma unroll
      for (int n = 0; n < 4; n++)
#pragma unroll
        for (int r = 0; r < 4; r++) s[n][r] = exp2f_fast(s[n][r] - mreg[r]);
      // P -> LDS (own-wave rows only; same-wave ordering via lgkmcnt)
#pragma unroll
      for (int n = 0; n < 4; n++)
#pragma unroll
        for (int r = 0; r < 4; r++)
          Ps[w * 16 + g * 4 + r][n * 16 + li] = f2b(s[n][r]);
      // PV: A = P rows (LDS), B = V frags (regs); +ones-MFMA row sum -> oL
      bf16x8 ap0 = *(const bf16x8*)&Ps[w * 16 + li][g * 8];
      bf16x8 ap1 = *(const bf16x8*)&Ps[w * 16 + li][32 + g * 8];
      __builtin_amdgcn_s_setprio(1);
#pragma unroll
      for (int n = 0; n < 4; n++) {
        o[n] = __builtin_amdgcn_mfma_f32_16x16x32_bf16(ap0, bv0[n], o[n], 0, 0, 0);
        o[n] = __builtin_amdgcn_mfma_f32_16x16x32_bf16(ap1, bv1[n], o[n], 0, 0, 0);
      }
      oL = __builtin_amdgcn_mfma_f32_16x16x32_bf16(ap0, ones.v, oL, 0, 0, 0);
      oL = __builtin_amdgcn_mfma_f32_16x16x32_bf16(ap1, ones.v, oL, 0, 0, 0);
      __builtin_amdgcn_s_setprio(0);
      __syncthreads();  // drains prefetch (vmcnt) + Ks/Ps traffic
      cur ^= 1;
    }
  }
  // epilogue: l-normalized partial O (bf16) + per-row (m,l)
#pragma unroll
  for (int r = 0; r < 4; r++) {
    int qrl = w * 16 + g * 4 + r;
    float lr_ = oL[r];
    float inv = (lr_ > 0.f) ? 1.0f / lr_ : 0.f;
#pragma unroll
    for (int n = 0; n < 4; n++)
      opart[((size_t)pidx * 64 + qrl) * 64 + n * 16 + li] = f2b(o[n][r] * inv);
    if (li == 0) {
      ml[(size_t)pidx * 128 + qrl] = mreg[r];
      ml[(size_t)pidx * 128 + 64 + qrl] = lr_;
    }
  }
}

// ---- merge the two key-split halves (packed 2-wide, static) ----
__global__ __launch_bounds__(256) void amerge_kernel(
    const unsigned short* __restrict__ opart, const float* __restrict__ ml,
    const float* __restrict__ meanVpart, unsigned short* __restrict__ ao) {
  int blk = blockIdx.x;  // bh*32 + qt  (1024 blocks)
  int bh = blk >> 5, qt = blk & 31;
  int b = bh >> 3, h = bh & 7;
  int tid = threadIdx.x;
  int d2 = (tid & 31) * 2;
  int pA = blk * 2, pB = blk * 2 + 1;
  for (int rr = tid >> 5; rr < 64; rr += 8) {
    float mA = ml[(size_t)pA * 128 + rr], lA = ml[(size_t)pA * 128 + 64 + rr];
    float mB = ml[(size_t)pB * 128 + rr], lB = ml[(size_t)pB * 128 + 64 + rr];
    float m = fmaxf(mA, mB);
    float v0, v1;
    if (m <= -1.0e8f) {
      // fully-masked row: uniform softmax over all keys = meanV
      float s0 = 0.f, s1 = 0.f;
      for (int cc = 0; cc < 32; cc++) {
        s0 += meanVpart[((size_t)bh * 32 + cc) * 64 + d2];
        s1 += meanVpart[((size_t)bh * 32 + cc) * 64 + d2 + 1];
      }
      v0 = s0 * (1.0f / (float)LL);
      v1 = s1 * (1.0f / (float)LL);
    } else {
      float a0 = 0.f, a1 = 0.f, wsum = 0.f;
      if (lA > 0.f) {
        float wA = exp2f_fast(mA - m) * lA;
        unsigned ua = *(const unsigned*)&opart[((size_t)pA * 64 + rr) * 64 + d2];
        a0 += b2f((unsigned short)ua) * wA;
        a1 += b2f((unsigned short)(ua >> 16)) * wA;
        wsum += wA;
      }
      if (lB > 0.f) {
        float wB = exp2f_fast(mB - m) * lB;
        unsigned ub = *(const unsigned*)&opart[((size_t)pB * 64 + rr) * 64 + d2];
        a0 += b2f((unsigned short)ub) * wB;
        a1 += b2f((unsigned short)(ub >> 16)) * wB;
        wsum += wB;
      }
      float inv = 1.0f / wsum;
      v0 = a0 * inv;
      v1 = a1 * inv;
    }
    int qr = qt * 64 + rr;
    *(unsigned*)&ao[(size_t)(b * LL + qr) * DD + h * 64 + d2] = pk2(v0, v1);
  }
}

// ---- LayerNorm (+npm), bf16 input. WF32: write fp32 out; WBF: write bf16;
// ADDTEM: emit xab = bf16(x+tem) only. ----
template <bool ADDTEM, bool WF32, bool WBF>
__global__ __launch_bounds__(256) void ln_kernel(
    const unsigned short* __restrict__ in, const float* __restrict__ g,
    const float* __restrict__ bta, const float* __restrict__ npm,
    const float* __restrict__ tem, float* __restrict__ out,
    unsigned short* __restrict__ out_bf) {
  __shared__ float red[4];
  int row = blockIdx.x;
  int tid = threadIdx.x;
  unsigned u = ((const unsigned*)(in + (size_t)row * DD))[tid];
  float v0 = b2f((unsigned short)u), v1 = b2f((unsigned short)(u >> 16));
  int e0 = tid * 2, e1 = tid * 2 + 1;
  float s = v0 + v1;
#pragma unroll
  for (int o = 32; o > 0; o >>= 1) s += __shfl_down(s, o, 64);
  if ((tid & 63) == 0) red[tid >> 6] = s;
  __syncthreads();
  float mean = (red[0] + red[1] + red[2] + red[3]) * (1.0f / (float)DD);
  float d0 = v0 - mean, d1 = v1 - mean;
  float sq = d0 * d0 + d1 * d1;
#pragma unroll
  for (int o = 32; o > 0; o >>= 1) sq += __shfl_down(sq, o, 64);
  __syncthreads();
  if ((tid & 63) == 0) red[tid >> 6] = sq;
  __syncthreads();
  float var = (red[0] + red[1] + red[2] + red[3]) * (1.0f / (float)DD);
  float rstd = rsqrtf(var + 1e-6f);
  float m = npm[row];
  float o0 = (d0 * rstd * g[e0] + bta[e0]) * m;
  float o1 = (d1 * rstd * g[e1] + bta[e1]) * m;
  if (WF32) ((float2*)(out + (size_t)row * DD))[tid] = make_float2(o0, o1);
  if (ADDTEM) {
    float2 tv = ((const float2*)(tem + (size_t)row * DD))[tid];
    ((unsigned*)(out_bf + (size_t)row * DD))[tid] =
        pk2(o0 + tv.x, o1 + tv.y);
  } else if (WBF) {
    ((unsigned*)(out_bf + (size_t)row * DD))[tid] = pk2(o0, o1);
  }
}

extern "C" void kernel_launch(void* const* d_in, const int* in_sizes, int n_in,
                              void* d_out, int out_size, void* d_ws,
                              size_t ws_size, hipStream_t stream) {
  const int* etype = (const int*)d_in[0];
  const float* etime = (const float*)d_in[1];
  const float* npm = (const float*)d_in[2];
  const float* emb = (const float*)d_in[3];
  const float* Wq = (const float*)d_in[4];
  const float* Wk = (const float*)d_in[5];
  const float* Wv = (const float*)d_in[6];
  const float* fc_w = (const float*)d_in[7];
  const float* fc_b = (const float*)d_in[8];
  const float* ln1_g = (const float*)d_in[9];
  const float* ln1_b = (const float*)d_in[10];
  const float* W1 = (const float*)d_in[11];
  const float* b1 = (const float*)d_in[12];
  const float* W2 = (const float*)d_in[13];
  const float* b2 = (const float*)d_in[14];
  const float* ln2_g = (const float*)d_in[15];
  const float* ln2_b = (const float*)d_in[16];

  float* x = (float*)d_out;
  char* ws = (char*)d_ws;
  const size_t SZF = (size_t)MM * DD * sizeof(float);
  const size_t SZB = (size_t)MM * DD * sizeof(short);
  float* tem = (float*)ws; ws += SZF;
  unsigned short* xab = (unsigned short*)ws; ws += SZB;
  unsigned short* xbf = (unsigned short*)ws; ws += SZB;
  unsigned short* qkv = (unsigned short*)ws; ws += (size_t)MM * 1536 * 2;
  unsigned short* vT  = (unsigned short*)ws; ws += (size_t)BB * NH * 64 * LL * 2;
  unsigned short* ao  = (unsigned short*)ws; ws += SZB;
  unsigned short* hb  = (unsigned short*)ws; ws += (size_t)MM * DINNER * 2;
  unsigned short* ybb = (unsigned short*)ws; ws += SZB;  // bf16 LN input
  unsigned short* qkvT = (unsigned short*)ws; ws += (size_t)NLAYERS * 1536 * 512 * 2;
  unsigned short* fcT  = (unsigned short*)ws; ws += (size_t)NLAYERS * 512 * 512 * 2;
  unsigned short* W1T  = (unsigned short*)ws; ws += (size_t)NLAYERS * 2048 * 512 * 2;
  unsigned short* W2T  = (unsigned short*)ws; ws += (size_t)NLAYERS * 512 * 2048 * 2;
  float* meanVpart = (float*)ws; ws += (size_t)32 * 32 * 64 * sizeof(float);
  unsigned short* opart = (unsigned short*)ws; ws += (size_t)2048 * 64 * 64 * 2;
  float* ml = (float*)ws; ws += (size_t)2048 * 128 * sizeof(float);

  init_kernel<<<MM, 512, 0, stream>>>(etype, etime, npm, emb, tem, xab);

  wtrans_kernel<<<dim3(16, 16, NLAYERS), 256, 0, stream>>>(
      Wq, qkvT + 0 * 512 * 512, 512, 512, 512L * 512, 1536L * 512);
  wtrans_kernel<<<dim3(16, 16, NLAYERS), 256, 0, stream>>>(
      Wk, qkvT + 1 * 512 * 512, 512, 512, 512L * 512, 1536L * 512);
  wtrans_kernel<<<dim3(16, 16, NLAYERS), 256, 0, stream>>>(
      Wv, qkvT + 2 * 512 * 512, 512, 512, 512L * 512, 1536L * 512);
  wtrans_kernel<<<dim3(16, 16, NLAYERS), 256, 0, stream>>>(
      fc_w, fcT, 512, 512, 512L * 512, 512L * 512);
  wtrans_kernel<<<dim3(64, 16, NLAYERS), 256, 0, stream>>>(
      W1, W1T, 512, 2048, 512L * 2048, 2048L * 512);
  wtrans_kernel<<<dim3(16, 64, NLAYERS), 256, 0, stream>>>(
      W2, W2T, 2048, 512, 2048L * 512, 512L * 2048);

  for (int l = 0; l < NLAYERS; l++) {
    // QKV (grid 3072, 64x64x64 tiles)
    gemm_kernel<64, 64, 64, false, false, false, true, false>
        <<<128 * 24, 256, 0, stream>>>(
            xab, qkvT + (size_t)l * 1536 * 512, nullptr, nullptr, 0, qkv, 1536,
            MM, 1536, 512);

    vtrans_kernel<<<dim3(32, 32), 256, 0, stream>>>(qkv, vT, meanVpart);
    attn_kernel<<<2048, 256, 0, stream>>>(qkv, vT, etype, opart, ml);
    amerge_kernel<<<1024, 256, 0, stream>>>(opart, ml, meanVpart, ao);

    // fc: +bias +residual(xab bf16) -> bf16 ybb (grid 1024, 64x64x64)
    gemm_kernel<64, 64, 64, true, true, false, true, true>
        <<<128 * 8, 256, 0, stream>>>(
            ao, fcT + (size_t)l * 512 * 512, fc_b + (size_t)l * 512, xab, 512,
            ybb, 512, MM, 512, 512);
    // LN1: bf16 out only
    ln_kernel<false, false, true><<<MM, 256, 0, stream>>>(
        ybb, ln1_g + (size_t)l * 512, ln1_b + (size_t)l * 512, npm, nullptr,
        nullptr, xbf);

    // FFN1 (grid 4096, 64x64x64 tiles)
    gemm_kernel<64, 64, 64, true, false, true, true, false>
        <<<128 * 32, 256, 0, stream>>>(
            xbf, W1T + (size_t)l * 2048 * 512, b1 + (size_t)l * 2048, nullptr,
            0, hb, 2048, MM, 2048, 512);
    // FFN2: +bias +residual(xbf bf16) -> bf16 ybb (grid 1024, 64x64x64)
    gemm_kernel<64, 64, 64, true, true, false, true, true>
        <<<128 * 8, 256, 0, stream>>>(
            hb, W2T + (size_t)l * 512 * 2048, b2 + (size_t)l * 512, xbf, 512,
            ybb, 512, MM, 512, 2048);
    if (l + 1 < NLAYERS) {
      // LN2: xab (bf16 of x+tem) for next layer
      ln_kernel<true, false, false><<<MM, 256, 0, stream>>>(
          ybb, ln2_g + (size_t)l * 512, ln2_b + (size_t)l * 512, npm, tem,
          nullptr, xab);
    } else {
      // final layer: only the fp32 output x
      ln_kernel<false, true, false><<<MM, 256, 0, stream>>>(
          ybb, ln2_g + (size_t)l * 512, ln2_b + (size_t)l * 512, npm, nullptr,
          x, nullptr);
    }
  }
}